// Round 9
// baseline (476.542 us; speedup 1.0000x reference)
//
#include <hip/hip_runtime.h>
#include <math.h>

// ---------------------------------------------------------------------------
// SwinV2 stage: B=32, H=W=56, C=128, NH=4, hd=32, WS=7, N=49, DEPTH=2, shift=3
// Round 9: fused MLP kernel (fc1+gelu+fc2+LN+residual, hid stays in LDS,
// 206 MB HBM round-trip deleted); exp-based tanh GELU. Rest unchanged.
// ---------------------------------------------------------------------------

namespace {
constexpr int kTok = 32 * 56 * 56;   // 100352 tokens
}

typedef __attribute__((ext_vector_type(8))) short bf16x8;
typedef __attribute__((ext_vector_type(4))) float f32x4;

union FragU {
    int4 i4;
    bf16x8 b8;
    unsigned short u[8];
};

__device__ __forceinline__ short f2bf(float f) {
    unsigned u = __float_as_uint(f);
    return (short)((u + 0x7FFFu + ((u >> 16) & 1u)) >> 16);
}
__device__ __forceinline__ float bf2f(unsigned short u) {
    return __uint_as_float(((unsigned)u) << 16);
}
__device__ __forceinline__ unsigned cvt_pk_bf16(float a, float b) {
    unsigned r;
    asm("v_cvt_pk_bf16_f32 %0, %1, %2" : "=v"(r) : "v"(a), "v"(b));
    return r;
}
__device__ __forceinline__ float gelu_f(float x) {
    return 0.5f * x * (1.0f + erff(x * 0.70710678118654752f));
}
// tanh-form GELU via hardware exp (inputs here are |x| <~ 2: approx err <1e-4)
__device__ __forceinline__ float gelu_t(float x) {
    float t = 0.7978845608f * fmaf(0.044715f * x * x, x, x);
    float e = __expf(2.0f * t);
    float th = 1.0f - 2.0f / (e + 1.0f);
    return 0.5f * x * (1.0f + th);
}

// --------------------------- CPB MLP (tiny) --------------------------------
__global__ __launch_bounds__(256) void k_cpb(
    const float* __restrict__ w1, const float* __restrict__ b1,
    const float* __restrict__ w2, float* __restrict__ out169) {
    int t = blockIdx.x;  // 0..168
    int ia = t / 13, ib = t % 13;
    float r0 = (float)(ia - 6) * (8.0f / 6.0f);
    float s0 = (r0 > 0.f) ? 1.f : (r0 < 0.f ? -1.f : 0.f);
    float t0 = s0 * log2f(fabsf(r0) + 1.0f) * (1.0f / 3.0f);
    float r1 = (float)(ib - 6) * (8.0f / 6.0f);
    float s1 = (r1 > 0.f) ? 1.f : (r1 < 0.f ? -1.f : 0.f);
    float t1 = s1 * log2f(fabsf(r1) + 1.0f) * (1.0f / 3.0f);

    int tid = threadIdx.x;
    float p0 = 0, p1 = 0, p2 = 0, p3 = 0;
    for (int c = tid; c < 512; c += 256) {
        float hv = fmaxf(t0 * w1[c] + t1 * w1[512 + c] + b1[c], 0.0f);
        p0 += hv * w2[c * 4 + 0];
        p1 += hv * w2[c * 4 + 1];
        p2 += hv * w2[c * 4 + 2];
        p3 += hv * w2[c * 4 + 3];
    }
    __shared__ float red[256][4];
    red[tid][0] = p0; red[tid][1] = p1; red[tid][2] = p2; red[tid][3] = p3;
    __syncthreads();
    for (int s = 128; s > 0; s >>= 1) {
        if (tid < s) {
            red[tid][0] += red[tid + s][0];
            red[tid][1] += red[tid + s][1];
            red[tid][2] += red[tid + s][2];
            red[tid][3] += red[tid + s][3];
        }
        __syncthreads();
    }
    if (tid < 4) out169[t * 4 + tid] = red[0][tid];
}

// rpb64[h][qrow64][krow64]; krow>=49 -> -30000 (k-pad baked in)
__global__ void k_rpb(const float* __restrict__ out169, float* __restrict__ rpb64) {
    int e = blockIdx.x * 256 + threadIdx.x;
    if (e >= 4 * 64 * 64) return;
    int h = e >> 12, r = e & 4095;
    int i = r >> 6, j = r & 63;
    float val;
    if (j >= 49) {
        val = -30000.0f;
    } else if (i >= 49) {
        val = 0.0f;
    } else {
        int dp = i / 7 - j / 7 + 6;
        int dq = i % 7 - j % 7 + 6;
        float v = out169[(dp * 13 + dq) * 4 + h];
        val = 16.0f / (1.0f + expf(-v));
    }
    rpb64[e] = val;
}

// ------------------- weight fp32 -> bf16 tiled image -----------------------
// Logical slot (nt*Kb + kb)*64 + nn holds W[kb*8+e][nt*64+nn], e=0..7.
// Stored at physical nn' = (nn & ~3) | ((nn ^ kb) & 3).
__global__ __launch_bounds__(256) void k_cvtw(
    const float* __restrict__ W, short* __restrict__ Wb, int Kb, int N) {
    int slt = blockIdx.x * 256 + threadIdx.x;
    if (slt >= Kb * N) return;
    int nn = slt & 63;
    int tmp = slt >> 6;
    int kb = tmp % Kb;
    int nt = tmp / Kb;
    int n = nt * 64 + nn;
    int k0 = kb * 8;
    union { int4 i4; short s8[8]; } u;
#pragma unroll
    for (int e = 0; e < 8; ++e) u.s8[e] = f2bf(W[(size_t)(k0 + e) * N + n]);
    int nns = (nn & ~3) | ((nn ^ kb) & 3);
    *(int4*)(Wb + (((size_t)tmp) * 64 + nns) * 8) = u.i4;
}

// ------------------- activation fp32 -> bf16 rows --------------------------
__global__ __launch_bounds__(256) void k_cvtx(
    const float* __restrict__ x, short* __restrict__ xb) {
    size_t e = ((size_t)blockIdx.x * 256 + threadIdx.x) * 8;
    const float* src = x + e;
    float4 f0 = *(const float4*)src;
    float4 f1 = *(const float4*)(src + 4);
    union { int4 i4; short s8[8]; } u;
    u.s8[0] = f2bf(f0.x); u.s8[1] = f2bf(f0.y);
    u.s8[2] = f2bf(f0.z); u.s8[3] = f2bf(f0.w);
    u.s8[4] = f2bf(f1.x); u.s8[5] = f2bf(f1.y);
    u.s8[6] = f2bf(f1.z); u.s8[7] = f2bf(f1.w);
    *(int4*)(xb + e) = u.i4;
}

// --------------------------- MFMA GEMM (bf16 A) ----------------------------
// EPI: 0 = raw fp32; 1 = qkv bias -> bf16 out (stride 384), roll on A.
template <int K, int EPI, int NT>
__global__ __launch_bounds__(256) void k_gemm(
    const short* __restrict__ Ain, const short* __restrict__ Wb,
    const float* __restrict__ bias0, const float* __restrict__ bias1,
    void* __restrict__ Out, int ostride, int shift) {
    constexpr int Kb = K / 8;
    constexpr int NC = K / 128;
    __shared__ int4 As4[2048];  // [16 kb][128 m], XOR-swizzled (8-wide)
    __shared__ int4 Ws4[1024];  // [16 kb][64 nn], XOR-swizzled (4-wide, in image)
    int tid = threadIdx.x;
    int nwg = gridDim.x;
    int chunk = nwg >> 3;
    int lid = (blockIdx.x & 7) * chunk + (blockIdx.x >> 3);
    int mt = lid / NT, nt = lid - mt * NT;
    int mb = mt * 128;
    int w = tid >> 6, l = tid & 63, lr = l & 15, lg = l >> 4;
    const f32x4 fz = {0.f, 0.f, 0.f, 0.f};
    f32x4 acc[2][4];
#pragma unroll
    for (int mi = 0; mi < 2; ++mi)
#pragma unroll
        for (int ni = 0; ni < 4; ++ni) acc[mi][ni] = fz;

    for (int c = 0; c < NC; ++c) {
        if (c) __syncthreads();
#pragma unroll
        for (int it = 0; it < 8; ++it) {
            int s = it * 256 + tid;
            int m = s >> 4, kb = s & 15;
            int gm = mb + m;
            if (EPI == 1 && shift) {
                int b = gm / 3136, r = gm % 3136;
                int hh = r / 56 + shift; if (hh >= 56) hh -= 56;
                int ww = r % 56 + shift; if (ww >= 56) ww -= 56;
                gm = b * 3136 + hh * 56 + ww;
            }
            int slot = kb * 128 + ((m & ~7) | ((m ^ kb) & 7));
            As4[slot] = *(const int4*)(Ain + (size_t)gm * K + c * 128 + kb * 8);
        }
        {
            const int4* wsrc = (const int4*)(Wb + ((size_t)nt * Kb + c * 16) * 64 * 8);
#pragma unroll
            for (int it = 0; it < 4; ++it) Ws4[it * 256 + tid] = wsrc[it * 256 + tid];
        }
        __syncthreads();
#pragma unroll
        for (int kk = 0; kk < 4; ++kk) {
            int kbl = kk * 4 + lg;
            int m0 = w * 32 + lr;
            bf16x8 a0 = *(const bf16x8*)&As4[kbl * 128 + ((m0 & ~7) | ((m0 ^ kbl) & 7))];
            int m1 = m0 + 16;
            bf16x8 a1 = *(const bf16x8*)&As4[kbl * 128 + ((m1 & ~7) | ((m1 ^ kbl) & 7))];
#pragma unroll
            for (int ni = 0; ni < 4; ++ni) {
                int nn = lr + 16 * ni;
                bf16x8 bfr = *(const bf16x8*)&Ws4[kbl * 64 + ((nn & ~3) | ((nn ^ kbl) & 3))];
                acc[0][ni] = __builtin_amdgcn_mfma_f32_16x16x32_bf16(a0, bfr, acc[0][ni], 0, 0, 0);
                acc[1][ni] = __builtin_amdgcn_mfma_f32_16x16x32_bf16(a1, bfr, acc[1][ni], 0, 0, 0);
            }
        }
    }
#pragma unroll
    for (int ni = 0; ni < 4; ++ni) {
        int col = nt * 64 + ni * 16 + lr;
        float bv = 0.f;
        if (EPI == 1) bv = (col < 128) ? bias0[col] : ((col < 256) ? 0.f : bias1[col - 256]);
#pragma unroll
        for (int mi = 0; mi < 2; ++mi) {
#pragma unroll
            for (int r = 0; r < 4; ++r) {
                int row = mb + w * 32 + mi * 16 + lg * 4 + r;
                float v = acc[mi][ni][r] + bv;
                if (EPI == 0) {
                    ((float*)Out)[(size_t)row * ostride + col] = v;
                } else {
                    ((short*)Out)[(size_t)row * 384 + col] = f2bf(v);
                }
            }
        }
    }
}

// ------------- MFMA GEMM + bias + LN + residual (+roll-back) ---------------
// Used for the attention projection (K=128).
template <int K>
__global__ __launch_bounds__(256) void k_gemm_ln(
    const short* __restrict__ Ain, const short* __restrict__ Wb,
    const float* __restrict__ bias, const float* __restrict__ g,
    const float* __restrict__ bt, const float* __restrict__ resid,
    float* __restrict__ xout, short* __restrict__ xoutb, int shift) {
    constexpr int Kb = K / 8;
    constexpr int NC = K / 128;
    __shared__ int4 As4[1024];  // [16 kb][64 m]
    __shared__ int4 Ws4[2048];  // [2 ntw][16 kb][64 nn]
    int tid = threadIdx.x;
    int mb = blockIdx.x * 64;
    int w = tid >> 6, l = tid & 63, lr = l & 15, lg = l >> 4;
    const f32x4 fz = {0.f, 0.f, 0.f, 0.f};
    f32x4 acc[8];
#pragma unroll
    for (int ni = 0; ni < 8; ++ni) acc[ni] = fz;

    for (int c = 0; c < NC; ++c) {
        if (c) __syncthreads();
#pragma unroll
        for (int it = 0; it < 4; ++it) {
            int s = it * 256 + tid;
            int m = s >> 4, kb = s & 15;
            int slot = kb * 64 + ((m & ~7) | ((m ^ kb) & 7));
            As4[slot] = *(const int4*)(Ain + (size_t)(mb + m) * K + c * 128 + kb * 8);
        }
        {
            const int4* w0 = (const int4*)(Wb + ((size_t)(c * 16)) * 64 * 8);
            const int4* w1 = (const int4*)(Wb + ((size_t)(Kb + c * 16)) * 64 * 8);
#pragma unroll
            for (int it = 0; it < 4; ++it) {
                Ws4[it * 256 + tid] = w0[it * 256 + tid];
                Ws4[1024 + it * 256 + tid] = w1[it * 256 + tid];
            }
        }
        __syncthreads();
#pragma unroll
        for (int kk = 0; kk < 4; ++kk) {
            int kbl = kk * 4 + lg;
            int m0 = w * 16 + lr;
            bf16x8 a0 = *(const bf16x8*)&As4[kbl * 64 + ((m0 & ~7) | ((m0 ^ kbl) & 7))];
#pragma unroll
            for (int ni = 0; ni < 8; ++ni) {
                int nn = lr + 16 * (ni & 3);
                bf16x8 bfr = *(const bf16x8*)&Ws4[(ni >> 2) * 1024 + kbl * 64 +
                                                  ((nn & ~3) | ((nn ^ kbl) & 3))];
                acc[ni] = __builtin_amdgcn_mfma_f32_16x16x32_bf16(a0, bfr, acc[ni], 0, 0, 0);
            }
        }
    }
    float bv[8], gv[8], btv[8];
#pragma unroll
    for (int ni = 0; ni < 8; ++ni) {
        int col = ni * 16 + lr;
        bv[ni] = bias[col]; gv[ni] = g[col]; btv[ni] = bt[col];
    }
#pragma unroll
    for (int r = 0; r < 4; ++r) {
        int row = mb + w * 16 + lg * 4 + r;
        float v[8];
        float s1 = 0.f, s2 = 0.f;
#pragma unroll
        for (int ni = 0; ni < 8; ++ni) {
            v[ni] = acc[ni][r] + bv[ni];
            s1 += v[ni];
            s2 = fmaf(v[ni], v[ni], s2);
        }
#pragma unroll
        for (int off = 8; off >= 1; off >>= 1) {
            s1 += __shfl_xor(s1, off);
            s2 += __shfl_xor(s2, off);
        }
        float mean = s1 * (1.0f / 128.0f);
        float var = s2 * (1.0f / 128.0f) - mean * mean;
        float rstd = rsqrtf(var + 1e-5f);
        int mo = row;
        if (shift) {
            int b = row / 3136, rr = row % 3136;
            int hh = rr / 56 + shift; if (hh >= 56) hh -= 56;
            int ww = rr % 56 + shift; if (ww >= 56) ww -= 56;
            mo = b * 3136 + hh * 56 + ww;
        }
        size_t base = (size_t)mo * 128;
#pragma unroll
        for (int ni = 0; ni < 8; ++ni) {
            int col = ni * 16 + lr;
            float o = resid[base + col] + (v[ni] - mean) * rstd * gv[ni] + btv[ni];
            xout[base + col] = o;
            xoutb[base + col] = f2bf(o);
        }
    }
}

// -------------------- Fused MLP: fc1 + GELU + fc2 + LN + residual ----------
// xout[row] = resid[row] + LN(gelu(x[row]@W1+b1)@W2+b2). BM=64, 4 waves.
// hid never leaves the CU: per 64-col chunk, each wave computes fc1 for its
// 16 rows, writes the chunk into a wave-private LDS A-image, and immediately
// accumulates fc2. 8 chunks; W1/W2 chunk slices staged in LDS per chunk.
__global__ __launch_bounds__(256) void k_mlp(
    const short* __restrict__ xbin, const short* __restrict__ W1b,
    const short* __restrict__ W2b, const float* __restrict__ b1,
    const float* __restrict__ b2, const float* __restrict__ g,
    const float* __restrict__ bt, const float* __restrict__ resid,
    float* __restrict__ xout, short* __restrict__ xoutb) {
    __shared__ int4 As4[1024];   // x rows: [16 kb][64 m]
    __shared__ int4 W1s[1024];   // chunk: [16 kb][64 nn]
    __shared__ int4 W2s[1024];   // chunk: [2 ntw][8 kb][64 nn]
    __shared__ int4 Hs[512];     // hid: [4 wave][8 kb][16 m] (wave-private)
    int tid = threadIdx.x;
    int mb = blockIdx.x * 64;
    int w = tid >> 6, l = tid & 63, lr = l & 15, lg = l >> 4;
    const f32x4 fz = {0.f, 0.f, 0.f, 0.f};

    // stage x rows once
#pragma unroll
    for (int it = 0; it < 4; ++it) {
        int s = it * 256 + tid;
        int m = s >> 4, kb = s & 15;
        int slot = kb * 64 + ((m & ~7) | ((m ^ kb) & 7));
        As4[slot] = *(const int4*)(xbin + (size_t)(mb + m) * 128 + kb * 8);
    }

    f32x4 acc2[8];
#pragma unroll
    for (int ni = 0; ni < 8; ++ni) acc2[ni] = fz;
    int4* Hw = Hs + w * 128;

    for (int c = 0; c < 8; ++c) {
        __syncthreads();   // prev chunk's W reads done (and As staged, c=0)
        {
            const int4* w1src = (const int4*)(W1b + (size_t)c * 8192);
#pragma unroll
            for (int it = 0; it < 4; ++it) W1s[it * 256 + tid] = w1src[it * 256 + tid];
            const int4* w2a = (const int4*)(W2b + (size_t)(c * 8) * 512);
            const int4* w2b_ = (const int4*)(W2b + (size_t)(64 + c * 8) * 512);
#pragma unroll
            for (int it = 0; it < 2; ++it) {
                W2s[it * 256 + tid] = w2a[it * 256 + tid];
                W2s[512 + it * 256 + tid] = w2b_[it * 256 + tid];
            }
        }
        __syncthreads();
        // fc1: 16 rows x 64 cols of this chunk
        f32x4 acc1[4];
#pragma unroll
        for (int ni = 0; ni < 4; ++ni) acc1[ni] = fz;
        __builtin_amdgcn_s_setprio(1);
#pragma unroll
        for (int kk = 0; kk < 4; ++kk) {
            int kbl = kk * 4 + lg;
            int m0 = w * 16 + lr;
            bf16x8 a0 = *(const bf16x8*)&As4[kbl * 64 + ((m0 & ~7) | ((m0 ^ kbl) & 7))];
#pragma unroll
            for (int ni = 0; ni < 4; ++ni) {
                int nn = lr + 16 * ni;
                bf16x8 bfr = *(const bf16x8*)&W1s[kbl * 64 + ((nn & ~3) | ((nn ^ kbl) & 3))];
                acc1[ni] = __builtin_amdgcn_mfma_f32_16x16x32_bf16(a0, bfr, acc1[ni], 0, 0, 0);
            }
        }
        __builtin_amdgcn_s_setprio(0);
        // bias + gelu -> wave-private hid A-image (col=k of fc2, m=local row)
#pragma unroll
        for (int ni = 0; ni < 4; ++ni) {
            float bb = b1[c * 64 + ni * 16 + lr];
#pragma unroll
            for (int r = 0; r < 4; ++r) {
                float hv = gelu_t(acc1[ni][r] + bb);
                int col = ni * 16 + lr;
                int m = lg * 4 + r;
                int kb = col >> 3;
                int slot = kb * 16 + ((m & ~7) | ((m ^ kb) & 7));
                ((short*)Hw)[slot * 8 + (col & 7)] = f2bf(hv);
            }
        }
        // fc2 accumulate: K=64 (this chunk)
        __builtin_amdgcn_s_setprio(1);
#pragma unroll
        for (int kk = 0; kk < 2; ++kk) {
            int kbl = kk * 4 + lg;   // local kb 0..7
            bf16x8 a0 = *(const bf16x8*)&Hw[kbl * 16 + ((lr & ~7) | ((lr ^ kbl) & 7))];
#pragma unroll
            for (int ni = 0; ni < 8; ++ni) {
                int nn = lr + 16 * (ni & 3);
                bf16x8 bfr = *(const bf16x8*)&W2s[(ni >> 2) * 512 + kbl * 64 +
                                                  ((nn & ~3) | ((nn ^ kbl) & 3))];
                acc2[ni] = __builtin_amdgcn_mfma_f32_16x16x32_bf16(a0, bfr, acc2[ni], 0, 0, 0);
            }
        }
        __builtin_amdgcn_s_setprio(0);
    }

    // LN + residual epilogue (identical math to k_gemm_ln, shift=0)
    float bv[8], gv[8], btv[8];
#pragma unroll
    for (int ni = 0; ni < 8; ++ni) {
        int col = ni * 16 + lr;
        bv[ni] = b2[col]; gv[ni] = g[col]; btv[ni] = bt[col];
    }
#pragma unroll
    for (int r = 0; r < 4; ++r) {
        int row = mb + w * 16 + lg * 4 + r;
        float v[8];
        float s1 = 0.f, s2 = 0.f;
#pragma unroll
        for (int ni = 0; ni < 8; ++ni) {
            v[ni] = acc2[ni][r] + bv[ni];
            s1 += v[ni];
            s2 = fmaf(v[ni], v[ni], s2);
        }
#pragma unroll
        for (int off = 8; off >= 1; off >>= 1) {
            s1 += __shfl_xor(s1, off);
            s2 += __shfl_xor(s2, off);
        }
        float mean = s1 * (1.0f / 128.0f);
        float var = s2 * (1.0f / 128.0f) - mean * mean;
        float rstd = rsqrtf(var + 1e-5f);
        size_t base = (size_t)row * 128;
#pragma unroll
        for (int ni = 0; ni < 8; ++ni) {
            int col = ni * 16 + lr;
            float o = resid[base + col] + (v[ni] - mean) * rstd * gv[ni] + btv[ni];
            xout[base + col] = o;
            xoutb[base + col] = f2bf(o);
        }
    }
}

// --------------------------- MFMA windowed attention -----------------------
__global__ __launch_bounds__(256) void k_attn(
    const short* __restrict__ qkv, const float* __restrict__ rpb64,
    const float* __restrict__ ls, short* __restrict__ aout, int shift) {
    __shared__ short lds[4 * 3584];
    int wid = blockIdx.x;
    int b = wid >> 6, wrem = wid & 63;
    int wh = wrem >> 3, ww_ = wrem & 7;
    int h = threadIdx.x >> 6;
    int l = threadIdx.x & 63, lr = l & 15, lg = l >> 4;
    short* Pt = lds + h * 3584;              // [16 qrow][72]
    short* Vt = Pt + 1152;                   // [32 d][72]
    float* invks = (float*)(Vt + 2304);      // [64] 1/||k_j||
    int tokbase = b * 3136 + wh * 7 * 56 + ww_ * 7;

    float scale = __expf(fminf(ls[h], 4.6051702f));  // ln(100)
    int4 qf[4], kf[4], vf[4];
    const int4 zero4 = make_int4(0, 0, 0, 0);
#pragma unroll
    for (int t = 0; t < 4; ++t) {
        int i = t * 16 + lr;
        bool valid = (i < 49);
        int tok = tokbase + (i / 7) * 56 + (i % 7);
        const short* base = qkv + (size_t)tok * 384 + h * 32 + lg * 8;
        qf[t] = valid ? *(const int4*)base : zero4;
        kf[t] = valid ? *(const int4*)(base + 128) : zero4;
    }
#pragma unroll
    for (int t = 0; t < 4; ++t) {
        int e = t * 64 + l;
        int j = e >> 2, dq = e & 3;
        if (j < 49) {
            int tok = tokbase + (j / 7) * 56 + (j % 7);
            vf[t] = *(const int4*)(qkv + (size_t)tok * 384 + 256 + h * 32 + dq * 8);
        } else {
            vf[t] = zero4;
        }
    }

    float invq[4];
#pragma unroll
    for (int t = 0; t < 4; ++t) {
        {
            FragU u; u.i4 = qf[t];
            float ss = 0.f;
#pragma unroll
            for (int e = 0; e < 8; ++e) { float x = bf2f(u.u[e]); ss = fmaf(x, x, ss); }
            ss += __shfl_xor(ss, 16);
            ss += __shfl_xor(ss, 32);
            invq[t] = scale / fmaxf(sqrtf(ss), 1e-12f);
        }
        {
            FragU u; u.i4 = kf[t];
            float ss = 0.f;
#pragma unroll
            for (int e = 0; e < 8; ++e) { float x = bf2f(u.u[e]); ss = fmaf(x, x, ss); }
            ss += __shfl_xor(ss, 16);
            ss += __shfl_xor(ss, 32);
            float ik = 1.0f / fmaxf(sqrtf(ss), 1e-12f);
            if (l < 16) invks[t * 16 + l] = ik;
        }
    }

    for (int t = l; t < 480; t += 64) {
        Vt[(t / 15) * 72 + 49 + (t % 15)] = 0;
    }
#pragma unroll
    for (int t = 0; t < 4; ++t) {
        int e = t * 64 + l;
        int j = e >> 2, dq = e & 3;
        if (j < 49) {
            FragU u; u.i4 = vf[t];
#pragma unroll
            for (int ee = 0; ee < 8; ++ee) Vt[(dq * 8 + ee) * 72 + j] = (short)u.u[ee];
        }
    }

    float ika[4][4];
#pragma unroll
    for (int jt = 0; jt < 4; ++jt) {
        float4 v4 = *(const float4*)&invks[jt * 16 + lg * 4];
        ika[jt][0] = v4.x; ika[jt][1] = v4.y; ika[jt][2] = v4.z; ika[jt][3] = v4.w;
    }

    bool edge = (shift != 0) && ((wh == 7) || (ww_ == 7));
    const float* rbase = rpb64 + h * 4096;
    const f32x4 fz = {0.f, 0.f, 0.f, 0.f};
    f32x4 oacc[2][4];
#pragma unroll
    for (int mi = 0; mi < 2; ++mi)
#pragma unroll
        for (int ni = 0; ni < 4; ++ni) oacc[mi][ni] = fz;

#pragma unroll
    for (int qt = 0; qt < 4; ++qt) {
        f32x4 at[4];
        __builtin_amdgcn_s_setprio(1);
#pragma unroll
        for (int jt = 0; jt < 4; ++jt) {
            FragU a; a.i4 = kf[jt];
            FragU bq; bq.i4 = qf[qt];
            at[jt] = __builtin_amdgcn_mfma_f32_16x16x32_bf16(a.b8, bq.b8, fz, 0, 0, 0);
        }
        __builtin_amdgcn_s_setprio(0);

        float iq = invq[qt];
        int qi = qt * 16 + lr;
        int qc = (qi < 49) ? qi : 48;
        int rlq = 0, clq = 0;
        if (edge) {
            rlq = (wh == 7) ? ((qc / 7) < 4 ? 1 : 2) : 0;
            clq = (ww_ == 7) ? ((qc % 7) < 4 ? 1 : 2) : 0;
        }
#pragma unroll
        for (int jt = 0; jt < 4; ++jt) {
            float4 rv = *(const float4*)(rbase + qc * 64 + jt * 16 + lg * 4);
            float rr[4] = {rv.x, rv.y, rv.z, rv.w};
#pragma unroll
            for (int r = 0; r < 4; ++r) {
                float v = fmaf(at[jt][r] * ika[jt][r], iq, rr[r]);
                if (edge) {
                    int j = jt * 16 + lg * 4 + r;
                    int jc = (j < 49) ? j : 48;
                    int rlk = (wh == 7) ? ((jc / 7) < 4 ? 1 : 2) : 0;
                    int clk = (ww_ == 7) ? ((jc % 7) < 4 ? 1 : 2) : 0;
                    if (rlk != rlq || clk != clq) v -= 100.0f;
                }
                at[jt][r] = v;
            }
        }
        float m = -1e30f;
#pragma unroll
        for (int jt = 0; jt < 4; ++jt)
#pragma unroll
            for (int r = 0; r < 4; ++r) m = fmaxf(m, at[jt][r]);
        m = fmaxf(m, __shfl_xor(m, 16));
        m = fmaxf(m, __shfl_xor(m, 32));
        float s = 0.f;
#pragma unroll
        for (int jt = 0; jt < 4; ++jt)
#pragma unroll
            for (int r = 0; r < 4; ++r) {
                float p = __expf(at[jt][r] - m);
                at[jt][r] = p;
                s += p;
            }
        s += __shfl_xor(s, 16);
        s += __shfl_xor(s, 32);
        float inv = 1.0f / s;
#pragma unroll
        for (int jt = 0; jt < 4; ++jt) {
            unsigned lo = cvt_pk_bf16(at[jt][0] * inv, at[jt][1] * inv);
            unsigned hi = cvt_pk_bf16(at[jt][2] * inv, at[jt][3] * inv);
            *(int2*)&Pt[lr * 72 + jt * 16 + lg * 4] = make_int2((int)lo, (int)hi);
        }
        __builtin_amdgcn_s_setprio(1);
#pragma unroll
        for (int kc = 0; kc < 2; ++kc) {
            FragU pb;
            pb.i4 = *(const int4*)&Pt[lr * 72 + kc * 32 + lg * 8];
#pragma unroll
            for (int mi = 0; mi < 2; ++mi) {
                FragU va;
                va.i4 = *(const int4*)&Vt[(mi * 16 + lr) * 72 + kc * 32 + lg * 8];
                oacc[mi][qt] = __builtin_amdgcn_mfma_f32_16x16x32_bf16(
                    va.b8, pb.b8, oacc[mi][qt], 0, 0, 0);
            }
        }
        __builtin_amdgcn_s_setprio(0);
    }

#pragma unroll
    for (int ni = 0; ni < 4; ++ni) {
        int qrow = ni * 16 + lr;
        if (qrow < 49) {
            int tok = tokbase + (qrow / 7) * 56 + (qrow % 7);
#pragma unroll
            for (int mi = 0; mi < 2; ++mi) {
                unsigned lo = cvt_pk_bf16(oacc[mi][ni][0], oacc[mi][ni][1]);
                unsigned hi = cvt_pk_bf16(oacc[mi][ni][2], oacc[mi][ni][3]);
                *(int2*)&aout[(size_t)tok * 128 + h * 32 + mi * 16 + lg * 4] =
                    make_int2((int)lo, (int)hi);
            }
        }
    }
}

// ------------- PatchMerging gather + LN -> bf16 rows [25088][512] ----------
__global__ __launch_bounds__(256) void k_pmln(
    const float* __restrict__ x, const float* __restrict__ g,
    const float* __restrict__ bt, short* __restrict__ outb) {
    int m2 = blockIdx.x * 4 + (threadIdx.x >> 6);
    int l = threadIdx.x & 63;
    int b = m2 / 784, r = m2 % 784;
    int h2 = r / 28, w2 = r % 28;
    int q0 = l * 8;
    int i2 = q0 >> 8, j2 = (q0 >> 7) & 1, c = q0 & 127;
    const float* src = x + (size_t)((b * 56 + 2 * h2 + i2) * 56 + 2 * w2 + j2) * 128 + c;
    float4 f0 = *(const float4*)src;
    float4 f1 = *(const float4*)(src + 4);
    float v[8] = {f0.x, f0.y, f0.z, f0.w, f1.x, f1.y, f1.z, f1.w};
    float s1 = 0.f, s2 = 0.f;
#pragma unroll
    for (int e = 0; e < 8; ++e) { s1 += v[e]; s2 = fmaf(v[e], v[e], s2); }
#pragma unroll
    for (int off = 32; off >= 1; off >>= 1) {
        s1 += __shfl_xor(s1, off);
        s2 += __shfl_xor(s2, off);
    }
    float mean = s1 * (1.0f / 512.0f);
    float var = s2 * (1.0f / 512.0f) - mean * mean;
    float rstd = rsqrtf(var + 1e-5f);
    union { int4 i4; short s8[8]; } u;
#pragma unroll
    for (int e = 0; e < 8; ++e)
        u.s8[e] = f2bf((v[e] - mean) * rstd * g[q0 + e] + bt[q0 + e]);
    *(int4*)(outb + (size_t)m2 * 512 + q0) = u.i4;
}

// ---------------------------------------------------------------------------
extern "C" void kernel_launch(void* const* d_in, const int* in_sizes, int n_in,
                              void* d_out, int out_size, void* d_ws, size_t ws_size,
                              hipStream_t stream) {
    const float* x_in   = (const float*)d_in[0];
    const float* qkv_w  = (const float*)d_in[1];
    const float* q_bias = (const float*)d_in[2];
    const float* v_bias = (const float*)d_in[3];
    const float* lscale = (const float*)d_in[4];
    const float* cpb_w1 = (const float*)d_in[5];
    const float* cpb_b1 = (const float*)d_in[6];
    const float* cpb_w2 = (const float*)d_in[7];
    const float* proj_w = (const float*)d_in[8];
    const float* proj_b = (const float*)d_in[9];
    const float* n1g    = (const float*)d_in[10];
    const float* n1b    = (const float*)d_in[11];
    const float* mw1    = (const float*)d_in[12];
    const float* mb1    = (const float*)d_in[13];
    const float* mw2    = (const float*)d_in[14];
    const float* mb2    = (const float*)d_in[15];
    const float* n2g    = (const float*)d_in[16];
    const float* n2b    = (const float*)d_in[17];
    const float* pmg    = (const float*)d_in[18];
    const float* pmb    = (const float*)d_in[19];
    const float* pmw    = (const float*)d_in[20];
    float* out = (float*)d_out;

    float* wsf     = (float*)d_ws;
    float* xcur    = wsf;
    float* R1      = wsf + (size_t)12845056;
    short* qkvb    = (short*)R1;
    short* attnout = (short*)(R1 + (size_t)19267584);   // kTok*128 bf16
    short* pmin    = (short*)R1;                        // 25088*512 bf16
    short* xb      = (short*)(R1 + (size_t)25690112);   // kTok*128 bf16
    float* wtail   = R1 + (size_t)38535168;
    short* wqkvb   = (short*)wtail;          // 49,152 bf16
    short* wprojb  = wqkvb + 49152;          // 16,384
    short* wm1b    = wprojb + 16384;         // 65,536
    short* wm2b    = wm1b + 65536;           // 65,536
    short* wpmb    = wm2b + 65536;           // 131,072
    float* out169  = wtail + 163840;
    float* rpb64   = out169 + 704;

    k_cvtx<<<6272, 256, 0, stream>>>(x_in, xb);

    for (int i = 0; i < 2; ++i) {
        int shift = i ? 3 : 0;
        const float* xi = (i == 0) ? x_in : xcur;
        k_cpb<<<169, 256, 0, stream>>>(cpb_w1 + i * 1024, cpb_b1 + i * 512,
                                       cpb_w2 + i * 2048, out169);
        k_rpb<<<64, 256, 0, stream>>>(out169, rpb64);
        k_cvtw<<<24, 256, 0, stream>>>(qkv_w + i * 49152, wqkvb, 16, 384);
        k_cvtw<<<8, 256, 0, stream>>>(proj_w + i * 16384, wprojb, 16, 128);
        k_cvtw<<<32, 256, 0, stream>>>(mw1 + i * 65536, wm1b, 16, 512);
        k_cvtw<<<32, 256, 0, stream>>>(mw2 + i * 65536, wm2b, 64, 128);

        k_gemm<128, 1, 6><<<4704, 256, 0, stream>>>(
            xb, wqkvb, q_bias + i * 128, v_bias + i * 128, qkvb, 384, shift);
        k_attn<<<2048, 256, 0, stream>>>(
            qkvb, rpb64, lscale + i * 4, attnout, shift);
        k_gemm_ln<128><<<1568, 256, 0, stream>>>(
            attnout, wprojb, proj_b + i * 128, n1g + i * 128, n1b + i * 128,
            xi, xcur, xb, shift);
        k_mlp<<<1568, 256, 0, stream>>>(
            xb, wm1b, wm2b, mb1 + i * 512, mb2 + i * 128,
            n2g + i * 128, n2b + i * 128, xcur, xcur, xb);
    }
    k_cvtw<<<64, 256, 0, stream>>>(pmw, wpmb, 64, 256);
    k_pmln<<<6272, 256, 0, stream>>>(xcur, pmg, pmb, pmin);
    k_gemm<512, 0, 4><<<784, 256, 0, stream>>>(
        pmin, wpmb, nullptr, nullptr, out, 256, 0);
}

// Round 10
// 442.824 us; speedup vs baseline: 1.0761x; 1.0761x over previous
//
#include <hip/hip_runtime.h>
#include <math.h>

// ---------------------------------------------------------------------------
// SwinV2 stage: B=32, H=W=56, C=128, NH=4, hd=32, WS=7, N=49, DEPTH=2, shift=3
// Round 10: k_mlp v2 — swapped-operand fc1 (H^T in A-layout directly),
// cvt_pk int2 hid writes, x rows in registers (no As4): LDS 57->41KB,
// 3 blocks/CU. Rest unchanged from R9.
// ---------------------------------------------------------------------------

namespace {
constexpr int kTok = 32 * 56 * 56;   // 100352 tokens
}

typedef __attribute__((ext_vector_type(8))) short bf16x8;
typedef __attribute__((ext_vector_type(4))) float f32x4;

union FragU {
    int4 i4;
    bf16x8 b8;
    unsigned short u[8];
};

__device__ __forceinline__ short f2bf(float f) {
    unsigned u = __float_as_uint(f);
    return (short)((u + 0x7FFFu + ((u >> 16) & 1u)) >> 16);
}
__device__ __forceinline__ float bf2f(unsigned short u) {
    return __uint_as_float(((unsigned)u) << 16);
}
__device__ __forceinline__ unsigned cvt_pk_bf16(float a, float b) {
    unsigned r;
    asm("v_cvt_pk_bf16_f32 %0, %1, %2" : "=v"(r) : "v"(a), "v"(b));
    return r;
}
// tanh-form GELU via hardware exp (inputs |x| <~ 2: approx err <1e-4)
__device__ __forceinline__ float gelu_t(float x) {
    float t = 0.7978845608f * fmaf(0.044715f * x * x, x, x);
    float e = __expf(2.0f * t);
    float th = 1.0f - 2.0f / (e + 1.0f);
    return 0.5f * x * (1.0f + th);
}

// --------------------------- CPB MLP (tiny) --------------------------------
__global__ __launch_bounds__(256) void k_cpb(
    const float* __restrict__ w1, const float* __restrict__ b1,
    const float* __restrict__ w2, float* __restrict__ out169) {
    int t = blockIdx.x;  // 0..168
    int ia = t / 13, ib = t % 13;
    float r0 = (float)(ia - 6) * (8.0f / 6.0f);
    float s0 = (r0 > 0.f) ? 1.f : (r0 < 0.f ? -1.f : 0.f);
    float t0 = s0 * log2f(fabsf(r0) + 1.0f) * (1.0f / 3.0f);
    float r1 = (float)(ib - 6) * (8.0f / 6.0f);
    float s1 = (r1 > 0.f) ? 1.f : (r1 < 0.f ? -1.f : 0.f);
    float t1 = s1 * log2f(fabsf(r1) + 1.0f) * (1.0f / 3.0f);

    int tid = threadIdx.x;
    float p0 = 0, p1 = 0, p2 = 0, p3 = 0;
    for (int c = tid; c < 512; c += 256) {
        float hv = fmaxf(t0 * w1[c] + t1 * w1[512 + c] + b1[c], 0.0f);
        p0 += hv * w2[c * 4 + 0];
        p1 += hv * w2[c * 4 + 1];
        p2 += hv * w2[c * 4 + 2];
        p3 += hv * w2[c * 4 + 3];
    }
    __shared__ float red[256][4];
    red[tid][0] = p0; red[tid][1] = p1; red[tid][2] = p2; red[tid][3] = p3;
    __syncthreads();
    for (int s = 128; s > 0; s >>= 1) {
        if (tid < s) {
            red[tid][0] += red[tid + s][0];
            red[tid][1] += red[tid + s][1];
            red[tid][2] += red[tid + s][2];
            red[tid][3] += red[tid + s][3];
        }
        __syncthreads();
    }
    if (tid < 4) out169[t * 4 + tid] = red[0][tid];
}

// rpb64[h][qrow64][krow64]; krow>=49 -> -30000 (k-pad baked in)
__global__ void k_rpb(const float* __restrict__ out169, float* __restrict__ rpb64) {
    int e = blockIdx.x * 256 + threadIdx.x;
    if (e >= 4 * 64 * 64) return;
    int h = e >> 12, r = e & 4095;
    int i = r >> 6, j = r & 63;
    float val;
    if (j >= 49) {
        val = -30000.0f;
    } else if (i >= 49) {
        val = 0.0f;
    } else {
        int dp = i / 7 - j / 7 + 6;
        int dq = i % 7 - j % 7 + 6;
        float v = out169[(dp * 13 + dq) * 4 + h];
        val = 16.0f / (1.0f + expf(-v));
    }
    rpb64[e] = val;
}

// ------------------- weight fp32 -> bf16 tiled image -----------------------
// Logical slot (nt*Kb + kb)*64 + nn holds W[kb*8+e][nt*64+nn], e=0..7.
// Stored at physical nn' = (nn & ~3) | ((nn ^ kb) & 3).
__global__ __launch_bounds__(256) void k_cvtw(
    const float* __restrict__ W, short* __restrict__ Wb, int Kb, int N) {
    int slt = blockIdx.x * 256 + threadIdx.x;
    if (slt >= Kb * N) return;
    int nn = slt & 63;
    int tmp = slt >> 6;
    int kb = tmp % Kb;
    int nt = tmp / Kb;
    int n = nt * 64 + nn;
    int k0 = kb * 8;
    union { int4 i4; short s8[8]; } u;
#pragma unroll
    for (int e = 0; e < 8; ++e) u.s8[e] = f2bf(W[(size_t)(k0 + e) * N + n]);
    int nns = (nn & ~3) | ((nn ^ kb) & 3);
    *(int4*)(Wb + (((size_t)tmp) * 64 + nns) * 8) = u.i4;
}

// ------------------- activation fp32 -> bf16 rows --------------------------
__global__ __launch_bounds__(256) void k_cvtx(
    const float* __restrict__ x, short* __restrict__ xb) {
    size_t e = ((size_t)blockIdx.x * 256 + threadIdx.x) * 8;
    const float* src = x + e;
    float4 f0 = *(const float4*)src;
    float4 f1 = *(const float4*)(src + 4);
    union { int4 i4; short s8[8]; } u;
    u.s8[0] = f2bf(f0.x); u.s8[1] = f2bf(f0.y);
    u.s8[2] = f2bf(f0.z); u.s8[3] = f2bf(f0.w);
    u.s8[4] = f2bf(f1.x); u.s8[5] = f2bf(f1.y);
    u.s8[6] = f2bf(f1.z); u.s8[7] = f2bf(f1.w);
    *(int4*)(xb + e) = u.i4;
}

// --------------------------- MFMA GEMM (bf16 A) ----------------------------
// EPI: 0 = raw fp32; 1 = qkv bias -> bf16 out (stride 384), roll on A.
template <int K, int EPI, int NT>
__global__ __launch_bounds__(256) void k_gemm(
    const short* __restrict__ Ain, const short* __restrict__ Wb,
    const float* __restrict__ bias0, const float* __restrict__ bias1,
    void* __restrict__ Out, int ostride, int shift) {
    constexpr int Kb = K / 8;
    constexpr int NC = K / 128;
    __shared__ int4 As4[2048];  // [16 kb][128 m], XOR-swizzled (8-wide)
    __shared__ int4 Ws4[1024];  // [16 kb][64 nn], XOR-swizzled (4-wide, in image)
    int tid = threadIdx.x;
    int nwg = gridDim.x;
    int chunk = nwg >> 3;
    int lid = (blockIdx.x & 7) * chunk + (blockIdx.x >> 3);
    int mt = lid / NT, nt = lid - mt * NT;
    int mb = mt * 128;
    int w = tid >> 6, l = tid & 63, lr = l & 15, lg = l >> 4;
    const f32x4 fz = {0.f, 0.f, 0.f, 0.f};
    f32x4 acc[2][4];
#pragma unroll
    for (int mi = 0; mi < 2; ++mi)
#pragma unroll
        for (int ni = 0; ni < 4; ++ni) acc[mi][ni] = fz;

    for (int c = 0; c < NC; ++c) {
        if (c) __syncthreads();
#pragma unroll
        for (int it = 0; it < 8; ++it) {
            int s = it * 256 + tid;
            int m = s >> 4, kb = s & 15;
            int gm = mb + m;
            if (EPI == 1 && shift) {
                int b = gm / 3136, r = gm % 3136;
                int hh = r / 56 + shift; if (hh >= 56) hh -= 56;
                int ww = r % 56 + shift; if (ww >= 56) ww -= 56;
                gm = b * 3136 + hh * 56 + ww;
            }
            int slot = kb * 128 + ((m & ~7) | ((m ^ kb) & 7));
            As4[slot] = *(const int4*)(Ain + (size_t)gm * K + c * 128 + kb * 8);
        }
        {
            const int4* wsrc = (const int4*)(Wb + ((size_t)nt * Kb + c * 16) * 64 * 8);
#pragma unroll
            for (int it = 0; it < 4; ++it) Ws4[it * 256 + tid] = wsrc[it * 256 + tid];
        }
        __syncthreads();
#pragma unroll
        for (int kk = 0; kk < 4; ++kk) {
            int kbl = kk * 4 + lg;
            int m0 = w * 32 + lr;
            bf16x8 a0 = *(const bf16x8*)&As4[kbl * 128 + ((m0 & ~7) | ((m0 ^ kbl) & 7))];
            int m1 = m0 + 16;
            bf16x8 a1 = *(const bf16x8*)&As4[kbl * 128 + ((m1 & ~7) | ((m1 ^ kbl) & 7))];
#pragma unroll
            for (int ni = 0; ni < 4; ++ni) {
                int nn = lr + 16 * ni;
                bf16x8 bfr = *(const bf16x8*)&Ws4[kbl * 64 + ((nn & ~3) | ((nn ^ kbl) & 3))];
                acc[0][ni] = __builtin_amdgcn_mfma_f32_16x16x32_bf16(a0, bfr, acc[0][ni], 0, 0, 0);
                acc[1][ni] = __builtin_amdgcn_mfma_f32_16x16x32_bf16(a1, bfr, acc[1][ni], 0, 0, 0);
            }
        }
    }
#pragma unroll
    for (int ni = 0; ni < 4; ++ni) {
        int col = nt * 64 + ni * 16 + lr;
        float bv = 0.f;
        if (EPI == 1) bv = (col < 128) ? bias0[col] : ((col < 256) ? 0.f : bias1[col - 256]);
#pragma unroll
        for (int mi = 0; mi < 2; ++mi) {
#pragma unroll
            for (int r = 0; r < 4; ++r) {
                int row = mb + w * 32 + mi * 16 + lg * 4 + r;
                float v = acc[mi][ni][r] + bv;
                if (EPI == 0) {
                    ((float*)Out)[(size_t)row * ostride + col] = v;
                } else {
                    ((short*)Out)[(size_t)row * 384 + col] = f2bf(v);
                }
            }
        }
    }
}

// ------------- MFMA GEMM + bias + LN + residual (+roll-back) ---------------
// Used for the attention projection (K=128).
template <int K>
__global__ __launch_bounds__(256) void k_gemm_ln(
    const short* __restrict__ Ain, const short* __restrict__ Wb,
    const float* __restrict__ bias, const float* __restrict__ g,
    const float* __restrict__ bt, const float* __restrict__ resid,
    float* __restrict__ xout, short* __restrict__ xoutb, int shift) {
    constexpr int Kb = K / 8;
    constexpr int NC = K / 128;
    __shared__ int4 As4[1024];  // [16 kb][64 m]
    __shared__ int4 Ws4[2048];  // [2 ntw][16 kb][64 nn]
    int tid = threadIdx.x;
    int mb = blockIdx.x * 64;
    int w = tid >> 6, l = tid & 63, lr = l & 15, lg = l >> 4;
    const f32x4 fz = {0.f, 0.f, 0.f, 0.f};
    f32x4 acc[8];
#pragma unroll
    for (int ni = 0; ni < 8; ++ni) acc[ni] = fz;

    for (int c = 0; c < NC; ++c) {
        if (c) __syncthreads();
#pragma unroll
        for (int it = 0; it < 4; ++it) {
            int s = it * 256 + tid;
            int m = s >> 4, kb = s & 15;
            int slot = kb * 64 + ((m & ~7) | ((m ^ kb) & 7));
            As4[slot] = *(const int4*)(Ain + (size_t)(mb + m) * K + c * 128 + kb * 8);
        }
        {
            const int4* w0 = (const int4*)(Wb + ((size_t)(c * 16)) * 64 * 8);
            const int4* w1 = (const int4*)(Wb + ((size_t)(Kb + c * 16)) * 64 * 8);
#pragma unroll
            for (int it = 0; it < 4; ++it) {
                Ws4[it * 256 + tid] = w0[it * 256 + tid];
                Ws4[1024 + it * 256 + tid] = w1[it * 256 + tid];
            }
        }
        __syncthreads();
#pragma unroll
        for (int kk = 0; kk < 4; ++kk) {
            int kbl = kk * 4 + lg;
            int m0 = w * 16 + lr;
            bf16x8 a0 = *(const bf16x8*)&As4[kbl * 64 + ((m0 & ~7) | ((m0 ^ kbl) & 7))];
#pragma unroll
            for (int ni = 0; ni < 8; ++ni) {
                int nn = lr + 16 * (ni & 3);
                bf16x8 bfr = *(const bf16x8*)&Ws4[(ni >> 2) * 1024 + kbl * 64 +
                                                  ((nn & ~3) | ((nn ^ kbl) & 3))];
                acc[ni] = __builtin_amdgcn_mfma_f32_16x16x32_bf16(a0, bfr, acc[ni], 0, 0, 0);
            }
        }
    }
    float bv[8], gv[8], btv[8];
#pragma unroll
    for (int ni = 0; ni < 8; ++ni) {
        int col = ni * 16 + lr;
        bv[ni] = bias[col]; gv[ni] = g[col]; btv[ni] = bt[col];
    }
#pragma unroll
    for (int r = 0; r < 4; ++r) {
        int row = mb + w * 16 + lg * 4 + r;
        float v[8];
        float s1 = 0.f, s2 = 0.f;
#pragma unroll
        for (int ni = 0; ni < 8; ++ni) {
            v[ni] = acc[ni][r] + bv[ni];
            s1 += v[ni];
            s2 = fmaf(v[ni], v[ni], s2);
        }
#pragma unroll
        for (int off = 8; off >= 1; off >>= 1) {
            s1 += __shfl_xor(s1, off);
            s2 += __shfl_xor(s2, off);
        }
        float mean = s1 * (1.0f / 128.0f);
        float var = s2 * (1.0f / 128.0f) - mean * mean;
        float rstd = rsqrtf(var + 1e-5f);
        int mo = row;
        if (shift) {
            int b = row / 3136, rr = row % 3136;
            int hh = rr / 56 + shift; if (hh >= 56) hh -= 56;
            int ww = rr % 56 + shift; if (ww >= 56) ww -= 56;
            mo = b * 3136 + hh * 56 + ww;
        }
        size_t base = (size_t)mo * 128;
#pragma unroll
        for (int ni = 0; ni < 8; ++ni) {
            int col = ni * 16 + lr;
            float o = resid[base + col] + (v[ni] - mean) * rstd * gv[ni] + btv[ni];
            xout[base + col] = o;
            xoutb[base + col] = f2bf(o);
        }
    }
}

// -------------------- Fused MLP v2: fc1 + GELU + fc2 + LN + residual -------
// xout[row] = resid[row] + LN(gelu(x[row]@W1+b1)@W2+b2). BM=64, 4 waves.
// Swapped-operand fc1: Ht = mfma(W1frag, xfrag) -> lane holds 4 consecutive
// hid cols per tile -> cvt_pk + int2 LDS writes straight into the fc2
// A-image Hw[16 tok][72]. x rows live in registers (no As4 staging).
__global__ __launch_bounds__(256) void k_mlp(
    const short* __restrict__ xbin, const short* __restrict__ W1b,
    const short* __restrict__ W2b, const float* __restrict__ b1,
    const float* __restrict__ b2, const float* __restrict__ g,
    const float* __restrict__ bt, const float* __restrict__ resid,
    float* __restrict__ xout, short* __restrict__ xoutb) {
    __shared__ int4 W1s[1024];       // chunk: [16 kb][64 nn] (swizzled image)
    __shared__ int4 W2s[1024];       // chunk: [2 ntw][8 kb][64 nn]
    __shared__ short Hs[4 * 1152];   // hid: [4 wave][16 tok][72] (wave-private)
    int tid = threadIdx.x;
    int mb = blockIdx.x * 64;
    int w = tid >> 6, l = tid & 63, lr = l & 15, lg = l >> 4;
    const f32x4 fz = {0.f, 0.f, 0.f, 0.f};
    short* Hw = Hs + w * 1152;

    // this wave's 16 token rows as A-fragments (row = lr, k = kk*32+lg*8+e)
    int4 xfrag[4];
#pragma unroll
    for (int kk = 0; kk < 4; ++kk)
        xfrag[kk] = *(const int4*)(xbin + (size_t)(mb + w * 16 + lr) * 128 + kk * 32 + lg * 8);

    f32x4 acc2[8];
#pragma unroll
    for (int ni = 0; ni < 8; ++ni) acc2[ni] = fz;

    for (int c = 0; c < 8; ++c) {
        __syncthreads();   // previous chunk's W reads complete
        {
            const int4* w1src = (const int4*)(W1b + (size_t)c * 8192);
#pragma unroll
            for (int it = 0; it < 4; ++it) W1s[it * 256 + tid] = w1src[it * 256 + tid];
            const int4* w2a = (const int4*)(W2b + (size_t)(c * 8) * 512);
            const int4* w2c = (const int4*)(W2b + (size_t)(64 + c * 8) * 512);
#pragma unroll
            for (int it = 0; it < 2; ++it) {
                W2s[it * 256 + tid] = w2a[it * 256 + tid];
                W2s[512 + it * 256 + tid] = w2c[it * 256 + tid];
            }
        }
        __syncthreads();
        // fc1 (swapped operands): Ht rows = hid cols ct*16+lg*4+r, cols = token lr
        f32x4 a1[4];
#pragma unroll
        for (int ct = 0; ct < 4; ++ct) a1[ct] = fz;
        __builtin_amdgcn_s_setprio(1);
#pragma unroll
        for (int kk = 0; kk < 4; ++kk) {
            int kbl = kk * 4 + lg;
            FragU xa; xa.i4 = xfrag[kk];
#pragma unroll
            for (int ct = 0; ct < 4; ++ct) {
                int nn = lr + 16 * ct;
                bf16x8 w1f = *(const bf16x8*)&W1s[kbl * 64 + ((nn & ~3) | ((nn ^ kbl) & 3))];
                a1[ct] = __builtin_amdgcn_mfma_f32_16x16x32_bf16(w1f, xa.b8, a1[ct], 0, 0, 0);
            }
        }
        __builtin_amdgcn_s_setprio(0);
        // bias + gelu + pack: lane writes 4 consecutive hid cols per tile
#pragma unroll
        for (int ct = 0; ct < 4; ++ct) {
            float4 bb = *(const float4*)(b1 + c * 64 + ct * 16 + lg * 4);
            float h0 = gelu_t(a1[ct][0] + bb.x);
            float h1 = gelu_t(a1[ct][1] + bb.y);
            float h2 = gelu_t(a1[ct][2] + bb.z);
            float h3 = gelu_t(a1[ct][3] + bb.w);
            unsigned p0 = cvt_pk_bf16(h0, h1);
            unsigned p1 = cvt_pk_bf16(h2, h3);
            *(int2*)&Hw[lr * 72 + ct * 16 + lg * 4] = make_int2((int)p0, (int)p1);
        }
        // fc2 accumulate (K=64 chunk), A from wave-private Hw
        __builtin_amdgcn_s_setprio(1);
#pragma unroll
        for (int kc = 0; kc < 2; ++kc) {
            int kbl = kc * 4 + lg;   // local kb 0..7
            FragU ha;
            ha.i4 = *(const int4*)&Hw[lr * 72 + kc * 32 + lg * 8];
#pragma unroll
            for (int ni = 0; ni < 8; ++ni) {
                int nn = lr + 16 * (ni & 3);
                bf16x8 w2f = *(const bf16x8*)&W2s[(ni >> 2) * 512 + kbl * 64 +
                                                  ((nn & ~3) | ((nn ^ kbl) & 3))];
                acc2[ni] = __builtin_amdgcn_mfma_f32_16x16x32_bf16(ha.b8, w2f, acc2[ni], 0, 0, 0);
            }
        }
        __builtin_amdgcn_s_setprio(0);
    }

    // LN + residual epilogue (identical math to k_gemm_ln, shift=0)
    float bv[8], gv[8], btv[8];
#pragma unroll
    for (int ni = 0; ni < 8; ++ni) {
        int col = ni * 16 + lr;
        bv[ni] = b2[col]; gv[ni] = g[col]; btv[ni] = bt[col];
    }
#pragma unroll
    for (int r = 0; r < 4; ++r) {
        int row = mb + w * 16 + lg * 4 + r;
        float v[8];
        float s1 = 0.f, s2 = 0.f;
#pragma unroll
        for (int ni = 0; ni < 8; ++ni) {
            v[ni] = acc2[ni][r] + bv[ni];
            s1 += v[ni];
            s2 = fmaf(v[ni], v[ni], s2);
        }
#pragma unroll
        for (int off = 8; off >= 1; off >>= 1) {
            s1 += __shfl_xor(s1, off);
            s2 += __shfl_xor(s2, off);
        }
        float mean = s1 * (1.0f / 128.0f);
        float var = s2 * (1.0f / 128.0f) - mean * mean;
        float rstd = rsqrtf(var + 1e-5f);
        size_t base = (size_t)row * 128;
#pragma unroll
        for (int ni = 0; ni < 8; ++ni) {
            int col = ni * 16 + lr;
            float o = resid[base + col] + (v[ni] - mean) * rstd * gv[ni] + btv[ni];
            xout[base + col] = o;
            xoutb[base + col] = f2bf(o);
        }
    }
}

// --------------------------- MFMA windowed attention -----------------------
__global__ __launch_bounds__(256) void k_attn(
    const short* __restrict__ qkv, const float* __restrict__ rpb64,
    const float* __restrict__ ls, short* __restrict__ aout, int shift) {
    __shared__ short lds[4 * 3584];
    int wid = blockIdx.x;
    int b = wid >> 6, wrem = wid & 63;
    int wh = wrem >> 3, ww_ = wrem & 7;
    int h = threadIdx.x >> 6;
    int l = threadIdx.x & 63, lr = l & 15, lg = l >> 4;
    short* Pt = lds + h * 3584;              // [16 qrow][72]
    short* Vt = Pt + 1152;                   // [32 d][72]
    float* invks = (float*)(Vt + 2304);      // [64] 1/||k_j||
    int tokbase = b * 3136 + wh * 7 * 56 + ww_ * 7;

    float scale = __expf(fminf(ls[h], 4.6051702f));  // ln(100)
    int4 qf[4], kf[4], vf[4];
    const int4 zero4 = make_int4(0, 0, 0, 0);
#pragma unroll
    for (int t = 0; t < 4; ++t) {
        int i = t * 16 + lr;
        bool valid = (i < 49);
        int tok = tokbase + (i / 7) * 56 + (i % 7);
        const short* base = qkv + (size_t)tok * 384 + h * 32 + lg * 8;
        qf[t] = valid ? *(const int4*)base : zero4;
        kf[t] = valid ? *(const int4*)(base + 128) : zero4;
    }
#pragma unroll
    for (int t = 0; t < 4; ++t) {
        int e = t * 64 + l;
        int j = e >> 2, dq = e & 3;
        if (j < 49) {
            int tok = tokbase + (j / 7) * 56 + (j % 7);
            vf[t] = *(const int4*)(qkv + (size_t)tok * 384 + 256 + h * 32 + dq * 8);
        } else {
            vf[t] = zero4;
        }
    }

    float invq[4];
#pragma unroll
    for (int t = 0; t < 4; ++t) {
        {
            FragU u; u.i4 = qf[t];
            float ss = 0.f;
#pragma unroll
            for (int e = 0; e < 8; ++e) { float x = bf2f(u.u[e]); ss = fmaf(x, x, ss); }
            ss += __shfl_xor(ss, 16);
            ss += __shfl_xor(ss, 32);
            invq[t] = scale / fmaxf(sqrtf(ss), 1e-12f);
        }
        {
            FragU u; u.i4 = kf[t];
            float ss = 0.f;
#pragma unroll
            for (int e = 0; e < 8; ++e) { float x = bf2f(u.u[e]); ss = fmaf(x, x, ss); }
            ss += __shfl_xor(ss, 16);
            ss += __shfl_xor(ss, 32);
            float ik = 1.0f / fmaxf(sqrtf(ss), 1e-12f);
            if (l < 16) invks[t * 16 + l] = ik;
        }
    }

    for (int t = l; t < 480; t += 64) {
        Vt[(t / 15) * 72 + 49 + (t % 15)] = 0;
    }
#pragma unroll
    for (int t = 0; t < 4; ++t) {
        int e = t * 64 + l;
        int j = e >> 2, dq = e & 3;
        if (j < 49) {
            FragU u; u.i4 = vf[t];
#pragma unroll
            for (int ee = 0; ee < 8; ++ee) Vt[(dq * 8 + ee) * 72 + j] = (short)u.u[ee];
        }
    }

    float ika[4][4];
#pragma unroll
    for (int jt = 0; jt < 4; ++jt) {
        float4 v4 = *(const float4*)&invks[jt * 16 + lg * 4];
        ika[jt][0] = v4.x; ika[jt][1] = v4.y; ika[jt][2] = v4.z; ika[jt][3] = v4.w;
    }

    bool edge = (shift != 0) && ((wh == 7) || (ww_ == 7));
    const float* rbase = rpb64 + h * 4096;
    const f32x4 fz = {0.f, 0.f, 0.f, 0.f};
    f32x4 oacc[2][4];
#pragma unroll
    for (int mi = 0; mi < 2; ++mi)
#pragma unroll
        for (int ni = 0; ni < 4; ++ni) oacc[mi][ni] = fz;

#pragma unroll
    for (int qt = 0; qt < 4; ++qt) {
        f32x4 at[4];
        __builtin_amdgcn_s_setprio(1);
#pragma unroll
        for (int jt = 0; jt < 4; ++jt) {
            FragU a; a.i4 = kf[jt];
            FragU bq; bq.i4 = qf[qt];
            at[jt] = __builtin_amdgcn_mfma_f32_16x16x32_bf16(a.b8, bq.b8, fz, 0, 0, 0);
        }
        __builtin_amdgcn_s_setprio(0);

        float iq = invq[qt];
        int qi = qt * 16 + lr;
        int qc = (qi < 49) ? qi : 48;
        int rlq = 0, clq = 0;
        if (edge) {
            rlq = (wh == 7) ? ((qc / 7) < 4 ? 1 : 2) : 0;
            clq = (ww_ == 7) ? ((qc % 7) < 4 ? 1 : 2) : 0;
        }
#pragma unroll
        for (int jt = 0; jt < 4; ++jt) {
            float4 rv = *(const float4*)(rbase + qc * 64 + jt * 16 + lg * 4);
            float rr[4] = {rv.x, rv.y, rv.z, rv.w};
#pragma unroll
            for (int r = 0; r < 4; ++r) {
                float v = fmaf(at[jt][r] * ika[jt][r], iq, rr[r]);
                if (edge) {
                    int j = jt * 16 + lg * 4 + r;
                    int jc = (j < 49) ? j : 48;
                    int rlk = (wh == 7) ? ((jc / 7) < 4 ? 1 : 2) : 0;
                    int clk = (ww_ == 7) ? ((jc % 7) < 4 ? 1 : 2) : 0;
                    if (rlk != rlq || clk != clq) v -= 100.0f;
                }
                at[jt][r] = v;
            }
        }
        float m = -1e30f;
#pragma unroll
        for (int jt = 0; jt < 4; ++jt)
#pragma unroll
            for (int r = 0; r < 4; ++r) m = fmaxf(m, at[jt][r]);
        m = fmaxf(m, __shfl_xor(m, 16));
        m = fmaxf(m, __shfl_xor(m, 32));
        float s = 0.f;
#pragma unroll
        for (int jt = 0; jt < 4; ++jt)
#pragma unroll
            for (int r = 0; r < 4; ++r) {
                float p = __expf(at[jt][r] - m);
                at[jt][r] = p;
                s += p;
            }
        s += __shfl_xor(s, 16);
        s += __shfl_xor(s, 32);
        float inv = 1.0f / s;
#pragma unroll
        for (int jt = 0; jt < 4; ++jt) {
            unsigned lo = cvt_pk_bf16(at[jt][0] * inv, at[jt][1] * inv);
            unsigned hi = cvt_pk_bf16(at[jt][2] * inv, at[jt][3] * inv);
            *(int2*)&Pt[lr * 72 + jt * 16 + lg * 4] = make_int2((int)lo, (int)hi);
        }
        __builtin_amdgcn_s_setprio(1);
#pragma unroll
        for (int kc = 0; kc < 2; ++kc) {
            FragU pb;
            pb.i4 = *(const int4*)&Pt[lr * 72 + kc * 32 + lg * 8];
#pragma unroll
            for (int mi = 0; mi < 2; ++mi) {
                FragU va;
                va.i4 = *(const int4*)&Vt[(mi * 16 + lr) * 72 + kc * 32 + lg * 8];
                oacc[mi][qt] = __builtin_amdgcn_mfma_f32_16x16x32_bf16(
                    va.b8, pb.b8, oacc[mi][qt], 0, 0, 0);
            }
        }
        __builtin_amdgcn_s_setprio(0);
    }

#pragma unroll
    for (int ni = 0; ni < 4; ++ni) {
        int qrow = ni * 16 + lr;
        if (qrow < 49) {
            int tok = tokbase + (qrow / 7) * 56 + (qrow % 7);
#pragma unroll
            for (int mi = 0; mi < 2; ++mi) {
                unsigned lo = cvt_pk_bf16(oacc[mi][ni][0], oacc[mi][ni][1]);
                unsigned hi = cvt_pk_bf16(oacc[mi][ni][2], oacc[mi][ni][3]);
                *(int2*)&aout[(size_t)tok * 128 + h * 32 + mi * 16 + lg * 4] =
                    make_int2((int)lo, (int)hi);
            }
        }
    }
}

// ------------- PatchMerging gather + LN -> bf16 rows [25088][512] ----------
__global__ __launch_bounds__(256) void k_pmln(
    const float* __restrict__ x, const float* __restrict__ g,
    const float* __restrict__ bt, short* __restrict__ outb) {
    int m2 = blockIdx.x * 4 + (threadIdx.x >> 6);
    int l = threadIdx.x & 63;
    int b = m2 / 784, r = m2 % 784;
    int h2 = r / 28, w2 = r % 28;
    int q0 = l * 8;
    int i2 = q0 >> 8, j2 = (q0 >> 7) & 1, c = q0 & 127;
    const float* src = x + (size_t)((b * 56 + 2 * h2 + i2) * 56 + 2 * w2 + j2) * 128 + c;
    float4 f0 = *(const float4*)src;
    float4 f1 = *(const float4*)(src + 4);
    float v[8] = {f0.x, f0.y, f0.z, f0.w, f1.x, f1.y, f1.z, f1.w};
    float s1 = 0.f, s2 = 0.f;
#pragma unroll
    for (int e = 0; e < 8; ++e) { s1 += v[e]; s2 = fmaf(v[e], v[e], s2); }
#pragma unroll
    for (int off = 32; off >= 1; off >>= 1) {
        s1 += __shfl_xor(s1, off);
        s2 += __shfl_xor(s2, off);
    }
    float mean = s1 * (1.0f / 512.0f);
    float var = s2 * (1.0f / 512.0f) - mean * mean;
    float rstd = rsqrtf(var + 1e-5f);
    union { int4 i4; short s8[8]; } u;
#pragma unroll
    for (int e = 0; e < 8; ++e)
        u.s8[e] = f2bf((v[e] - mean) * rstd * g[q0 + e] + bt[q0 + e]);
    *(int4*)(outb + (size_t)m2 * 512 + q0) = u.i4;
}

// ---------------------------------------------------------------------------
extern "C" void kernel_launch(void* const* d_in, const int* in_sizes, int n_in,
                              void* d_out, int out_size, void* d_ws, size_t ws_size,
                              hipStream_t stream) {
    const float* x_in   = (const float*)d_in[0];
    const float* qkv_w  = (const float*)d_in[1];
    const float* q_bias = (const float*)d_in[2];
    const float* v_bias = (const float*)d_in[3];
    const float* lscale = (const float*)d_in[4];
    const float* cpb_w1 = (const float*)d_in[5];
    const float* cpb_b1 = (const float*)d_in[6];
    const float* cpb_w2 = (const float*)d_in[7];
    const float* proj_w = (const float*)d_in[8];
    const float* proj_b = (const float*)d_in[9];
    const float* n1g    = (const float*)d_in[10];
    const float* n1b    = (const float*)d_in[11];
    const float* mw1    = (const float*)d_in[12];
    const float* mb1    = (const float*)d_in[13];
    const float* mw2    = (const float*)d_in[14];
    const float* mb2    = (const float*)d_in[15];
    const float* n2g    = (const float*)d_in[16];
    const float* n2b    = (const float*)d_in[17];
    const float* pmg    = (const float*)d_in[18];
    const float* pmb    = (const float*)d_in[19];
    const float* pmw    = (const float*)d_in[20];
    float* out = (float*)d_out;

    float* wsf     = (float*)d_ws;
    float* xcur    = wsf;
    float* R1      = wsf + (size_t)12845056;
    short* qkvb    = (short*)R1;
    short* attnout = (short*)(R1 + (size_t)19267584);   // kTok*128 bf16
    short* pmin    = (short*)R1;                        // 25088*512 bf16
    short* xb      = (short*)(R1 + (size_t)25690112);   // kTok*128 bf16
    float* wtail   = R1 + (size_t)38535168;
    short* wqkvb   = (short*)wtail;          // 49,152 bf16
    short* wprojb  = wqkvb + 49152;          // 16,384
    short* wm1b    = wprojb + 16384;         // 65,536
    short* wm2b    = wm1b + 65536;           // 65,536
    short* wpmb    = wm2b + 65536;           // 131,072
    float* out169  = wtail + 163840;
    float* rpb64   = out169 + 704;

    k_cvtx<<<6272, 256, 0, stream>>>(x_in, xb);

    for (int i = 0; i < 2; ++i) {
        int shift = i ? 3 : 0;
        const float* xi = (i == 0) ? x_in : xcur;
        k_cpb<<<169, 256, 0, stream>>>(cpb_w1 + i * 1024, cpb_b1 + i * 512,
                                       cpb_w2 + i * 2048, out169);
        k_rpb<<<64, 256, 0, stream>>>(out169, rpb64);
        k_cvtw<<<24, 256, 0, stream>>>(qkv_w + i * 49152, wqkvb, 16, 384);
        k_cvtw<<<8, 256, 0, stream>>>(proj_w + i * 16384, wprojb, 16, 128);
        k_cvtw<<<32, 256, 0, stream>>>(mw1 + i * 65536, wm1b, 16, 512);
        k_cvtw<<<32, 256, 0, stream>>>(mw2 + i * 65536, wm2b, 64, 128);

        k_gemm<128, 1, 6><<<4704, 256, 0, stream>>>(
            xb, wqkvb, q_bias + i * 128, v_bias + i * 128, qkvb, 384, shift);
        k_attn<<<2048, 256, 0, stream>>>(
            qkvb, rpb64, lscale + i * 4, attnout, shift);
        k_gemm_ln<128><<<1568, 256, 0, stream>>>(
            attnout, wprojb, proj_b + i * 128, n1g + i * 128, n1b + i * 128,
            xi, xcur, xb, shift);
        k_mlp<<<1568, 256, 0, stream>>>(
            xb, wm1b, wm2b, mb1 + i * 512, mb2 + i * 128,
            n2g + i * 128, n2b + i * 128, xcur, xcur, xb);
    }
    k_cvtw<<<64, 256, 0, stream>>>(pmw, wpmb, 64, 256);
    k_pmln<<<6272, 256, 0, stream>>>(xcur, pmg, pmb, pmin);
    k_gemm<512, 0, 4><<<784, 256, 0, stream>>>(
        pmin, wpmb, nullptr, nullptr, out, 256, 0);
}

// Round 11
// 429.549 us; speedup vs baseline: 1.1094x; 1.0309x over previous
//
#include <hip/hip_runtime.h>
#include <math.h>

// ---------------------------------------------------------------------------
// SwinV2 stage: B=32, H=W=56, C=128, NH=4, hd=32, WS=7, N=49, DEPTH=2, shift=3
// Round 11: k_mlp v3 — 32 rows/wave (W-fragment LDS reads amortized over
// 2 MFMA), lean 8-inst GELU (exp2 + v_rcp, no IEEE div). Rest unchanged.
// ---------------------------------------------------------------------------

namespace {
constexpr int kTok = 32 * 56 * 56;   // 100352 tokens
}

typedef __attribute__((ext_vector_type(8))) short bf16x8;
typedef __attribute__((ext_vector_type(4))) float f32x4;

union FragU {
    int4 i4;
    bf16x8 b8;
    unsigned short u[8];
};

__device__ __forceinline__ short f2bf(float f) {
    unsigned u = __float_as_uint(f);
    return (short)((u + 0x7FFFu + ((u >> 16) & 1u)) >> 16);
}
__device__ __forceinline__ float bf2f(unsigned short u) {
    return __uint_as_float(((unsigned)u) << 16);
}
__device__ __forceinline__ unsigned cvt_pk_bf16(float a, float b) {
    unsigned r;
    asm("v_cvt_pk_bf16_f32 %0, %1, %2" : "=v"(r) : "v"(a), "v"(b));
    return r;
}
// tanh-form GELU, 8 insts: x2, c*x2, fma -> t0, mul-const, exp2, add, rcp, fma
__device__ __forceinline__ float gelu_t(float x) {
    float x2 = x * x;
    float t0 = fmaf(0.044715f * x2, x, x);
    float e = exp2f(2.3022227f * t0);           // exp(2*0.79788456*t0)
    float r = __builtin_amdgcn_rcpf(e + 1.0f);
    return fmaf(-x, r, x);                      // x * (1 - 1/(e+1))
}

// --------------------------- CPB MLP (tiny) --------------------------------
__global__ __launch_bounds__(256) void k_cpb(
    const float* __restrict__ w1, const float* __restrict__ b1,
    const float* __restrict__ w2, float* __restrict__ out169) {
    int t = blockIdx.x;  // 0..168
    int ia = t / 13, ib = t % 13;
    float r0 = (float)(ia - 6) * (8.0f / 6.0f);
    float s0 = (r0 > 0.f) ? 1.f : (r0 < 0.f ? -1.f : 0.f);
    float t0 = s0 * log2f(fabsf(r0) + 1.0f) * (1.0f / 3.0f);
    float r1 = (float)(ib - 6) * (8.0f / 6.0f);
    float s1 = (r1 > 0.f) ? 1.f : (r1 < 0.f ? -1.f : 0.f);
    float t1 = s1 * log2f(fabsf(r1) + 1.0f) * (1.0f / 3.0f);

    int tid = threadIdx.x;
    float p0 = 0, p1 = 0, p2 = 0, p3 = 0;
    for (int c = tid; c < 512; c += 256) {
        float hv = fmaxf(t0 * w1[c] + t1 * w1[512 + c] + b1[c], 0.0f);
        p0 += hv * w2[c * 4 + 0];
        p1 += hv * w2[c * 4 + 1];
        p2 += hv * w2[c * 4 + 2];
        p3 += hv * w2[c * 4 + 3];
    }
    __shared__ float red[256][4];
    red[tid][0] = p0; red[tid][1] = p1; red[tid][2] = p2; red[tid][3] = p3;
    __syncthreads();
    for (int s = 128; s > 0; s >>= 1) {
        if (tid < s) {
            red[tid][0] += red[tid + s][0];
            red[tid][1] += red[tid + s][1];
            red[tid][2] += red[tid + s][2];
            red[tid][3] += red[tid + s][3];
        }
        __syncthreads();
    }
    if (tid < 4) out169[t * 4 + tid] = red[0][tid];
}

// rpb64[h][qrow64][krow64]; krow>=49 -> -30000 (k-pad baked in)
__global__ void k_rpb(const float* __restrict__ out169, float* __restrict__ rpb64) {
    int e = blockIdx.x * 256 + threadIdx.x;
    if (e >= 4 * 64 * 64) return;
    int h = e >> 12, r = e & 4095;
    int i = r >> 6, j = r & 63;
    float val;
    if (j >= 49) {
        val = -30000.0f;
    } else if (i >= 49) {
        val = 0.0f;
    } else {
        int dp = i / 7 - j / 7 + 6;
        int dq = i % 7 - j % 7 + 6;
        float v = out169[(dp * 13 + dq) * 4 + h];
        val = 16.0f / (1.0f + expf(-v));
    }
    rpb64[e] = val;
}

// ------------------- weight fp32 -> bf16 tiled image -----------------------
// Logical slot (nt*Kb + kb)*64 + nn holds W[kb*8+e][nt*64+nn], e=0..7.
// Stored at physical nn' = (nn & ~3) | ((nn ^ kb) & 3).
__global__ __launch_bounds__(256) void k_cvtw(
    const float* __restrict__ W, short* __restrict__ Wb, int Kb, int N) {
    int slt = blockIdx.x * 256 + threadIdx.x;
    if (slt >= Kb * N) return;
    int nn = slt & 63;
    int tmp = slt >> 6;
    int kb = tmp % Kb;
    int nt = tmp / Kb;
    int n = nt * 64 + nn;
    int k0 = kb * 8;
    union { int4 i4; short s8[8]; } u;
#pragma unroll
    for (int e = 0; e < 8; ++e) u.s8[e] = f2bf(W[(size_t)(k0 + e) * N + n]);
    int nns = (nn & ~3) | ((nn ^ kb) & 3);
    *(int4*)(Wb + (((size_t)tmp) * 64 + nns) * 8) = u.i4;
}

// ------------------- activation fp32 -> bf16 rows --------------------------
__global__ __launch_bounds__(256) void k_cvtx(
    const float* __restrict__ x, short* __restrict__ xb) {
    size_t e = ((size_t)blockIdx.x * 256 + threadIdx.x) * 8;
    const float* src = x + e;
    float4 f0 = *(const float4*)src;
    float4 f1 = *(const float4*)(src + 4);
    union { int4 i4; short s8[8]; } u;
    u.s8[0] = f2bf(f0.x); u.s8[1] = f2bf(f0.y);
    u.s8[2] = f2bf(f0.z); u.s8[3] = f2bf(f0.w);
    u.s8[4] = f2bf(f1.x); u.s8[5] = f2bf(f1.y);
    u.s8[6] = f2bf(f1.z); u.s8[7] = f2bf(f1.w);
    *(int4*)(xb + e) = u.i4;
}

// --------------------------- MFMA GEMM (bf16 A) ----------------------------
// EPI: 0 = raw fp32; 1 = qkv bias -> bf16 out (stride 384), roll on A.
template <int K, int EPI, int NT>
__global__ __launch_bounds__(256) void k_gemm(
    const short* __restrict__ Ain, const short* __restrict__ Wb,
    const float* __restrict__ bias0, const float* __restrict__ bias1,
    void* __restrict__ Out, int ostride, int shift) {
    constexpr int Kb = K / 8;
    constexpr int NC = K / 128;
    __shared__ int4 As4[2048];  // [16 kb][128 m], XOR-swizzled (8-wide)
    __shared__ int4 Ws4[1024];  // [16 kb][64 nn], XOR-swizzled (4-wide, in image)
    int tid = threadIdx.x;
    int nwg = gridDim.x;
    int chunk = nwg >> 3;
    int lid = (blockIdx.x & 7) * chunk + (blockIdx.x >> 3);
    int mt = lid / NT, nt = lid - mt * NT;
    int mb = mt * 128;
    int w = tid >> 6, l = tid & 63, lr = l & 15, lg = l >> 4;
    const f32x4 fz = {0.f, 0.f, 0.f, 0.f};
    f32x4 acc[2][4];
#pragma unroll
    for (int mi = 0; mi < 2; ++mi)
#pragma unroll
        for (int ni = 0; ni < 4; ++ni) acc[mi][ni] = fz;

    for (int c = 0; c < NC; ++c) {
        if (c) __syncthreads();
#pragma unroll
        for (int it = 0; it < 8; ++it) {
            int s = it * 256 + tid;
            int m = s >> 4, kb = s & 15;
            int gm = mb + m;
            if (EPI == 1 && shift) {
                int b = gm / 3136, r = gm % 3136;
                int hh = r / 56 + shift; if (hh >= 56) hh -= 56;
                int ww = r % 56 + shift; if (ww >= 56) ww -= 56;
                gm = b * 3136 + hh * 56 + ww;
            }
            int slot = kb * 128 + ((m & ~7) | ((m ^ kb) & 7));
            As4[slot] = *(const int4*)(Ain + (size_t)gm * K + c * 128 + kb * 8);
        }
        {
            const int4* wsrc = (const int4*)(Wb + ((size_t)nt * Kb + c * 16) * 64 * 8);
#pragma unroll
            for (int it = 0; it < 4; ++it) Ws4[it * 256 + tid] = wsrc[it * 256 + tid];
        }
        __syncthreads();
#pragma unroll
        for (int kk = 0; kk < 4; ++kk) {
            int kbl = kk * 4 + lg;
            int m0 = w * 32 + lr;
            bf16x8 a0 = *(const bf16x8*)&As4[kbl * 128 + ((m0 & ~7) | ((m0 ^ kbl) & 7))];
            int m1 = m0 + 16;
            bf16x8 a1 = *(const bf16x8*)&As4[kbl * 128 + ((m1 & ~7) | ((m1 ^ kbl) & 7))];
#pragma unroll
            for (int ni = 0; ni < 4; ++ni) {
                int nn = lr + 16 * ni;
                bf16x8 bfr = *(const bf16x8*)&Ws4[kbl * 64 + ((nn & ~3) | ((nn ^ kbl) & 3))];
                acc[0][ni] = __builtin_amdgcn_mfma_f32_16x16x32_bf16(a0, bfr, acc[0][ni], 0, 0, 0);
                acc[1][ni] = __builtin_amdgcn_mfma_f32_16x16x32_bf16(a1, bfr, acc[1][ni], 0, 0, 0);
            }
        }
    }
#pragma unroll
    for (int ni = 0; ni < 4; ++ni) {
        int col = nt * 64 + ni * 16 + lr;
        float bv = 0.f;
        if (EPI == 1) bv = (col < 128) ? bias0[col] : ((col < 256) ? 0.f : bias1[col - 256]);
#pragma unroll
        for (int mi = 0; mi < 2; ++mi) {
#pragma unroll
            for (int r = 0; r < 4; ++r) {
                int row = mb + w * 32 + mi * 16 + lg * 4 + r;
                float v = acc[mi][ni][r] + bv;
                if (EPI == 0) {
                    ((float*)Out)[(size_t)row * ostride + col] = v;
                } else {
                    ((short*)Out)[(size_t)row * 384 + col] = f2bf(v);
                }
            }
        }
    }
}

// ------------- MFMA GEMM + bias + LN + residual (+roll-back) ---------------
// Used for the attention projection (K=128).
template <int K>
__global__ __launch_bounds__(256) void k_gemm_ln(
    const short* __restrict__ Ain, const short* __restrict__ Wb,
    const float* __restrict__ bias, const float* __restrict__ g,
    const float* __restrict__ bt, const float* __restrict__ resid,
    float* __restrict__ xout, short* __restrict__ xoutb, int shift) {
    constexpr int Kb = K / 8;
    constexpr int NC = K / 128;
    __shared__ int4 As4[1024];  // [16 kb][64 m]
    __shared__ int4 Ws4[2048];  // [2 ntw][16 kb][64 nn]
    int tid = threadIdx.x;
    int mb = blockIdx.x * 64;
    int w = tid >> 6, l = tid & 63, lr = l & 15, lg = l >> 4;
    const f32x4 fz = {0.f, 0.f, 0.f, 0.f};
    f32x4 acc[8];
#pragma unroll
    for (int ni = 0; ni < 8; ++ni) acc[ni] = fz;

    for (int c = 0; c < NC; ++c) {
        if (c) __syncthreads();
#pragma unroll
        for (int it = 0; it < 4; ++it) {
            int s = it * 256 + tid;
            int m = s >> 4, kb = s & 15;
            int slot = kb * 64 + ((m & ~7) | ((m ^ kb) & 7));
            As4[slot] = *(const int4*)(Ain + (size_t)(mb + m) * K + c * 128 + kb * 8);
        }
        {
            const int4* w0 = (const int4*)(Wb + ((size_t)(c * 16)) * 64 * 8);
            const int4* w1 = (const int4*)(Wb + ((size_t)(Kb + c * 16)) * 64 * 8);
#pragma unroll
            for (int it = 0; it < 4; ++it) {
                Ws4[it * 256 + tid] = w0[it * 256 + tid];
                Ws4[1024 + it * 256 + tid] = w1[it * 256 + tid];
            }
        }
        __syncthreads();
#pragma unroll
        for (int kk = 0; kk < 4; ++kk) {
            int kbl = kk * 4 + lg;
            int m0 = w * 16 + lr;
            bf16x8 a0 = *(const bf16x8*)&As4[kbl * 64 + ((m0 & ~7) | ((m0 ^ kbl) & 7))];
#pragma unroll
            for (int ni = 0; ni < 8; ++ni) {
                int nn = lr + 16 * (ni & 3);
                bf16x8 bfr = *(const bf16x8*)&Ws4[(ni >> 2) * 1024 + kbl * 64 +
                                                  ((nn & ~3) | ((nn ^ kbl) & 3))];
                acc[ni] = __builtin_amdgcn_mfma_f32_16x16x32_bf16(a0, bfr, acc[ni], 0, 0, 0);
            }
        }
    }
    float bv[8], gv[8], btv[8];
#pragma unroll
    for (int ni = 0; ni < 8; ++ni) {
        int col = ni * 16 + lr;
        bv[ni] = bias[col]; gv[ni] = g[col]; btv[ni] = bt[col];
    }
#pragma unroll
    for (int r = 0; r < 4; ++r) {
        int row = mb + w * 16 + lg * 4 + r;
        float v[8];
        float s1 = 0.f, s2 = 0.f;
#pragma unroll
        for (int ni = 0; ni < 8; ++ni) {
            v[ni] = acc[ni][r] + bv[ni];
            s1 += v[ni];
            s2 = fmaf(v[ni], v[ni], s2);
        }
#pragma unroll
        for (int off = 8; off >= 1; off >>= 1) {
            s1 += __shfl_xor(s1, off);
            s2 += __shfl_xor(s2, off);
        }
        float mean = s1 * (1.0f / 128.0f);
        float var = s2 * (1.0f / 128.0f) - mean * mean;
        float rstd = rsqrtf(var + 1e-5f);
        int mo = row;
        if (shift) {
            int b = row / 3136, rr = row % 3136;
            int hh = rr / 56 + shift; if (hh >= 56) hh -= 56;
            int ww = rr % 56 + shift; if (ww >= 56) ww -= 56;
            mo = b * 3136 + hh * 56 + ww;
        }
        size_t base = (size_t)mo * 128;
#pragma unroll
        for (int ni = 0; ni < 8; ++ni) {
            int col = ni * 16 + lr;
            float o = resid[base + col] + (v[ni] - mean) * rstd * gv[ni] + btv[ni];
            xout[base + col] = o;
            xoutb[base + col] = f2bf(o);
        }
    }
}

// -------------------- Fused MLP v3: fc1 + GELU + fc2 + LN + residual -------
// BM=128, 4 waves x 32 rows. W-fragment LDS reads shared across the 2
// row-groups (mi) -> 36 ds_read_b128 per 64 MFMA per chunk.
__global__ __launch_bounds__(256) void k_mlp(
    const short* __restrict__ xbin, const short* __restrict__ W1b,
    const short* __restrict__ W2b, const float* __restrict__ b1,
    const float* __restrict__ b2, const float* __restrict__ g,
    const float* __restrict__ bt, const float* __restrict__ resid,
    float* __restrict__ xout, short* __restrict__ xoutb) {
    __shared__ int4 W1s[1024];       // chunk: [16 kb][64 nn] (swizzled image)
    __shared__ int4 W2s[1024];       // chunk: [2 ntw][8 kb][64 nn]
    __shared__ short Hs[4 * 2304];   // hid: [4 wave][32 tok][72] (wave-private)
    int tid = threadIdx.x;
    int mb = blockIdx.x * 128;
    int w = tid >> 6, l = tid & 63, lr = l & 15, lg = l >> 4;
    const f32x4 fz = {0.f, 0.f, 0.f, 0.f};
    short* Hw = Hs + w * 2304;

    // this wave's 32 token rows as two A-frag sets (row = w*32 + mi*16 + lr)
    int4 xfrag[2][4];
#pragma unroll
    for (int mi = 0; mi < 2; ++mi)
#pragma unroll
        for (int kk = 0; kk < 4; ++kk)
            xfrag[mi][kk] = *(const int4*)(
                xbin + (size_t)(mb + w * 32 + mi * 16 + lr) * 128 + kk * 32 + lg * 8);

    f32x4 acc2[2][8];
#pragma unroll
    for (int mi = 0; mi < 2; ++mi)
#pragma unroll
        for (int ni = 0; ni < 8; ++ni) acc2[mi][ni] = fz;

    for (int c = 0; c < 8; ++c) {
        __syncthreads();   // previous chunk's W reads complete
        {
            const int4* w1src = (const int4*)(W1b + (size_t)c * 8192);
#pragma unroll
            for (int it = 0; it < 4; ++it) W1s[it * 256 + tid] = w1src[it * 256 + tid];
            const int4* w2a = (const int4*)(W2b + (size_t)(c * 8) * 512);
            const int4* w2c = (const int4*)(W2b + (size_t)(64 + c * 8) * 512);
#pragma unroll
            for (int it = 0; it < 2; ++it) {
                W2s[it * 256 + tid] = w2a[it * 256 + tid];
                W2s[512 + it * 256 + tid] = w2c[it * 256 + tid];
            }
        }
        __syncthreads();
        // fc1 (swapped operands): Ht rows = hid cols, cols = token (lr)
        f32x4 a1[2][4];
#pragma unroll
        for (int mi = 0; mi < 2; ++mi)
#pragma unroll
            for (int ct = 0; ct < 4; ++ct) a1[mi][ct] = fz;
        __builtin_amdgcn_s_setprio(1);
#pragma unroll
        for (int kk = 0; kk < 4; ++kk) {
            int kbl = kk * 4 + lg;
            FragU xa0; xa0.i4 = xfrag[0][kk];
            FragU xa1; xa1.i4 = xfrag[1][kk];
#pragma unroll
            for (int ct = 0; ct < 4; ++ct) {
                int nn = lr + 16 * ct;
                bf16x8 w1f = *(const bf16x8*)&W1s[kbl * 64 + ((nn & ~3) | ((nn ^ kbl) & 3))];
                a1[0][ct] = __builtin_amdgcn_mfma_f32_16x16x32_bf16(w1f, xa0.b8, a1[0][ct], 0, 0, 0);
                a1[1][ct] = __builtin_amdgcn_mfma_f32_16x16x32_bf16(w1f, xa1.b8, a1[1][ct], 0, 0, 0);
            }
        }
        __builtin_amdgcn_s_setprio(0);
        // bias + gelu + pack: lane writes 4 consecutive hid cols per (mi,ct)
#pragma unroll
        for (int mi = 0; mi < 2; ++mi) {
#pragma unroll
            for (int ct = 0; ct < 4; ++ct) {
                float4 bb = *(const float4*)(b1 + c * 64 + ct * 16 + lg * 4);
                float h0 = gelu_t(a1[mi][ct][0] + bb.x);
                float h1 = gelu_t(a1[mi][ct][1] + bb.y);
                float h2 = gelu_t(a1[mi][ct][2] + bb.z);
                float h3 = gelu_t(a1[mi][ct][3] + bb.w);
                unsigned p0 = cvt_pk_bf16(h0, h1);
                unsigned p1 = cvt_pk_bf16(h2, h3);
                *(int2*)&Hw[(mi * 16 + lr) * 72 + ct * 16 + lg * 4] =
                    make_int2((int)p0, (int)p1);
            }
        }
        // fc2 accumulate (K=64 chunk), A from wave-private Hw
        __builtin_amdgcn_s_setprio(1);
#pragma unroll
        for (int kc = 0; kc < 2; ++kc) {
            int kbl = kc * 4 + lg;   // local kb 0..7
            FragU ha0; ha0.i4 = *(const int4*)&Hw[lr * 72 + kc * 32 + lg * 8];
            FragU ha1; ha1.i4 = *(const int4*)&Hw[(16 + lr) * 72 + kc * 32 + lg * 8];
#pragma unroll
            for (int ni = 0; ni < 8; ++ni) {
                int nn = lr + 16 * (ni & 3);
                bf16x8 w2f = *(const bf16x8*)&W2s[(ni >> 2) * 512 + kbl * 64 +
                                                  ((nn & ~3) | ((nn ^ kbl) & 3))];
                acc2[0][ni] = __builtin_amdgcn_mfma_f32_16x16x32_bf16(ha0.b8, w2f, acc2[0][ni], 0, 0, 0);
                acc2[1][ni] = __builtin_amdgcn_mfma_f32_16x16x32_bf16(ha1.b8, w2f, acc2[1][ni], 0, 0, 0);
            }
        }
        __builtin_amdgcn_s_setprio(0);
    }

    // LN + residual epilogue (identical math to k_gemm_ln, shift=0)
    float bv[8], gv[8], btv[8];
#pragma unroll
    for (int ni = 0; ni < 8; ++ni) {
        int col = ni * 16 + lr;
        bv[ni] = b2[col]; gv[ni] = g[col]; btv[ni] = bt[col];
    }
#pragma unroll
    for (int mi = 0; mi < 2; ++mi) {
#pragma unroll
        for (int r = 0; r < 4; ++r) {
            int row = mb + w * 32 + mi * 16 + lg * 4 + r;
            float v[8];
            float s1 = 0.f, s2 = 0.f;
#pragma unroll
            for (int ni = 0; ni < 8; ++ni) {
                v[ni] = acc2[mi][ni][r] + bv[ni];
                s1 += v[ni];
                s2 = fmaf(v[ni], v[ni], s2);
            }
#pragma unroll
            for (int off = 8; off >= 1; off >>= 1) {
                s1 += __shfl_xor(s1, off);
                s2 += __shfl_xor(s2, off);
            }
            float mean = s1 * (1.0f / 128.0f);
            float var = s2 * (1.0f / 128.0f) - mean * mean;
            float rstd = rsqrtf(var + 1e-5f);
            size_t base = (size_t)row * 128;
#pragma unroll
            for (int ni = 0; ni < 8; ++ni) {
                int col = ni * 16 + lr;
                float o = resid[base + col] + (v[ni] - mean) * rstd * gv[ni] + btv[ni];
                xout[base + col] = o;
                xoutb[base + col] = f2bf(o);
            }
        }
    }
}

// --------------------------- MFMA windowed attention -----------------------
__global__ __launch_bounds__(256) void k_attn(
    const short* __restrict__ qkv, const float* __restrict__ rpb64,
    const float* __restrict__ ls, short* __restrict__ aout, int shift) {
    __shared__ short lds[4 * 3584];
    int wid = blockIdx.x;
    int b = wid >> 6, wrem = wid & 63;
    int wh = wrem >> 3, ww_ = wrem & 7;
    int h = threadIdx.x >> 6;
    int l = threadIdx.x & 63, lr = l & 15, lg = l >> 4;
    short* Pt = lds + h * 3584;              // [16 qrow][72]
    short* Vt = Pt + 1152;                   // [32 d][72]
    float* invks = (float*)(Vt + 2304);      // [64] 1/||k_j||
    int tokbase = b * 3136 + wh * 7 * 56 + ww_ * 7;

    float scale = __expf(fminf(ls[h], 4.6051702f));  // ln(100)
    int4 qf[4], kf[4], vf[4];
    const int4 zero4 = make_int4(0, 0, 0, 0);
#pragma unroll
    for (int t = 0; t < 4; ++t) {
        int i = t * 16 + lr;
        bool valid = (i < 49);
        int tok = tokbase + (i / 7) * 56 + (i % 7);
        const short* base = qkv + (size_t)tok * 384 + h * 32 + lg * 8;
        qf[t] = valid ? *(const int4*)base : zero4;
        kf[t] = valid ? *(const int4*)(base + 128) : zero4;
    }
#pragma unroll
    for (int t = 0; t < 4; ++t) {
        int e = t * 64 + l;
        int j = e >> 2, dq = e & 3;
        if (j < 49) {
            int tok = tokbase + (j / 7) * 56 + (j % 7);
            vf[t] = *(const int4*)(qkv + (size_t)tok * 384 + 256 + h * 32 + dq * 8);
        } else {
            vf[t] = zero4;
        }
    }

    float invq[4];
#pragma unroll
    for (int t = 0; t < 4; ++t) {
        {
            FragU u; u.i4 = qf[t];
            float ss = 0.f;
#pragma unroll
            for (int e = 0; e < 8; ++e) { float x = bf2f(u.u[e]); ss = fmaf(x, x, ss); }
            ss += __shfl_xor(ss, 16);
            ss += __shfl_xor(ss, 32);
            invq[t] = scale / fmaxf(sqrtf(ss), 1e-12f);
        }
        {
            FragU u; u.i4 = kf[t];
            float ss = 0.f;
#pragma unroll
            for (int e = 0; e < 8; ++e) { float x = bf2f(u.u[e]); ss = fmaf(x, x, ss); }
            ss += __shfl_xor(ss, 16);
            ss += __shfl_xor(ss, 32);
            float ik = 1.0f / fmaxf(sqrtf(ss), 1e-12f);
            if (l < 16) invks[t * 16 + l] = ik;
        }
    }

    for (int t = l; t < 480; t += 64) {
        Vt[(t / 15) * 72 + 49 + (t % 15)] = 0;
    }
#pragma unroll
    for (int t = 0; t < 4; ++t) {
        int e = t * 64 + l;
        int j = e >> 2, dq = e & 3;
        if (j < 49) {
            FragU u; u.i4 = vf[t];
#pragma unroll
            for (int ee = 0; ee < 8; ++ee) Vt[(dq * 8 + ee) * 72 + j] = (short)u.u[ee];
        }
    }

    float ika[4][4];
#pragma unroll
    for (int jt = 0; jt < 4; ++jt) {
        float4 v4 = *(const float4*)&invks[jt * 16 + lg * 4];
        ika[jt][0] = v4.x; ika[jt][1] = v4.y; ika[jt][2] = v4.z; ika[jt][3] = v4.w;
    }

    bool edge = (shift != 0) && ((wh == 7) || (ww_ == 7));
    const float* rbase = rpb64 + h * 4096;
    const f32x4 fz = {0.f, 0.f, 0.f, 0.f};
    f32x4 oacc[2][4];
#pragma unroll
    for (int mi = 0; mi < 2; ++mi)
#pragma unroll
        for (int ni = 0; ni < 4; ++ni) oacc[mi][ni] = fz;

#pragma unroll
    for (int qt = 0; qt < 4; ++qt) {
        f32x4 at[4];
        __builtin_amdgcn_s_setprio(1);
#pragma unroll
        for (int jt = 0; jt < 4; ++jt) {
            FragU a; a.i4 = kf[jt];
            FragU bq; bq.i4 = qf[qt];
            at[jt] = __builtin_amdgcn_mfma_f32_16x16x32_bf16(a.b8, bq.b8, fz, 0, 0, 0);
        }
        __builtin_amdgcn_s_setprio(0);

        float iq = invq[qt];
        int qi = qt * 16 + lr;
        int qc = (qi < 49) ? qi : 48;
        int rlq = 0, clq = 0;
        if (edge) {
            rlq = (wh == 7) ? ((qc / 7) < 4 ? 1 : 2) : 0;
            clq = (ww_ == 7) ? ((qc % 7) < 4 ? 1 : 2) : 0;
        }
#pragma unroll
        for (int jt = 0; jt < 4; ++jt) {
            float4 rv = *(const float4*)(rbase + qc * 64 + jt * 16 + lg * 4);
            float rr[4] = {rv.x, rv.y, rv.z, rv.w};
#pragma unroll
            for (int r = 0; r < 4; ++r) {
                float v = fmaf(at[jt][r] * ika[jt][r], iq, rr[r]);
                if (edge) {
                    int j = jt * 16 + lg * 4 + r;
                    int jc = (j < 49) ? j : 48;
                    int rlk = (wh == 7) ? ((jc / 7) < 4 ? 1 : 2) : 0;
                    int clk = (ww_ == 7) ? ((jc % 7) < 4 ? 1 : 2) : 0;
                    if (rlk != rlq || clk != clq) v -= 100.0f;
                }
                at[jt][r] = v;
            }
        }
        float m = -1e30f;
#pragma unroll
        for (int jt = 0; jt < 4; ++jt)
#pragma unroll
            for (int r = 0; r < 4; ++r) m = fmaxf(m, at[jt][r]);
        m = fmaxf(m, __shfl_xor(m, 16));
        m = fmaxf(m, __shfl_xor(m, 32));
        float s = 0.f;
#pragma unroll
        for (int jt = 0; jt < 4; ++jt)
#pragma unroll
            for (int r = 0; r < 4; ++r) {
                float p = __expf(at[jt][r] - m);
                at[jt][r] = p;
                s += p;
            }
        s += __shfl_xor(s, 16);
        s += __shfl_xor(s, 32);
        float inv = 1.0f / s;
#pragma unroll
        for (int jt = 0; jt < 4; ++jt) {
            unsigned lo = cvt_pk_bf16(at[jt][0] * inv, at[jt][1] * inv);
            unsigned hi = cvt_pk_bf16(at[jt][2] * inv, at[jt][3] * inv);
            *(int2*)&Pt[lr * 72 + jt * 16 + lg * 4] = make_int2((int)lo, (int)hi);
        }
        __builtin_amdgcn_s_setprio(1);
#pragma unroll
        for (int kc = 0; kc < 2; ++kc) {
            FragU pb;
            pb.i4 = *(const int4*)&Pt[lr * 72 + kc * 32 + lg * 8];
#pragma unroll
            for (int mi = 0; mi < 2; ++mi) {
                FragU va;
                va.i4 = *(const int4*)&Vt[(mi * 16 + lr) * 72 + kc * 32 + lg * 8];
                oacc[mi][qt] = __builtin_amdgcn_mfma_f32_16x16x32_bf16(
                    va.b8, pb.b8, oacc[mi][qt], 0, 0, 0);
            }
        }
        __builtin_amdgcn_s_setprio(0);
    }

#pragma unroll
    for (int ni = 0; ni < 4; ++ni) {
        int qrow = ni * 16 + lr;
        if (qrow < 49) {
            int tok = tokbase + (qrow / 7) * 56 + (qrow % 7);
#pragma unroll
            for (int mi = 0; mi < 2; ++mi) {
                unsigned lo = cvt_pk_bf16(oacc[mi][ni][0], oacc[mi][ni][1]);
                unsigned hi = cvt_pk_bf16(oacc[mi][ni][2], oacc[mi][ni][3]);
                *(int2*)&aout[(size_t)tok * 128 + h * 32 + mi * 16 + lg * 4] =
                    make_int2((int)lo, (int)hi);
            }
        }
    }
}

// ------------- PatchMerging gather + LN -> bf16 rows [25088][512] ----------
__global__ __launch_bounds__(256) void k_pmln(
    const float* __restrict__ x, const float* __restrict__ g,
    const float* __restrict__ bt, short* __restrict__ outb) {
    int m2 = blockIdx.x * 4 + (threadIdx.x >> 6);
    int l = threadIdx.x & 63;
    int b = m2 / 784, r = m2 % 784;
    int h2 = r / 28, w2 = r % 28;
    int q0 = l * 8;
    int i2 = q0 >> 8, j2 = (q0 >> 7) & 1, c = q0 & 127;
    const float* src = x + (size_t)((b * 56 + 2 * h2 + i2) * 56 + 2 * w2 + j2) * 128 + c;
    float4 f0 = *(const float4*)src;
    float4 f1 = *(const float4*)(src + 4);
    float v[8] = {f0.x, f0.y, f0.z, f0.w, f1.x, f1.y, f1.z, f1.w};
    float s1 = 0.f, s2 = 0.f;
#pragma unroll
    for (int e = 0; e < 8; ++e) { s1 += v[e]; s2 = fmaf(v[e], v[e], s2); }
#pragma unroll
    for (int off = 32; off >= 1; off >>= 1) {
        s1 += __shfl_xor(s1, off);
        s2 += __shfl_xor(s2, off);
    }
    float mean = s1 * (1.0f / 512.0f);
    float var = s2 * (1.0f / 512.0f) - mean * mean;
    float rstd = rsqrtf(var + 1e-5f);
    union { int4 i4; short s8[8]; } u;
#pragma unroll
    for (int e = 0; e < 8; ++e)
        u.s8[e] = f2bf((v[e] - mean) * rstd * g[q0 + e] + bt[q0 + e]);
    *(int4*)(outb + (size_t)m2 * 512 + q0) = u.i4;
}

// ---------------------------------------------------------------------------
extern "C" void kernel_launch(void* const* d_in, const int* in_sizes, int n_in,
                              void* d_out, int out_size, void* d_ws, size_t ws_size,
                              hipStream_t stream) {
    const float* x_in   = (const float*)d_in[0];
    const float* qkv_w  = (const float*)d_in[1];
    const float* q_bias = (const float*)d_in[2];
    const float* v_bias = (const float*)d_in[3];
    const float* lscale = (const float*)d_in[4];
    const float* cpb_w1 = (const float*)d_in[5];
    const float* cpb_b1 = (const float*)d_in[6];
    const float* cpb_w2 = (const float*)d_in[7];
    const float* proj_w = (const float*)d_in[8];
    const float* proj_b = (const float*)d_in[9];
    const float* n1g    = (const float*)d_in[10];
    const float* n1b    = (const float*)d_in[11];
    const float* mw1    = (const float*)d_in[12];
    const float* mb1    = (const float*)d_in[13];
    const float* mw2    = (const float*)d_in[14];
    const float* mb2    = (const float*)d_in[15];
    const float* n2g    = (const float*)d_in[16];
    const float* n2b    = (const float*)d_in[17];
    const float* pmg    = (const float*)d_in[18];
    const float* pmb    = (const float*)d_in[19];
    const float* pmw    = (const float*)d_in[20];
    float* out = (float*)d_out;

    float* wsf     = (float*)d_ws;
    float* xcur    = wsf;
    float* R1      = wsf + (size_t)12845056;
    short* qkvb    = (short*)R1;
    short* attnout = (short*)(R1 + (size_t)19267584);   // kTok*128 bf16
    short* pmin    = (short*)R1;                        // 25088*512 bf16
    short* xb      = (short*)(R1 + (size_t)25690112);   // kTok*128 bf16
    float* wtail   = R1 + (size_t)38535168;
    short* wqkvb   = (short*)wtail;          // 49,152 bf16
    short* wprojb  = wqkvb + 49152;          // 16,384
    short* wm1b    = wprojb + 16384;         // 65,536
    short* wm2b    = wm1b + 65536;           // 65,536
    short* wpmb    = wm2b + 65536;           // 131,072
    float* out169  = wtail + 163840;
    float* rpb64   = out169 + 704;

    k_cvtx<<<6272, 256, 0, stream>>>(x_in, xb);

    for (int i = 0; i < 2; ++i) {
        int shift = i ? 3 : 0;
        const float* xi = (i == 0) ? x_in : xcur;
        k_cpb<<<169, 256, 0, stream>>>(cpb_w1 + i * 1024, cpb_b1 + i * 512,
                                       cpb_w2 + i * 2048, out169);
        k_rpb<<<64, 256, 0, stream>>>(out169, rpb64);
        k_cvtw<<<24, 256, 0, stream>>>(qkv_w + i * 49152, wqkvb, 16, 384);
        k_cvtw<<<8, 256, 0, stream>>>(proj_w + i * 16384, wprojb, 16, 128);
        k_cvtw<<<32, 256, 0, stream>>>(mw1 + i * 65536, wm1b, 16, 512);
        k_cvtw<<<32, 256, 0, stream>>>(mw2 + i * 65536, wm2b, 64, 128);

        k_gemm<128, 1, 6><<<4704, 256, 0, stream>>>(
            xb, wqkvb, q_bias + i * 128, v_bias + i * 128, qkvb, 384, shift);
        k_attn<<<2048, 256, 0, stream>>>(
            qkvb, rpb64, lscale + i * 4, attnout, shift);
        k_gemm_ln<128><<<1568, 256, 0, stream>>>(
            attnout, wprojb, proj_b + i * 128, n1g + i * 128, n1b + i * 128,
            xi, xcur, xb, shift);
        k_mlp<<<784, 256, 0, stream>>>(
            xb, wm1b, wm2b, mb1 + i * 512, mb2 + i * 128,
            n2g + i * 128, n2b + i * 128, xcur, xcur, xb);
    }
    k_cvtw<<<64, 256, 0, stream>>>(pmw, wpmb, 64, 256);
    k_pmln<<<6272, 256, 0, stream>>>(xcur, pmg, pmb, pmin);
    k_gemm<512, 0, 4><<<784, 256, 0, stream>>>(
        pmin, wpmb, nullptr, nullptr, out, 256, 0);
}

// Round 12
// 395.808 us; speedup vs baseline: 1.2040x; 1.0852x over previous
//
#include <hip/hip_runtime.h>
#include <math.h>

// ---------------------------------------------------------------------------
// SwinV2 stage: B=32, H=W=56, C=128, NH=4, hd=32, WS=7, N=49, DEPTH=2, shift=3
// Round 12: bf16-only residual stream (fp32 xcur deleted) — LN/residual math
// stays fp32 in-register, only storage is bf16. proj_ln/mlp epilogues store
// half the bytes; mlp fully in-place on xb. Rest unchanged from R11.
// ---------------------------------------------------------------------------

namespace {
constexpr int kTok = 32 * 56 * 56;   // 100352 tokens
}

typedef __attribute__((ext_vector_type(8))) short bf16x8;
typedef __attribute__((ext_vector_type(4))) float f32x4;

union FragU {
    int4 i4;
    bf16x8 b8;
    unsigned short u[8];
};

__device__ __forceinline__ short f2bf(float f) {
    unsigned u = __float_as_uint(f);
    return (short)((u + 0x7FFFu + ((u >> 16) & 1u)) >> 16);
}
__device__ __forceinline__ float bf2f(unsigned short u) {
    return __uint_as_float(((unsigned)u) << 16);
}
__device__ __forceinline__ unsigned cvt_pk_bf16(float a, float b) {
    unsigned r;
    asm("v_cvt_pk_bf16_f32 %0, %1, %2" : "=v"(r) : "v"(a), "v"(b));
    return r;
}
// tanh-form GELU, 8 insts (exp2 + v_rcp, no IEEE div)
__device__ __forceinline__ float gelu_t(float x) {
    float x2 = x * x;
    float t0 = fmaf(0.044715f * x2, x, x);
    float e = exp2f(2.3022227f * t0);           // exp(2*0.79788456*t0)
    float r = __builtin_amdgcn_rcpf(e + 1.0f);
    return fmaf(-x, r, x);                      // x * (1 - 1/(e+1))
}

// --------------------------- CPB MLP (tiny) --------------------------------
__global__ __launch_bounds__(256) void k_cpb(
    const float* __restrict__ w1, const float* __restrict__ b1,
    const float* __restrict__ w2, float* __restrict__ out169) {
    int t = blockIdx.x;  // 0..168
    int ia = t / 13, ib = t % 13;
    float r0 = (float)(ia - 6) * (8.0f / 6.0f);
    float s0 = (r0 > 0.f) ? 1.f : (r0 < 0.f ? -1.f : 0.f);
    float t0 = s0 * log2f(fabsf(r0) + 1.0f) * (1.0f / 3.0f);
    float r1 = (float)(ib - 6) * (8.0f / 6.0f);
    float s1 = (r1 > 0.f) ? 1.f : (r1 < 0.f ? -1.f : 0.f);
    float t1 = s1 * log2f(fabsf(r1) + 1.0f) * (1.0f / 3.0f);

    int tid = threadIdx.x;
    float p0 = 0, p1 = 0, p2 = 0, p3 = 0;
    for (int c = tid; c < 512; c += 256) {
        float hv = fmaxf(t0 * w1[c] + t1 * w1[512 + c] + b1[c], 0.0f);
        p0 += hv * w2[c * 4 + 0];
        p1 += hv * w2[c * 4 + 1];
        p2 += hv * w2[c * 4 + 2];
        p3 += hv * w2[c * 4 + 3];
    }
    __shared__ float red[256][4];
    red[tid][0] = p0; red[tid][1] = p1; red[tid][2] = p2; red[tid][3] = p3;
    __syncthreads();
    for (int s = 128; s > 0; s >>= 1) {
        if (tid < s) {
            red[tid][0] += red[tid + s][0];
            red[tid][1] += red[tid + s][1];
            red[tid][2] += red[tid + s][2];
            red[tid][3] += red[tid + s][3];
        }
        __syncthreads();
    }
    if (tid < 4) out169[t * 4 + tid] = red[0][tid];
}

// rpb64[h][qrow64][krow64]; krow>=49 -> -30000 (k-pad baked in)
__global__ void k_rpb(const float* __restrict__ out169, float* __restrict__ rpb64) {
    int e = blockIdx.x * 256 + threadIdx.x;
    if (e >= 4 * 64 * 64) return;
    int h = e >> 12, r = e & 4095;
    int i = r >> 6, j = r & 63;
    float val;
    if (j >= 49) {
        val = -30000.0f;
    } else if (i >= 49) {
        val = 0.0f;
    } else {
        int dp = i / 7 - j / 7 + 6;
        int dq = i % 7 - j % 7 + 6;
        float v = out169[(dp * 13 + dq) * 4 + h];
        val = 16.0f / (1.0f + expf(-v));
    }
    rpb64[e] = val;
}

// ------------------- weight fp32 -> bf16 tiled image -----------------------
// Logical slot (nt*Kb + kb)*64 + nn holds W[kb*8+e][nt*64+nn], e=0..7.
// Stored at physical nn' = (nn & ~3) | ((nn ^ kb) & 3).
__global__ __launch_bounds__(256) void k_cvtw(
    const float* __restrict__ W, short* __restrict__ Wb, int Kb, int N) {
    int slt = blockIdx.x * 256 + threadIdx.x;
    if (slt >= Kb * N) return;
    int nn = slt & 63;
    int tmp = slt >> 6;
    int kb = tmp % Kb;
    int nt = tmp / Kb;
    int n = nt * 64 + nn;
    int k0 = kb * 8;
    union { int4 i4; short s8[8]; } u;
#pragma unroll
    for (int e = 0; e < 8; ++e) u.s8[e] = f2bf(W[(size_t)(k0 + e) * N + n]);
    int nns = (nn & ~3) | ((nn ^ kb) & 3);
    *(int4*)(Wb + (((size_t)tmp) * 64 + nns) * 8) = u.i4;
}

// ------------------- activation fp32 -> bf16 rows --------------------------
__global__ __launch_bounds__(256) void k_cvtx(
    const float* __restrict__ x, short* __restrict__ xb) {
    size_t e = ((size_t)blockIdx.x * 256 + threadIdx.x) * 8;
    const float* src = x + e;
    float4 f0 = *(const float4*)src;
    float4 f1 = *(const float4*)(src + 4);
    union { int4 i4; short s8[8]; } u;
    u.s8[0] = f2bf(f0.x); u.s8[1] = f2bf(f0.y);
    u.s8[2] = f2bf(f0.z); u.s8[3] = f2bf(f0.w);
    u.s8[4] = f2bf(f1.x); u.s8[5] = f2bf(f1.y);
    u.s8[6] = f2bf(f1.z); u.s8[7] = f2bf(f1.w);
    *(int4*)(xb + e) = u.i4;
}

// --------------------------- MFMA GEMM (bf16 A) ----------------------------
// EPI: 0 = raw fp32; 1 = qkv bias -> bf16 out (stride 384), roll on A.
template <int K, int EPI, int NT>
__global__ __launch_bounds__(256) void k_gemm(
    const short* __restrict__ Ain, const short* __restrict__ Wb,
    const float* __restrict__ bias0, const float* __restrict__ bias1,
    void* __restrict__ Out, int ostride, int shift) {
    constexpr int Kb = K / 8;
    constexpr int NC = K / 128;
    __shared__ int4 As4[2048];  // [16 kb][128 m], XOR-swizzled (8-wide)
    __shared__ int4 Ws4[1024];  // [16 kb][64 nn], XOR-swizzled (4-wide, in image)
    int tid = threadIdx.x;
    int nwg = gridDim.x;
    int chunk = nwg >> 3;
    int lid = (blockIdx.x & 7) * chunk + (blockIdx.x >> 3);
    int mt = lid / NT, nt = lid - mt * NT;
    int mb = mt * 128;
    int w = tid >> 6, l = tid & 63, lr = l & 15, lg = l >> 4;
    const f32x4 fz = {0.f, 0.f, 0.f, 0.f};
    f32x4 acc[2][4];
#pragma unroll
    for (int mi = 0; mi < 2; ++mi)
#pragma unroll
        for (int ni = 0; ni < 4; ++ni) acc[mi][ni] = fz;

    for (int c = 0; c < NC; ++c) {
        if (c) __syncthreads();
#pragma unroll
        for (int it = 0; it < 8; ++it) {
            int s = it * 256 + tid;
            int m = s >> 4, kb = s & 15;
            int gm = mb + m;
            if (EPI == 1 && shift) {
                int b = gm / 3136, r = gm % 3136;
                int hh = r / 56 + shift; if (hh >= 56) hh -= 56;
                int ww = r % 56 + shift; if (ww >= 56) ww -= 56;
                gm = b * 3136 + hh * 56 + ww;
            }
            int slot = kb * 128 + ((m & ~7) | ((m ^ kb) & 7));
            As4[slot] = *(const int4*)(Ain + (size_t)gm * K + c * 128 + kb * 8);
        }
        {
            const int4* wsrc = (const int4*)(Wb + ((size_t)nt * Kb + c * 16) * 64 * 8);
#pragma unroll
            for (int it = 0; it < 4; ++it) Ws4[it * 256 + tid] = wsrc[it * 256 + tid];
        }
        __syncthreads();
#pragma unroll
        for (int kk = 0; kk < 4; ++kk) {
            int kbl = kk * 4 + lg;
            int m0 = w * 32 + lr;
            bf16x8 a0 = *(const bf16x8*)&As4[kbl * 128 + ((m0 & ~7) | ((m0 ^ kbl) & 7))];
            int m1 = m0 + 16;
            bf16x8 a1 = *(const bf16x8*)&As4[kbl * 128 + ((m1 & ~7) | ((m1 ^ kbl) & 7))];
#pragma unroll
            for (int ni = 0; ni < 4; ++ni) {
                int nn = lr + 16 * ni;
                bf16x8 bfr = *(const bf16x8*)&Ws4[kbl * 64 + ((nn & ~3) | ((nn ^ kbl) & 3))];
                acc[0][ni] = __builtin_amdgcn_mfma_f32_16x16x32_bf16(a0, bfr, acc[0][ni], 0, 0, 0);
                acc[1][ni] = __builtin_amdgcn_mfma_f32_16x16x32_bf16(a1, bfr, acc[1][ni], 0, 0, 0);
            }
        }
    }
#pragma unroll
    for (int ni = 0; ni < 4; ++ni) {
        int col = nt * 64 + ni * 16 + lr;
        float bv = 0.f;
        if (EPI == 1) bv = (col < 128) ? bias0[col] : ((col < 256) ? 0.f : bias1[col - 256]);
#pragma unroll
        for (int mi = 0; mi < 2; ++mi) {
#pragma unroll
            for (int r = 0; r < 4; ++r) {
                int row = mb + w * 32 + mi * 16 + lg * 4 + r;
                float v = acc[mi][ni][r] + bv;
                if (EPI == 0) {
                    ((float*)Out)[(size_t)row * ostride + col] = v;
                } else {
                    ((short*)Out)[(size_t)row * 384 + col] = f2bf(v);
                }
            }
        }
    }
}

// ------------- MFMA GEMM + bias + LN + residual (+roll-back) ---------------
// Attention projection (K=128). Residual read fp32 (RF32) or bf16; output
// stored bf16-only (math in fp32 registers).
template <int K, bool RF32>
__global__ __launch_bounds__(256) void k_gemm_ln(
    const short* __restrict__ Ain, const short* __restrict__ Wb,
    const float* __restrict__ bias, const float* __restrict__ g,
    const float* __restrict__ bt, const void* __restrict__ resid,
    short* __restrict__ xoutb, int shift) {
    constexpr int Kb = K / 8;
    constexpr int NC = K / 128;
    __shared__ int4 As4[1024];  // [16 kb][64 m]
    __shared__ int4 Ws4[2048];  // [2 ntw][16 kb][64 nn]
    int tid = threadIdx.x;
    int mb = blockIdx.x * 64;
    int w = tid >> 6, l = tid & 63, lr = l & 15, lg = l >> 4;
    const f32x4 fz = {0.f, 0.f, 0.f, 0.f};
    f32x4 acc[8];
#pragma unroll
    for (int ni = 0; ni < 8; ++ni) acc[ni] = fz;

    for (int c = 0; c < NC; ++c) {
        if (c) __syncthreads();
#pragma unroll
        for (int it = 0; it < 4; ++it) {
            int s = it * 256 + tid;
            int m = s >> 4, kb = s & 15;
            int slot = kb * 64 + ((m & ~7) | ((m ^ kb) & 7));
            As4[slot] = *(const int4*)(Ain + (size_t)(mb + m) * K + c * 128 + kb * 8);
        }
        {
            const int4* w0 = (const int4*)(Wb + ((size_t)(c * 16)) * 64 * 8);
            const int4* w1 = (const int4*)(Wb + ((size_t)(Kb + c * 16)) * 64 * 8);
#pragma unroll
            for (int it = 0; it < 4; ++it) {
                Ws4[it * 256 + tid] = w0[it * 256 + tid];
                Ws4[1024 + it * 256 + tid] = w1[it * 256 + tid];
            }
        }
        __syncthreads();
#pragma unroll
        for (int kk = 0; kk < 4; ++kk) {
            int kbl = kk * 4 + lg;
            int m0 = w * 16 + lr;
            bf16x8 a0 = *(const bf16x8*)&As4[kbl * 64 + ((m0 & ~7) | ((m0 ^ kbl) & 7))];
#pragma unroll
            for (int ni = 0; ni < 8; ++ni) {
                int nn = lr + 16 * (ni & 3);
                bf16x8 bfr = *(const bf16x8*)&Ws4[(ni >> 2) * 1024 + kbl * 64 +
                                                  ((nn & ~3) | ((nn ^ kbl) & 3))];
                acc[ni] = __builtin_amdgcn_mfma_f32_16x16x32_bf16(a0, bfr, acc[ni], 0, 0, 0);
            }
        }
    }
    float bv[8], gv[8], btv[8];
#pragma unroll
    for (int ni = 0; ni < 8; ++ni) {
        int col = ni * 16 + lr;
        bv[ni] = bias[col]; gv[ni] = g[col]; btv[ni] = bt[col];
    }
#pragma unroll
    for (int r = 0; r < 4; ++r) {
        int row = mb + w * 16 + lg * 4 + r;
        float v[8];
        float s1 = 0.f, s2 = 0.f;
#pragma unroll
        for (int ni = 0; ni < 8; ++ni) {
            v[ni] = acc[ni][r] + bv[ni];
            s1 += v[ni];
            s2 = fmaf(v[ni], v[ni], s2);
        }
#pragma unroll
        for (int off = 8; off >= 1; off >>= 1) {
            s1 += __shfl_xor(s1, off);
            s2 += __shfl_xor(s2, off);
        }
        float mean = s1 * (1.0f / 128.0f);
        float var = s2 * (1.0f / 128.0f) - mean * mean;
        float rstd = rsqrtf(var + 1e-5f);
        int mo = row;
        if (shift) {
            int b = row / 3136, rr = row % 3136;
            int hh = rr / 56 + shift; if (hh >= 56) hh -= 56;
            int ww = rr % 56 + shift; if (ww >= 56) ww -= 56;
            mo = b * 3136 + hh * 56 + ww;
        }
        size_t base = (size_t)mo * 128;
#pragma unroll
        for (int ni = 0; ni < 8; ++ni) {
            int col = ni * 16 + lr;
            float rv = RF32 ? ((const float*)resid)[base + col]
                            : bf2f(((const unsigned short*)resid)[base + col]);
            float o = rv + (v[ni] - mean) * rstd * gv[ni] + btv[ni];
            xoutb[base + col] = f2bf(o);
        }
    }
}

// -------------------- Fused MLP: fc1 + GELU + fc2 + LN + residual ----------
// In-place on xb (block-row-private). BM=128, 4 waves x 32 rows.
__global__ __launch_bounds__(256) void k_mlp(
    short* __restrict__ xb, const short* __restrict__ W1b,
    const short* __restrict__ W2b, const float* __restrict__ b1,
    const float* __restrict__ b2, const float* __restrict__ g,
    const float* __restrict__ bt) {
    __shared__ int4 W1s[1024];       // chunk: [16 kb][64 nn] (swizzled image)
    __shared__ int4 W2s[1024];       // chunk: [2 ntw][8 kb][64 nn]
    __shared__ short Hs[4 * 2304];   // hid: [4 wave][32 tok][72] (wave-private)
    int tid = threadIdx.x;
    int mb = blockIdx.x * 128;
    int w = tid >> 6, l = tid & 63, lr = l & 15, lg = l >> 4;
    const f32x4 fz = {0.f, 0.f, 0.f, 0.f};
    short* Hw = Hs + w * 2304;

    // this wave's 32 token rows as two A-frag sets (row = w*32 + mi*16 + lr)
    int4 xfrag[2][4];
#pragma unroll
    for (int mi = 0; mi < 2; ++mi)
#pragma unroll
        for (int kk = 0; kk < 4; ++kk)
            xfrag[mi][kk] = *(const int4*)(
                xb + (size_t)(mb + w * 32 + mi * 16 + lr) * 128 + kk * 32 + lg * 8);

    f32x4 acc2[2][8];
#pragma unroll
    for (int mi = 0; mi < 2; ++mi)
#pragma unroll
        for (int ni = 0; ni < 8; ++ni) acc2[mi][ni] = fz;

    for (int c = 0; c < 8; ++c) {
        __syncthreads();   // previous chunk's W reads complete
        {
            const int4* w1src = (const int4*)(W1b + (size_t)c * 8192);
#pragma unroll
            for (int it = 0; it < 4; ++it) W1s[it * 256 + tid] = w1src[it * 256 + tid];
            const int4* w2a = (const int4*)(W2b + (size_t)(c * 8) * 512);
            const int4* w2c = (const int4*)(W2b + (size_t)(64 + c * 8) * 512);
#pragma unroll
            for (int it = 0; it < 2; ++it) {
                W2s[it * 256 + tid] = w2a[it * 256 + tid];
                W2s[512 + it * 256 + tid] = w2c[it * 256 + tid];
            }
        }
        __syncthreads();
        // fc1 (swapped operands): Ht rows = hid cols, cols = token (lr)
        f32x4 a1[2][4];
#pragma unroll
        for (int mi = 0; mi < 2; ++mi)
#pragma unroll
            for (int ct = 0; ct < 4; ++ct) a1[mi][ct] = fz;
        __builtin_amdgcn_s_setprio(1);
#pragma unroll
        for (int kk = 0; kk < 4; ++kk) {
            int kbl = kk * 4 + lg;
            FragU xa0; xa0.i4 = xfrag[0][kk];
            FragU xa1; xa1.i4 = xfrag[1][kk];
#pragma unroll
            for (int ct = 0; ct < 4; ++ct) {
                int nn = lr + 16 * ct;
                bf16x8 w1f = *(const bf16x8*)&W1s[kbl * 64 + ((nn & ~3) | ((nn ^ kbl) & 3))];
                a1[0][ct] = __builtin_amdgcn_mfma_f32_16x16x32_bf16(w1f, xa0.b8, a1[0][ct], 0, 0, 0);
                a1[1][ct] = __builtin_amdgcn_mfma_f32_16x16x32_bf16(w1f, xa1.b8, a1[1][ct], 0, 0, 0);
            }
        }
        __builtin_amdgcn_s_setprio(0);
        // bias + gelu + pack: lane writes 4 consecutive hid cols per (mi,ct)
#pragma unroll
        for (int mi = 0; mi < 2; ++mi) {
#pragma unroll
            for (int ct = 0; ct < 4; ++ct) {
                float4 bb = *(const float4*)(b1 + c * 64 + ct * 16 + lg * 4);
                float h0 = gelu_t(a1[mi][ct][0] + bb.x);
                float h1 = gelu_t(a1[mi][ct][1] + bb.y);
                float h2 = gelu_t(a1[mi][ct][2] + bb.z);
                float h3 = gelu_t(a1[mi][ct][3] + bb.w);
                unsigned p0 = cvt_pk_bf16(h0, h1);
                unsigned p1 = cvt_pk_bf16(h2, h3);
                *(int2*)&Hw[(mi * 16 + lr) * 72 + ct * 16 + lg * 4] =
                    make_int2((int)p0, (int)p1);
            }
        }
        // fc2 accumulate (K=64 chunk), A from wave-private Hw
        __builtin_amdgcn_s_setprio(1);
#pragma unroll
        for (int kc = 0; kc < 2; ++kc) {
            int kbl = kc * 4 + lg;   // local kb 0..7
            FragU ha0; ha0.i4 = *(const int4*)&Hw[lr * 72 + kc * 32 + lg * 8];
            FragU ha1; ha1.i4 = *(const int4*)&Hw[(16 + lr) * 72 + kc * 32 + lg * 8];
#pragma unroll
            for (int ni = 0; ni < 8; ++ni) {
                int nn = lr + 16 * (ni & 3);
                bf16x8 w2f = *(const bf16x8*)&W2s[(ni >> 2) * 512 + kbl * 64 +
                                                  ((nn & ~3) | ((nn ^ kbl) & 3))];
                acc2[0][ni] = __builtin_amdgcn_mfma_f32_16x16x32_bf16(ha0.b8, w2f, acc2[0][ni], 0, 0, 0);
                acc2[1][ni] = __builtin_amdgcn_mfma_f32_16x16x32_bf16(ha1.b8, w2f, acc2[1][ni], 0, 0, 0);
            }
        }
        __builtin_amdgcn_s_setprio(0);
    }

    // LN + residual epilogue (fp32 math, bf16 storage, in-place)
    float bv[8], gv[8], btv[8];
#pragma unroll
    for (int ni = 0; ni < 8; ++ni) {
        int col = ni * 16 + lr;
        bv[ni] = b2[col]; gv[ni] = g[col]; btv[ni] = bt[col];
    }
#pragma unroll
    for (int mi = 0; mi < 2; ++mi) {
#pragma unroll
        for (int r = 0; r < 4; ++r) {
            int row = mb + w * 32 + mi * 16 + lg * 4 + r;
            float v[8];
            float s1 = 0.f, s2 = 0.f;
#pragma unroll
            for (int ni = 0; ni < 8; ++ni) {
                v[ni] = acc2[mi][ni][r] + bv[ni];
                s1 += v[ni];
                s2 = fmaf(v[ni], v[ni], s2);
            }
#pragma unroll
            for (int off = 8; off >= 1; off >>= 1) {
                s1 += __shfl_xor(s1, off);
                s2 += __shfl_xor(s2, off);
            }
            float mean = s1 * (1.0f / 128.0f);
            float var = s2 * (1.0f / 128.0f) - mean * mean;
            float rstd = rsqrtf(var + 1e-5f);
            size_t base = (size_t)row * 128;
#pragma unroll
            for (int ni = 0; ni < 8; ++ni) {
                int col = ni * 16 + lr;
                float rv = bf2f(((const unsigned short*)xb)[base + col]);
                float o = rv + (v[ni] - mean) * rstd * gv[ni] + btv[ni];
                xb[base + col] = f2bf(o);
            }
        }
    }
}

// --------------------------- MFMA windowed attention -----------------------
__global__ __launch_bounds__(256) void k_attn(
    const short* __restrict__ qkv, const float* __restrict__ rpb64,
    const float* __restrict__ ls, short* __restrict__ aout, int shift) {
    __shared__ short lds[4 * 3584];
    int wid = blockIdx.x;
    int b = wid >> 6, wrem = wid & 63;
    int wh = wrem >> 3, ww_ = wrem & 7;
    int h = threadIdx.x >> 6;
    int l = threadIdx.x & 63, lr = l & 15, lg = l >> 4;
    short* Pt = lds + h * 3584;              // [16 qrow][72]
    short* Vt = Pt + 1152;                   // [32 d][72]
    float* invks = (float*)(Vt + 2304);      // [64] 1/||k_j||
    int tokbase = b * 3136 + wh * 7 * 56 + ww_ * 7;

    float scale = __expf(fminf(ls[h], 4.6051702f));  // ln(100)
    int4 qf[4], kf[4], vf[4];
    const int4 zero4 = make_int4(0, 0, 0, 0);
#pragma unroll
    for (int t = 0; t < 4; ++t) {
        int i = t * 16 + lr;
        bool valid = (i < 49);
        int tok = tokbase + (i / 7) * 56 + (i % 7);
        const short* base = qkv + (size_t)tok * 384 + h * 32 + lg * 8;
        qf[t] = valid ? *(const int4*)base : zero4;
        kf[t] = valid ? *(const int4*)(base + 128) : zero4;
    }
#pragma unroll
    for (int t = 0; t < 4; ++t) {
        int e = t * 64 + l;
        int j = e >> 2, dq = e & 3;
        if (j < 49) {
            int tok = tokbase + (j / 7) * 56 + (j % 7);
            vf[t] = *(const int4*)(qkv + (size_t)tok * 384 + 256 + h * 32 + dq * 8);
        } else {
            vf[t] = zero4;
        }
    }

    float invq[4];
#pragma unroll
    for (int t = 0; t < 4; ++t) {
        {
            FragU u; u.i4 = qf[t];
            float ss = 0.f;
#pragma unroll
            for (int e = 0; e < 8; ++e) { float x = bf2f(u.u[e]); ss = fmaf(x, x, ss); }
            ss += __shfl_xor(ss, 16);
            ss += __shfl_xor(ss, 32);
            invq[t] = scale / fmaxf(sqrtf(ss), 1e-12f);
        }
        {
            FragU u; u.i4 = kf[t];
            float ss = 0.f;
#pragma unroll
            for (int e = 0; e < 8; ++e) { float x = bf2f(u.u[e]); ss = fmaf(x, x, ss); }
            ss += __shfl_xor(ss, 16);
            ss += __shfl_xor(ss, 32);
            float ik = 1.0f / fmaxf(sqrtf(ss), 1e-12f);
            if (l < 16) invks[t * 16 + l] = ik;
        }
    }

    for (int t = l; t < 480; t += 64) {
        Vt[(t / 15) * 72 + 49 + (t % 15)] = 0;
    }
#pragma unroll
    for (int t = 0; t < 4; ++t) {
        int e = t * 64 + l;
        int j = e >> 2, dq = e & 3;
        if (j < 49) {
            FragU u; u.i4 = vf[t];
#pragma unroll
            for (int ee = 0; ee < 8; ++ee) Vt[(dq * 8 + ee) * 72 + j] = (short)u.u[ee];
        }
    }

    float ika[4][4];
#pragma unroll
    for (int jt = 0; jt < 4; ++jt) {
        float4 v4 = *(const float4*)&invks[jt * 16 + lg * 4];
        ika[jt][0] = v4.x; ika[jt][1] = v4.y; ika[jt][2] = v4.z; ika[jt][3] = v4.w;
    }

    bool edge = (shift != 0) && ((wh == 7) || (ww_ == 7));
    const float* rbase = rpb64 + h * 4096;
    const f32x4 fz = {0.f, 0.f, 0.f, 0.f};
    f32x4 oacc[2][4];
#pragma unroll
    for (int mi = 0; mi < 2; ++mi)
#pragma unroll
        for (int ni = 0; ni < 4; ++ni) oacc[mi][ni] = fz;

#pragma unroll
    for (int qt = 0; qt < 4; ++qt) {
        f32x4 at[4];
        __builtin_amdgcn_s_setprio(1);
#pragma unroll
        for (int jt = 0; jt < 4; ++jt) {
            FragU a; a.i4 = kf[jt];
            FragU bq; bq.i4 = qf[qt];
            at[jt] = __builtin_amdgcn_mfma_f32_16x16x32_bf16(a.b8, bq.b8, fz, 0, 0, 0);
        }
        __builtin_amdgcn_s_setprio(0);

        float iq = invq[qt];
        int qi = qt * 16 + lr;
        int qc = (qi < 49) ? qi : 48;
        int rlq = 0, clq = 0;
        if (edge) {
            rlq = (wh == 7) ? ((qc / 7) < 4 ? 1 : 2) : 0;
            clq = (ww_ == 7) ? ((qc % 7) < 4 ? 1 : 2) : 0;
        }
#pragma unroll
        for (int jt = 0; jt < 4; ++jt) {
            float4 rv = *(const float4*)(rbase + qc * 64 + jt * 16 + lg * 4);
            float rr[4] = {rv.x, rv.y, rv.z, rv.w};
#pragma unroll
            for (int r = 0; r < 4; ++r) {
                float v = fmaf(at[jt][r] * ika[jt][r], iq, rr[r]);
                if (edge) {
                    int j = jt * 16 + lg * 4 + r;
                    int jc = (j < 49) ? j : 48;
                    int rlk = (wh == 7) ? ((jc / 7) < 4 ? 1 : 2) : 0;
                    int clk = (ww_ == 7) ? ((jc % 7) < 4 ? 1 : 2) : 0;
                    if (rlk != rlq || clk != clq) v -= 100.0f;
                }
                at[jt][r] = v;
            }
        }
        float m = -1e30f;
#pragma unroll
        for (int jt = 0; jt < 4; ++jt)
#pragma unroll
            for (int r = 0; r < 4; ++r) m = fmaxf(m, at[jt][r]);
        m = fmaxf(m, __shfl_xor(m, 16));
        m = fmaxf(m, __shfl_xor(m, 32));
        float s = 0.f;
#pragma unroll
        for (int jt = 0; jt < 4; ++jt)
#pragma unroll
            for (int r = 0; r < 4; ++r) {
                float p = __expf(at[jt][r] - m);
                at[jt][r] = p;
                s += p;
            }
        s += __shfl_xor(s, 16);
        s += __shfl_xor(s, 32);
        float inv = 1.0f / s;
#pragma unroll
        for (int jt = 0; jt < 4; ++jt) {
            unsigned lo = cvt_pk_bf16(at[jt][0] * inv, at[jt][1] * inv);
            unsigned hi = cvt_pk_bf16(at[jt][2] * inv, at[jt][3] * inv);
            *(int2*)&Pt[lr * 72 + jt * 16 + lg * 4] = make_int2((int)lo, (int)hi);
        }
        __builtin_amdgcn_s_setprio(1);
#pragma unroll
        for (int kc = 0; kc < 2; ++kc) {
            FragU pb;
            pb.i4 = *(const int4*)&Pt[lr * 72 + kc * 32 + lg * 8];
#pragma unroll
            for (int mi = 0; mi < 2; ++mi) {
                FragU va;
                va.i4 = *(const int4*)&Vt[(mi * 16 + lr) * 72 + kc * 32 + lg * 8];
                oacc[mi][qt] = __builtin_amdgcn_mfma_f32_16x16x32_bf16(
                    va.b8, pb.b8, oacc[mi][qt], 0, 0, 0);
            }
        }
        __builtin_amdgcn_s_setprio(0);
    }

#pragma unroll
    for (int ni = 0; ni < 4; ++ni) {
        int qrow = ni * 16 + lr;
        if (qrow < 49) {
            int tok = tokbase + (qrow / 7) * 56 + (qrow % 7);
#pragma unroll
            for (int mi = 0; mi < 2; ++mi) {
                unsigned lo = cvt_pk_bf16(oacc[mi][ni][0], oacc[mi][ni][1]);
                unsigned hi = cvt_pk_bf16(oacc[mi][ni][2], oacc[mi][ni][3]);
                *(int2*)&aout[(size_t)tok * 128 + h * 32 + mi * 16 + lg * 4] =
                    make_int2((int)lo, (int)hi);
            }
        }
    }
}

// ------------- PatchMerging gather + LN -> bf16 rows [25088][512] ----------
// input now bf16 (xb)
__global__ __launch_bounds__(256) void k_pmln(
    const short* __restrict__ x, const float* __restrict__ g,
    const float* __restrict__ bt, short* __restrict__ outb) {
    int m2 = blockIdx.x * 4 + (threadIdx.x >> 6);
    int l = threadIdx.x & 63;
    int b = m2 / 784, r = m2 % 784;
    int h2 = r / 28, w2 = r % 28;
    int q0 = l * 8;
    int i2 = q0 >> 8, j2 = (q0 >> 7) & 1, c = q0 & 127;
    const short* src = x + (size_t)((b * 56 + 2 * h2 + i2) * 56 + 2 * w2 + j2) * 128 + c;
    FragU u; u.i4 = *(const int4*)src;
    float v[8];
#pragma unroll
    for (int e = 0; e < 8; ++e) v[e] = bf2f(u.u[e]);
    float s1 = 0.f, s2 = 0.f;
#pragma unroll
    for (int e = 0; e < 8; ++e) { s1 += v[e]; s2 = fmaf(v[e], v[e], s2); }
#pragma unroll
    for (int off = 32; off >= 1; off >>= 1) {
        s1 += __shfl_xor(s1, off);
        s2 += __shfl_xor(s2, off);
    }
    float mean = s1 * (1.0f / 512.0f);
    float var = s2 * (1.0f / 512.0f) - mean * mean;
    float rstd = rsqrtf(var + 1e-5f);
    union { int4 i4; short s8[8]; } o;
#pragma unroll
    for (int e = 0; e < 8; ++e)
        o.s8[e] = f2bf((v[e] - mean) * rstd * g[q0 + e] + bt[q0 + e]);
    *(int4*)(outb + (size_t)m2 * 512 + q0) = o.i4;
}

// ---------------------------------------------------------------------------
extern "C" void kernel_launch(void* const* d_in, const int* in_sizes, int n_in,
                              void* d_out, int out_size, void* d_ws, size_t ws_size,
                              hipStream_t stream) {
    const float* x_in   = (const float*)d_in[0];
    const float* qkv_w  = (const float*)d_in[1];
    const float* q_bias = (const float*)d_in[2];
    const float* v_bias = (const float*)d_in[3];
    const float* lscale = (const float*)d_in[4];
    const float* cpb_w1 = (const float*)d_in[5];
    const float* cpb_b1 = (const float*)d_in[6];
    const float* cpb_w2 = (const float*)d_in[7];
    const float* proj_w = (const float*)d_in[8];
    const float* proj_b = (const float*)d_in[9];
    const float* n1g    = (const float*)d_in[10];
    const float* n1b    = (const float*)d_in[11];
    const float* mw1    = (const float*)d_in[12];
    const float* mb1    = (const float*)d_in[13];
    const float* mw2    = (const float*)d_in[14];
    const float* mb2    = (const float*)d_in[15];
    const float* n2g    = (const float*)d_in[16];
    const float* n2b    = (const float*)d_in[17];
    const float* pmg    = (const float*)d_in[18];
    const float* pmb    = (const float*)d_in[19];
    const float* pmw    = (const float*)d_in[20];
    float* out = (float*)d_out;

    float* wsf     = (float*)d_ws;
    float* R1      = wsf + (size_t)12845056;
    short* qkvb    = (short*)R1;
    short* attnout = (short*)(R1 + (size_t)19267584);   // kTok*128 bf16
    short* pmin    = (short*)R1;                        // 25088*512 bf16
    short* xb      = (short*)(R1 + (size_t)25690112);   // kTok*128 bf16
    float* wtail   = R1 + (size_t)38535168;
    short* wqkvb   = (short*)wtail;          // 49,152 bf16
    short* wprojb  = wqkvb + 49152;          // 16,384
    short* wm1b    = wprojb + 16384;         // 65,536
    short* wm2b    = wm1b + 65536;           // 65,536
    short* wpmb    = wm2b + 65536;           // 131,072
    float* out169  = wtail + 163840;
    float* rpb64   = out169 + 704;

    k_cvtx<<<6272, 256, 0, stream>>>(x_in, xb);

    for (int i = 0; i < 2; ++i) {
        int shift = i ? 3 : 0;
        k_cpb<<<169, 256, 0, stream>>>(cpb_w1 + i * 1024, cpb_b1 + i * 512,
                                       cpb_w2 + i * 2048, out169);
        k_rpb<<<64, 256, 0, stream>>>(out169, rpb64);
        k_cvtw<<<24, 256, 0, stream>>>(qkv_w + i * 49152, wqkvb, 16, 384);
        k_cvtw<<<8, 256, 0, stream>>>(proj_w + i * 16384, wprojb, 16, 128);
        k_cvtw<<<32, 256, 0, stream>>>(mw1 + i * 65536, wm1b, 16, 512);
        k_cvtw<<<32, 256, 0, stream>>>(mw2 + i * 65536, wm2b, 64, 128);

        k_gemm<128, 1, 6><<<4704, 256, 0, stream>>>(
            xb, wqkvb, q_bias + i * 128, v_bias + i * 128, qkvb, 384, shift);
        k_attn<<<2048, 256, 0, stream>>>(
            qkvb, rpb64, lscale + i * 4, attnout, shift);
        if (i == 0) {
            k_gemm_ln<128, true><<<1568, 256, 0, stream>>>(
                attnout, wprojb, proj_b, n1g, n1b, x_in, xb, shift);
        } else {
            k_gemm_ln<128, false><<<1568, 256, 0, stream>>>(
                attnout, wprojb, proj_b + i * 128, n1g + i * 128, n1b + i * 128,
                xb, xb, shift);
        }
        k_mlp<<<784, 256, 0, stream>>>(
            xb, wm1b, wm2b, mb1 + i * 512, mb2 + i * 128,
            n2g + i * 128, n2b + i * 128);
    }
    k_cvtw<<<64, 256, 0, stream>>>(pmw, wpmb, 64, 256);
    k_pmln<<<6272, 256, 0, stream>>>(xb, pmg, pmb, pmin);
    k_gemm<512, 0, 4><<<784, 256, 0, stream>>>(
        pmin, wpmb, nullptr, nullptr, out, 256, 0);
}

// Round 13
// 380.361 us; speedup vs baseline: 1.2529x; 1.0406x over previous
//
#include <hip/hip_runtime.h>
#include <math.h>

// ---------------------------------------------------------------------------
// SwinV2 stage: B=32, H=W=56, C=128, NH=4, hd=32, WS=7, N=49, DEPTH=2, shift=3
// Round 13: k_mlp T14 async W-prefetch (global->reg early, ds_write late);
// all weight conversions fused into one up-front kernel (24 -> 14 dispatches).
// ---------------------------------------------------------------------------

namespace {
constexpr int kTok = 32 * 56 * 56;   // 100352 tokens
}

typedef __attribute__((ext_vector_type(8))) short bf16x8;
typedef __attribute__((ext_vector_type(4))) float f32x4;

union FragU {
    int4 i4;
    bf16x8 b8;
    unsigned short u[8];
};

__device__ __forceinline__ short f2bf(float f) {
    unsigned u = __float_as_uint(f);
    return (short)((u + 0x7FFFu + ((u >> 16) & 1u)) >> 16);
}
__device__ __forceinline__ float bf2f(unsigned short u) {
    return __uint_as_float(((unsigned)u) << 16);
}
__device__ __forceinline__ unsigned cvt_pk_bf16(float a, float b) {
    unsigned r;
    asm("v_cvt_pk_bf16_f32 %0, %1, %2" : "=v"(r) : "v"(a), "v"(b));
    return r;
}
// tanh-form GELU, 8 insts (exp2 + v_rcp, no IEEE div)
__device__ __forceinline__ float gelu_t(float x) {
    float x2 = x * x;
    float t0 = fmaf(0.044715f * x2, x, x);
    float e = exp2f(2.3022227f * t0);           // exp(2*0.79788456*t0)
    float r = __builtin_amdgcn_rcpf(e + 1.0f);
    return fmaf(-x, r, x);                      // x * (1 - 1/(e+1))
}

// --------------------------- CPB MLP (both layers) -------------------------
__global__ __launch_bounds__(256) void k_cpb(
    const float* __restrict__ w1, const float* __restrict__ b1,
    const float* __restrict__ w2, float* __restrict__ out169) {
    int L = blockIdx.x / 169;
    int t = blockIdx.x % 169;
    const float* w1L = w1 + L * 1024;
    const float* b1L = b1 + L * 512;
    const float* w2L = w2 + L * 2048;
    float* outL = out169 + L * 704;
    int ia = t / 13, ib = t % 13;
    float r0 = (float)(ia - 6) * (8.0f / 6.0f);
    float s0 = (r0 > 0.f) ? 1.f : (r0 < 0.f ? -1.f : 0.f);
    float t0 = s0 * log2f(fabsf(r0) + 1.0f) * (1.0f / 3.0f);
    float r1 = (float)(ib - 6) * (8.0f / 6.0f);
    float s1 = (r1 > 0.f) ? 1.f : (r1 < 0.f ? -1.f : 0.f);
    float t1 = s1 * log2f(fabsf(r1) + 1.0f) * (1.0f / 3.0f);

    int tid = threadIdx.x;
    float p0 = 0, p1 = 0, p2 = 0, p3 = 0;
    for (int c = tid; c < 512; c += 256) {
        float hv = fmaxf(t0 * w1L[c] + t1 * w1L[512 + c] + b1L[c], 0.0f);
        p0 += hv * w2L[c * 4 + 0];
        p1 += hv * w2L[c * 4 + 1];
        p2 += hv * w2L[c * 4 + 2];
        p3 += hv * w2L[c * 4 + 3];
    }
    __shared__ float red[256][4];
    red[tid][0] = p0; red[tid][1] = p1; red[tid][2] = p2; red[tid][3] = p3;
    __syncthreads();
    for (int s = 128; s > 0; s >>= 1) {
        if (tid < s) {
            red[tid][0] += red[tid + s][0];
            red[tid][1] += red[tid + s][1];
            red[tid][2] += red[tid + s][2];
            red[tid][3] += red[tid + s][3];
        }
        __syncthreads();
    }
    if (tid < 4) outL[t * 4 + tid] = red[0][tid];
}

// rpb64[L][h][qrow64][krow64]; krow>=49 -> -30000 (k-pad baked in)
__global__ void k_rpb(const float* __restrict__ out169, float* __restrict__ rpb64) {
    int e2 = blockIdx.x * 256 + threadIdx.x;   // over 2 * 16384
    int L = e2 >> 14, e = e2 & 16383;
    int h = e >> 12, r = e & 4095;
    int i = r >> 6, j = r & 63;
    float val;
    if (j >= 49) {
        val = -30000.0f;
    } else if (i >= 49) {
        val = 0.0f;
    } else {
        int dp = i / 7 - j / 7 + 6;
        int dq = i % 7 - j % 7 + 6;
        float v = out169[L * 704 + (dp * 13 + dq) * 4 + h];
        val = 16.0f / (1.0f + expf(-v));
    }
    rpb64[e2] = val;
}

// ---------------- all weights fp32 -> bf16 tiled images, one pass ----------
// slot layout per region (Kb,N): tmp = slot>>6, nn = slot&63; kb = tmp%Kb,
// nt = tmp/Kb; element e: W[kb*8+e][nt*64+nn]; stored at nn'=(nn&~3)|((nn^kb)&3).
__device__ __forceinline__ void cvt_slot(
    const float* __restrict__ W, short* __restrict__ Wb, int slt, int Kb, int N) {
    int nn = slt & 63;
    int tmp = slt >> 6;
    int kb = tmp % Kb;
    int nt = tmp / Kb;
    int n = nt * 64 + nn;
    int k0 = kb * 8;
    union { int4 i4; short s8[8]; } u;
#pragma unroll
    for (int e = 0; e < 8; ++e) u.s8[e] = f2bf(W[(size_t)(k0 + e) * N + n]);
    int nns = (nn & ~3) | ((nn ^ kb) & 3);
    *(int4*)(Wb + (((size_t)tmp) * 64 + nns) * 8) = u.i4;
}

__global__ __launch_bounds__(256) void k_cvtall(
    const float* __restrict__ qkv_w, const float* __restrict__ proj_w,
    const float* __restrict__ mw1, const float* __restrict__ mw2,
    const float* __restrict__ pmw, short* __restrict__ wall) {
    int s = blockIdx.x * 256 + threadIdx.x;    // 0..65535
    short* wqkvb  = wall;                      // 2 x 49152 shorts
    short* wprojb = wall + 98304;              // 2 x 16384
    short* wm1b   = wall + 131072;             // 2 x 65536
    short* wm2b   = wall + 262144;             // 2 x 65536
    short* wpmb   = wall + 393216;             // 131072
    if (s < 12288) {
        int L = s / 6144, r = s % 6144;
        cvt_slot(qkv_w + L * 49152, wqkvb + L * 49152, r, 16, 384);
    } else if (s < 16384) {
        int s2 = s - 12288;
        int L = s2 / 2048, r = s2 % 2048;
        cvt_slot(proj_w + L * 16384, wprojb + L * 16384, r, 16, 128);
    } else if (s < 32768) {
        int s2 = s - 16384;
        int L = s2 / 8192, r = s2 % 8192;
        cvt_slot(mw1 + L * 65536, wm1b + L * 65536, r, 16, 512);
    } else if (s < 49152) {
        int s2 = s - 32768;
        int L = s2 / 8192, r = s2 % 8192;
        cvt_slot(mw2 + L * 65536, wm2b + L * 65536, r, 64, 128);
    } else {
        cvt_slot(pmw, wpmb, s - 49152, 64, 256);
    }
}

// ------------------- activation fp32 -> bf16 rows --------------------------
__global__ __launch_bounds__(256) void k_cvtx(
    const float* __restrict__ x, short* __restrict__ xb) {
    size_t e = ((size_t)blockIdx.x * 256 + threadIdx.x) * 8;
    const float* src = x + e;
    float4 f0 = *(const float4*)src;
    float4 f1 = *(const float4*)(src + 4);
    union { int4 i4; short s8[8]; } u;
    u.s8[0] = f2bf(f0.x); u.s8[1] = f2bf(f0.y);
    u.s8[2] = f2bf(f0.z); u.s8[3] = f2bf(f0.w);
    u.s8[4] = f2bf(f1.x); u.s8[5] = f2bf(f1.y);
    u.s8[6] = f2bf(f1.z); u.s8[7] = f2bf(f1.w);
    *(int4*)(xb + e) = u.i4;
}

// --------------------------- MFMA GEMM (bf16 A) ----------------------------
// EPI: 0 = raw fp32; 1 = qkv bias -> bf16 out (stride 384), roll on A.
template <int K, int EPI, int NT>
__global__ __launch_bounds__(256) void k_gemm(
    const short* __restrict__ Ain, const short* __restrict__ Wb,
    const float* __restrict__ bias0, const float* __restrict__ bias1,
    void* __restrict__ Out, int ostride, int shift) {
    constexpr int Kb = K / 8;
    constexpr int NC = K / 128;
    __shared__ int4 As4[2048];  // [16 kb][128 m], XOR-swizzled (8-wide)
    __shared__ int4 Ws4[1024];  // [16 kb][64 nn], XOR-swizzled (4-wide, in image)
    int tid = threadIdx.x;
    int nwg = gridDim.x;
    int chunk = nwg >> 3;
    int lid = (blockIdx.x & 7) * chunk + (blockIdx.x >> 3);
    int mt = lid / NT, nt = lid - mt * NT;
    int mb = mt * 128;
    int w = tid >> 6, l = tid & 63, lr = l & 15, lg = l >> 4;
    const f32x4 fz = {0.f, 0.f, 0.f, 0.f};
    f32x4 acc[2][4];
#pragma unroll
    for (int mi = 0; mi < 2; ++mi)
#pragma unroll
        for (int ni = 0; ni < 4; ++ni) acc[mi][ni] = fz;

    for (int c = 0; c < NC; ++c) {
        if (c) __syncthreads();
#pragma unroll
        for (int it = 0; it < 8; ++it) {
            int s = it * 256 + tid;
            int m = s >> 4, kb = s & 15;
            int gm = mb + m;
            if (EPI == 1 && shift) {
                int b = gm / 3136, r = gm % 3136;
                int hh = r / 56 + shift; if (hh >= 56) hh -= 56;
                int ww = r % 56 + shift; if (ww >= 56) ww -= 56;
                gm = b * 3136 + hh * 56 + ww;
            }
            int slot = kb * 128 + ((m & ~7) | ((m ^ kb) & 7));
            As4[slot] = *(const int4*)(Ain + (size_t)gm * K + c * 128 + kb * 8);
        }
        {
            const int4* wsrc = (const int4*)(Wb + ((size_t)nt * Kb + c * 16) * 64 * 8);
#pragma unroll
            for (int it = 0; it < 4; ++it) Ws4[it * 256 + tid] = wsrc[it * 256 + tid];
        }
        __syncthreads();
#pragma unroll
        for (int kk = 0; kk < 4; ++kk) {
            int kbl = kk * 4 + lg;
            int m0 = w * 32 + lr;
            bf16x8 a0 = *(const bf16x8*)&As4[kbl * 128 + ((m0 & ~7) | ((m0 ^ kbl) & 7))];
            int m1 = m0 + 16;
            bf16x8 a1 = *(const bf16x8*)&As4[kbl * 128 + ((m1 & ~7) | ((m1 ^ kbl) & 7))];
#pragma unroll
            for (int ni = 0; ni < 4; ++ni) {
                int nn = lr + 16 * ni;
                bf16x8 bfr = *(const bf16x8*)&Ws4[kbl * 64 + ((nn & ~3) | ((nn ^ kbl) & 3))];
                acc[0][ni] = __builtin_amdgcn_mfma_f32_16x16x32_bf16(a0, bfr, acc[0][ni], 0, 0, 0);
                acc[1][ni] = __builtin_amdgcn_mfma_f32_16x16x32_bf16(a1, bfr, acc[1][ni], 0, 0, 0);
            }
        }
    }
#pragma unroll
    for (int ni = 0; ni < 4; ++ni) {
        int col = nt * 64 + ni * 16 + lr;
        float bv = 0.f;
        if (EPI == 1) bv = (col < 128) ? bias0[col] : ((col < 256) ? 0.f : bias1[col - 256]);
#pragma unroll
        for (int mi = 0; mi < 2; ++mi) {
#pragma unroll
            for (int r = 0; r < 4; ++r) {
                int row = mb + w * 32 + mi * 16 + lg * 4 + r;
                float v = acc[mi][ni][r] + bv;
                if (EPI == 0) {
                    ((float*)Out)[(size_t)row * ostride + col] = v;
                } else {
                    ((short*)Out)[(size_t)row * 384 + col] = f2bf(v);
                }
            }
        }
    }
}

// ------------- MFMA GEMM + bias + LN + residual (+roll-back) ---------------
// Attention projection (K=128). Residual fp32 (RF32) or bf16; bf16 store.
template <int K, bool RF32>
__global__ __launch_bounds__(256) void k_gemm_ln(
    const short* __restrict__ Ain, const short* __restrict__ Wb,
    const float* __restrict__ bias, const float* __restrict__ g,
    const float* __restrict__ bt, const void* __restrict__ resid,
    short* __restrict__ xoutb, int shift) {
    constexpr int Kb = K / 8;
    constexpr int NC = K / 128;
    __shared__ int4 As4[1024];  // [16 kb][64 m]
    __shared__ int4 Ws4[2048];  // [2 ntw][16 kb][64 nn]
    int tid = threadIdx.x;
    int mb = blockIdx.x * 64;
    int w = tid >> 6, l = tid & 63, lr = l & 15, lg = l >> 4;
    const f32x4 fz = {0.f, 0.f, 0.f, 0.f};
    f32x4 acc[8];
#pragma unroll
    for (int ni = 0; ni < 8; ++ni) acc[ni] = fz;

    for (int c = 0; c < NC; ++c) {
        if (c) __syncthreads();
#pragma unroll
        for (int it = 0; it < 4; ++it) {
            int s = it * 256 + tid;
            int m = s >> 4, kb = s & 15;
            int slot = kb * 64 + ((m & ~7) | ((m ^ kb) & 7));
            As4[slot] = *(const int4*)(Ain + (size_t)(mb + m) * K + c * 128 + kb * 8);
        }
        {
            const int4* w0 = (const int4*)(Wb + ((size_t)(c * 16)) * 64 * 8);
            const int4* w1 = (const int4*)(Wb + ((size_t)(Kb + c * 16)) * 64 * 8);
#pragma unroll
            for (int it = 0; it < 4; ++it) {
                Ws4[it * 256 + tid] = w0[it * 256 + tid];
                Ws4[1024 + it * 256 + tid] = w1[it * 256 + tid];
            }
        }
        __syncthreads();
#pragma unroll
        for (int kk = 0; kk < 4; ++kk) {
            int kbl = kk * 4 + lg;
            int m0 = w * 16 + lr;
            bf16x8 a0 = *(const bf16x8*)&As4[kbl * 64 + ((m0 & ~7) | ((m0 ^ kbl) & 7))];
#pragma unroll
            for (int ni = 0; ni < 8; ++ni) {
                int nn = lr + 16 * (ni & 3);
                bf16x8 bfr = *(const bf16x8*)&Ws4[(ni >> 2) * 1024 + kbl * 64 +
                                                  ((nn & ~3) | ((nn ^ kbl) & 3))];
                acc[ni] = __builtin_amdgcn_mfma_f32_16x16x32_bf16(a0, bfr, acc[ni], 0, 0, 0);
            }
        }
    }
    float bv[8], gv[8], btv[8];
#pragma unroll
    for (int ni = 0; ni < 8; ++ni) {
        int col = ni * 16 + lr;
        bv[ni] = bias[col]; gv[ni] = g[col]; btv[ni] = bt[col];
    }
#pragma unroll
    for (int r = 0; r < 4; ++r) {
        int row = mb + w * 16 + lg * 4 + r;
        float v[8];
        float s1 = 0.f, s2 = 0.f;
#pragma unroll
        for (int ni = 0; ni < 8; ++ni) {
            v[ni] = acc[ni][r] + bv[ni];
            s1 += v[ni];
            s2 = fmaf(v[ni], v[ni], s2);
        }
#pragma unroll
        for (int off = 8; off >= 1; off >>= 1) {
            s1 += __shfl_xor(s1, off);
            s2 += __shfl_xor(s2, off);
        }
        float mean = s1 * (1.0f / 128.0f);
        float var = s2 * (1.0f / 128.0f) - mean * mean;
        float rstd = rsqrtf(var + 1e-5f);
        int mo = row;
        if (shift) {
            int b = row / 3136, rr = row % 3136;
            int hh = rr / 56 + shift; if (hh >= 56) hh -= 56;
            int ww = rr % 56 + shift; if (ww >= 56) ww -= 56;
            mo = b * 3136 + hh * 56 + ww;
        }
        size_t base = (size_t)mo * 128;
#pragma unroll
        for (int ni = 0; ni < 8; ++ni) {
            int col = ni * 16 + lr;
            float rv = RF32 ? ((const float*)resid)[base + col]
                            : bf2f(((const unsigned short*)resid)[base + col]);
            float o = rv + (v[ni] - mean) * rstd * gv[ni] + btv[ni];
            xoutb[base + col] = f2bf(o);
        }
    }
}

// -------------------- Fused MLP: fc1 + GELU + fc2 + LN + residual ----------
// In-place on xb. BM=128, 4 waves x 32 rows. T14: next chunk's W issued to
// registers before compute, ds_write after the post-compute barrier.
__global__ __launch_bounds__(256) void k_mlp(
    short* __restrict__ xb, const short* __restrict__ W1b,
    const short* __restrict__ W2b, const float* __restrict__ b1,
    const float* __restrict__ b2, const float* __restrict__ g,
    const float* __restrict__ bt) {
    __shared__ int4 W1s[1024];       // chunk: [16 kb][64 nn] (swizzled image)
    __shared__ int4 W2s[1024];       // chunk: [2 ntw][8 kb][64 nn]
    __shared__ short Hs[4 * 2304];   // hid: [4 wave][32 tok][72] (wave-private)
    int tid = threadIdx.x;
    int mb = blockIdx.x * 128;
    int w = tid >> 6, l = tid & 63, lr = l & 15, lg = l >> 4;
    const f32x4 fz = {0.f, 0.f, 0.f, 0.f};
    short* Hw = Hs + w * 2304;

    int4 xfrag[2][4];
#pragma unroll
    for (int mi = 0; mi < 2; ++mi)
#pragma unroll
        for (int kk = 0; kk < 4; ++kk)
            xfrag[mi][kk] = *(const int4*)(
                xb + (size_t)(mb + w * 32 + mi * 16 + lr) * 128 + kk * 32 + lg * 8);

    f32x4 acc2[2][8];
#pragma unroll
    for (int mi = 0; mi < 2; ++mi)
#pragma unroll
        for (int ni = 0; ni < 8; ++ni) acc2[mi][ni] = fz;

    int4 wr0, wr1, wr2, wr3, wr4, wr5, wr6, wr7;
#define LOADW(c)                                                            \
    {                                                                       \
        const int4* w1src = (const int4*)(W1b + (size_t)(c) * 8192);        \
        wr0 = w1src[tid]; wr1 = w1src[256 + tid];                           \
        wr2 = w1src[512 + tid]; wr3 = w1src[768 + tid];                     \
        const int4* w2a = (const int4*)(W2b + (size_t)((c) * 8) * 512);     \
        const int4* w2c = (const int4*)(W2b + (size_t)(64 + (c) * 8) * 512);\
        wr4 = w2a[tid]; wr5 = w2a[256 + tid];                               \
        wr6 = w2c[tid]; wr7 = w2c[256 + tid];                               \
    }
#define STOREW()                                                            \
    {                                                                       \
        W1s[tid] = wr0; W1s[256 + tid] = wr1;                               \
        W1s[512 + tid] = wr2; W1s[768 + tid] = wr3;                         \
        W2s[tid] = wr4; W2s[256 + tid] = wr5;                               \
        W2s[512 + tid] = wr6; W2s[768 + tid] = wr7;                         \
    }

    LOADW(0);
    STOREW();
    __syncthreads();

    for (int c = 0; c < 8; ++c) {
        if (c < 7) LOADW(c + 1);   // in flight across this chunk's compute
        // fc1 (swapped operands): Ht rows = hid cols, cols = token (lr)
        f32x4 a1[2][4];
#pragma unroll
        for (int mi = 0; mi < 2; ++mi)
#pragma unroll
            for (int ct = 0; ct < 4; ++ct) a1[mi][ct] = fz;
        __builtin_amdgcn_s_setprio(1);
#pragma unroll
        for (int kk = 0; kk < 4; ++kk) {
            int kbl = kk * 4 + lg;
            FragU xa0; xa0.i4 = xfrag[0][kk];
            FragU xa1; xa1.i4 = xfrag[1][kk];
#pragma unroll
            for (int ct = 0; ct < 4; ++ct) {
                int nn = lr + 16 * ct;
                bf16x8 w1f = *(const bf16x8*)&W1s[kbl * 64 + ((nn & ~3) | ((nn ^ kbl) & 3))];
                a1[0][ct] = __builtin_amdgcn_mfma_f32_16x16x32_bf16(w1f, xa0.b8, a1[0][ct], 0, 0, 0);
                a1[1][ct] = __builtin_amdgcn_mfma_f32_16x16x32_bf16(w1f, xa1.b8, a1[1][ct], 0, 0, 0);
            }
        }
        __builtin_amdgcn_s_setprio(0);
        // bias + gelu + pack
#pragma unroll
        for (int mi = 0; mi < 2; ++mi) {
#pragma unroll
            for (int ct = 0; ct < 4; ++ct) {
                float4 bb = *(const float4*)(b1 + c * 64 + ct * 16 + lg * 4);
                float h0 = gelu_t(a1[mi][ct][0] + bb.x);
                float h1 = gelu_t(a1[mi][ct][1] + bb.y);
                float h2 = gelu_t(a1[mi][ct][2] + bb.z);
                float h3 = gelu_t(a1[mi][ct][3] + bb.w);
                unsigned p0 = cvt_pk_bf16(h0, h1);
                unsigned p1 = cvt_pk_bf16(h2, h3);
                *(int2*)&Hw[(mi * 16 + lr) * 72 + ct * 16 + lg * 4] =
                    make_int2((int)p0, (int)p1);
            }
        }
        // fc2 accumulate (K=64 chunk)
        __builtin_amdgcn_s_setprio(1);
#pragma unroll
        for (int kc = 0; kc < 2; ++kc) {
            int kbl = kc * 4 + lg;
            FragU ha0; ha0.i4 = *(const int4*)&Hw[lr * 72 + kc * 32 + lg * 8];
            FragU ha1; ha1.i4 = *(const int4*)&Hw[(16 + lr) * 72 + kc * 32 + lg * 8];
#pragma unroll
            for (int ni = 0; ni < 8; ++ni) {
                int nn = lr + 16 * (ni & 3);
                bf16x8 w2f = *(const bf16x8*)&W2s[(ni >> 2) * 512 + kbl * 64 +
                                                  ((nn & ~3) | ((nn ^ kbl) & 3))];
                acc2[0][ni] = __builtin_amdgcn_mfma_f32_16x16x32_bf16(ha0.b8, w2f, acc2[0][ni], 0, 0, 0);
                acc2[1][ni] = __builtin_amdgcn_mfma_f32_16x16x32_bf16(ha1.b8, w2f, acc2[1][ni], 0, 0, 0);
            }
        }
        __builtin_amdgcn_s_setprio(0);
        if (c < 7) {
            __syncthreads();   // all waves done reading chunk c
            STOREW();          // vmcnt wait folded here, overlapped w/ compute
            __syncthreads();   // chunk c+1 visible
        }
    }
#undef LOADW
#undef STOREW

    // LN + residual epilogue (fp32 math, bf16 storage, in-place)
    float bv[8], gv[8], btv[8];
#pragma unroll
    for (int ni = 0; ni < 8; ++ni) {
        int col = ni * 16 + lr;
        bv[ni] = b2[col]; gv[ni] = g[col]; btv[ni] = bt[col];
    }
#pragma unroll
    for (int mi = 0; mi < 2; ++mi) {
#pragma unroll
        for (int r = 0; r < 4; ++r) {
            int row = mb + w * 32 + mi * 16 + lg * 4 + r;
            float v[8];
            float s1 = 0.f, s2 = 0.f;
#pragma unroll
            for (int ni = 0; ni < 8; ++ni) {
                v[ni] = acc2[mi][ni][r] + bv[ni];
                s1 += v[ni];
                s2 = fmaf(v[ni], v[ni], s2);
            }
#pragma unroll
            for (int off = 8; off >= 1; off >>= 1) {
                s1 += __shfl_xor(s1, off);
                s2 += __shfl_xor(s2, off);
            }
            float mean = s1 * (1.0f / 128.0f);
            float var = s2 * (1.0f / 128.0f) - mean * mean;
            float rstd = rsqrtf(var + 1e-5f);
            size_t base = (size_t)row * 128;
#pragma unroll
            for (int ni = 0; ni < 8; ++ni) {
                int col = ni * 16 + lr;
                float rv = bf2f(((const unsigned short*)xb)[base + col]);
                float o = rv + (v[ni] - mean) * rstd * gv[ni] + btv[ni];
                xb[base + col] = f2bf(o);
            }
        }
    }
}

// --------------------------- MFMA windowed attention -----------------------
__global__ __launch_bounds__(256) void k_attn(
    const short* __restrict__ qkv, const float* __restrict__ rpb64,
    const float* __restrict__ ls, short* __restrict__ aout, int shift) {
    __shared__ short lds[4 * 3584];
    int wid = blockIdx.x;
    int b = wid >> 6, wrem = wid & 63;
    int wh = wrem >> 3, ww_ = wrem & 7;
    int h = threadIdx.x >> 6;
    int l = threadIdx.x & 63, lr = l & 15, lg = l >> 4;
    short* Pt = lds + h * 3584;              // [16 qrow][72]
    short* Vt = Pt + 1152;                   // [32 d][72]
    float* invks = (float*)(Vt + 2304);      // [64] 1/||k_j||
    int tokbase = b * 3136 + wh * 7 * 56 + ww_ * 7;

    float scale = __expf(fminf(ls[h], 4.6051702f));  // ln(100)
    int4 qf[4], kf[4], vf[4];
    const int4 zero4 = make_int4(0, 0, 0, 0);
#pragma unroll
    for (int t = 0; t < 4; ++t) {
        int i = t * 16 + lr;
        bool valid = (i < 49);
        int tok = tokbase + (i / 7) * 56 + (i % 7);
        const short* base = qkv + (size_t)tok * 384 + h * 32 + lg * 8;
        qf[t] = valid ? *(const int4*)base : zero4;
        kf[t] = valid ? *(const int4*)(base + 128) : zero4;
    }
#pragma unroll
    for (int t = 0; t < 4; ++t) {
        int e = t * 64 + l;
        int j = e >> 2, dq = e & 3;
        if (j < 49) {
            int tok = tokbase + (j / 7) * 56 + (j % 7);
            vf[t] = *(const int4*)(qkv + (size_t)tok * 384 + 256 + h * 32 + dq * 8);
        } else {
            vf[t] = zero4;
        }
    }

    float invq[4];
#pragma unroll
    for (int t = 0; t < 4; ++t) {
        {
            FragU u; u.i4 = qf[t];
            float ss = 0.f;
#pragma unroll
            for (int e = 0; e < 8; ++e) { float x = bf2f(u.u[e]); ss = fmaf(x, x, ss); }
            ss += __shfl_xor(ss, 16);
            ss += __shfl_xor(ss, 32);
            invq[t] = scale / fmaxf(sqrtf(ss), 1e-12f);
        }
        {
            FragU u; u.i4 = kf[t];
            float ss = 0.f;
#pragma unroll
            for (int e = 0; e < 8; ++e) { float x = bf2f(u.u[e]); ss = fmaf(x, x, ss); }
            ss += __shfl_xor(ss, 16);
            ss += __shfl_xor(ss, 32);
            float ik = 1.0f / fmaxf(sqrtf(ss), 1e-12f);
            if (l < 16) invks[t * 16 + l] = ik;
        }
    }

    for (int t = l; t < 480; t += 64) {
        Vt[(t / 15) * 72 + 49 + (t % 15)] = 0;
    }
#pragma unroll
    for (int t = 0; t < 4; ++t) {
        int e = t * 64 + l;
        int j = e >> 2, dq = e & 3;
        if (j < 49) {
            FragU u; u.i4 = vf[t];
#pragma unroll
            for (int ee = 0; ee < 8; ++ee) Vt[(dq * 8 + ee) * 72 + j] = (short)u.u[ee];
        }
    }

    float ika[4][4];
#pragma unroll
    for (int jt = 0; jt < 4; ++jt) {
        float4 v4 = *(const float4*)&invks[jt * 16 + lg * 4];
        ika[jt][0] = v4.x; ika[jt][1] = v4.y; ika[jt][2] = v4.z; ika[jt][3] = v4.w;
    }

    bool edge = (shift != 0) && ((wh == 7) || (ww_ == 7));
    const float* rbase = rpb64 + h * 4096;
    const f32x4 fz = {0.f, 0.f, 0.f, 0.f};
    f32x4 oacc[2][4];
#pragma unroll
    for (int mi = 0; mi < 2; ++mi)
#pragma unroll
        for (int ni = 0; ni < 4; ++ni) oacc[mi][ni] = fz;

#pragma unroll
    for (int qt = 0; qt < 4; ++qt) {
        f32x4 at[4];
        __builtin_amdgcn_s_setprio(1);
#pragma unroll
        for (int jt = 0; jt < 4; ++jt) {
            FragU a; a.i4 = kf[jt];
            FragU bq; bq.i4 = qf[qt];
            at[jt] = __builtin_amdgcn_mfma_f32_16x16x32_bf16(a.b8, bq.b8, fz, 0, 0, 0);
        }
        __builtin_amdgcn_s_setprio(0);

        float iq = invq[qt];
        int qi = qt * 16 + lr;
        int qc = (qi < 49) ? qi : 48;
        int rlq = 0, clq = 0;
        if (edge) {
            rlq = (wh == 7) ? ((qc / 7) < 4 ? 1 : 2) : 0;
            clq = (ww_ == 7) ? ((qc % 7) < 4 ? 1 : 2) : 0;
        }
#pragma unroll
        for (int jt = 0; jt < 4; ++jt) {
            float4 rv = *(const float4*)(rbase + qc * 64 + jt * 16 + lg * 4);
            float rr[4] = {rv.x, rv.y, rv.z, rv.w};
#pragma unroll
            for (int r = 0; r < 4; ++r) {
                float v = fmaf(at[jt][r] * ika[jt][r], iq, rr[r]);
                if (edge) {
                    int j = jt * 16 + lg * 4 + r;
                    int jc = (j < 49) ? j : 48;
                    int rlk = (wh == 7) ? ((jc / 7) < 4 ? 1 : 2) : 0;
                    int clk = (ww_ == 7) ? ((jc % 7) < 4 ? 1 : 2) : 0;
                    if (rlk != rlq || clk != clq) v -= 100.0f;
                }
                at[jt][r] = v;
            }
        }
        float m = -1e30f;
#pragma unroll
        for (int jt = 0; jt < 4; ++jt)
#pragma unroll
            for (int r = 0; r < 4; ++r) m = fmaxf(m, at[jt][r]);
        m = fmaxf(m, __shfl_xor(m, 16));
        m = fmaxf(m, __shfl_xor(m, 32));
        float s = 0.f;
#pragma unroll
        for (int jt = 0; jt < 4; ++jt)
#pragma unroll
            for (int r = 0; r < 4; ++r) {
                float p = __expf(at[jt][r] - m);
                at[jt][r] = p;
                s += p;
            }
        s += __shfl_xor(s, 16);
        s += __shfl_xor(s, 32);
        float inv = 1.0f / s;
#pragma unroll
        for (int jt = 0; jt < 4; ++jt) {
            unsigned lo = cvt_pk_bf16(at[jt][0] * inv, at[jt][1] * inv);
            unsigned hi = cvt_pk_bf16(at[jt][2] * inv, at[jt][3] * inv);
            *(int2*)&Pt[lr * 72 + jt * 16 + lg * 4] = make_int2((int)lo, (int)hi);
        }
        __builtin_amdgcn_s_setprio(1);
#pragma unroll
        for (int kc = 0; kc < 2; ++kc) {
            FragU pb;
            pb.i4 = *(const int4*)&Pt[lr * 72 + kc * 32 + lg * 8];
#pragma unroll
            for (int mi = 0; mi < 2; ++mi) {
                FragU va;
                va.i4 = *(const int4*)&Vt[(mi * 16 + lr) * 72 + kc * 32 + lg * 8];
                oacc[mi][qt] = __builtin_amdgcn_mfma_f32_16x16x32_bf16(
                    va.b8, pb.b8, oacc[mi][qt], 0, 0, 0);
            }
        }
        __builtin_amdgcn_s_setprio(0);
    }

#pragma unroll
    for (int ni = 0; ni < 4; ++ni) {
        int qrow = ni * 16 + lr;
        if (qrow < 49) {
            int tok = tokbase + (qrow / 7) * 56 + (qrow % 7);
#pragma unroll
            for (int mi = 0; mi < 2; ++mi) {
                unsigned lo = cvt_pk_bf16(oacc[mi][ni][0], oacc[mi][ni][1]);
                unsigned hi = cvt_pk_bf16(oacc[mi][ni][2], oacc[mi][ni][3]);
                *(int2*)&aout[(size_t)tok * 128 + h * 32 + mi * 16 + lg * 4] =
                    make_int2((int)lo, (int)hi);
            }
        }
    }
}

// ------------- PatchMerging gather + LN -> bf16 rows [25088][512] ----------
__global__ __launch_bounds__(256) void k_pmln(
    const short* __restrict__ x, const float* __restrict__ g,
    const float* __restrict__ bt, short* __restrict__ outb) {
    int m2 = blockIdx.x * 4 + (threadIdx.x >> 6);
    int l = threadIdx.x & 63;
    int b = m2 / 784, r = m2 % 784;
    int h2 = r / 28, w2 = r % 28;
    int q0 = l * 8;
    int i2 = q0 >> 8, j2 = (q0 >> 7) & 1, c = q0 & 127;
    const short* src = x + (size_t)((b * 56 + 2 * h2 + i2) * 56 + 2 * w2 + j2) * 128 + c;
    FragU u; u.i4 = *(const int4*)src;
    float v[8];
#pragma unroll
    for (int e = 0; e < 8; ++e) v[e] = bf2f(u.u[e]);
    float s1 = 0.f, s2 = 0.f;
#pragma unroll
    for (int e = 0; e < 8; ++e) { s1 += v[e]; s2 = fmaf(v[e], v[e], s2); }
#pragma unroll
    for (int off = 32; off >= 1; off >>= 1) {
        s1 += __shfl_xor(s1, off);
        s2 += __shfl_xor(s2, off);
    }
    float mean = s1 * (1.0f / 512.0f);
    float var = s2 * (1.0f / 512.0f) - mean * mean;
    float rstd = rsqrtf(var + 1e-5f);
    union { int4 i4; short s8[8]; } o;
#pragma unroll
    for (int e = 0; e < 8; ++e)
        o.s8[e] = f2bf((v[e] - mean) * rstd * g[q0 + e] + bt[q0 + e]);
    *(int4*)(outb + (size_t)m2 * 512 + q0) = o.i4;
}

// ---------------------------------------------------------------------------
extern "C" void kernel_launch(void* const* d_in, const int* in_sizes, int n_in,
                              void* d_out, int out_size, void* d_ws, size_t ws_size,
                              hipStream_t stream) {
    const float* x_in   = (const float*)d_in[0];
    const float* qkv_w  = (const float*)d_in[1];
    const float* q_bias = (const float*)d_in[2];
    const float* v_bias = (const float*)d_in[3];
    const float* lscale = (const float*)d_in[4];
    const float* cpb_w1 = (const float*)d_in[5];
    const float* cpb_b1 = (const float*)d_in[6];
    const float* cpb_w2 = (const float*)d_in[7];
    const float* proj_w = (const float*)d_in[8];
    const float* proj_b = (const float*)d_in[9];
    const float* n1g    = (const float*)d_in[10];
    const float* n1b    = (const float*)d_in[11];
    const float* mw1    = (const float*)d_in[12];
    const float* mb1    = (const float*)d_in[13];
    const float* mw2    = (const float*)d_in[14];
    const float* mb2    = (const float*)d_in[15];
    const float* n2g    = (const float*)d_in[16];
    const float* n2b    = (const float*)d_in[17];
    const float* pmg    = (const float*)d_in[18];
    const float* pmb    = (const float*)d_in[19];
    const float* pmw    = (const float*)d_in[20];
    float* out = (float*)d_out;

    // front region: weight images + cpb tables (xcur's old slot)
    float* wsf    = (float*)d_ws;
    short* wall   = (short*)wsf;                 // 524,288 shorts
    short* wqkvb  = wall;                        // 2 x 49,152
    short* wprojb = wall + 98304;                // 2 x 16,384
    short* wm1b   = wall + 131072;               // 2 x 65,536
    short* wm2b   = wall + 262144;               // 2 x 65,536
    short* wpmb   = wall + 393216;               // 131,072
    float* out169 = wsf + 262144;                // 2 x 704
    float* rpb64  = out169 + 1408;               // 2 x 16,384

    float* R1      = wsf + (size_t)12845056;
    short* qkvb    = (short*)R1;
    short* attnout = (short*)(R1 + (size_t)19267584);   // kTok*128 bf16
    short* pmin    = (short*)R1;                        // 25088*512 bf16
    short* xb      = (short*)(R1 + (size_t)25690112);   // kTok*128 bf16

    k_cvtall<<<256, 256, 0, stream>>>(qkv_w, proj_w, mw1, mw2, pmw, wall);
    k_cpb<<<338, 256, 0, stream>>>(cpb_w1, cpb_b1, cpb_w2, out169);
    k_rpb<<<128, 256, 0, stream>>>(out169, rpb64);
    k_cvtx<<<6272, 256, 0, stream>>>(x_in, xb);

    for (int i = 0; i < 2; ++i) {
        int shift = i ? 3 : 0;
        k_gemm<128, 1, 6><<<4704, 256, 0, stream>>>(
            xb, wqkvb + i * 49152, q_bias + i * 128, v_bias + i * 128,
            qkvb, 384, shift);
        k_attn<<<2048, 256, 0, stream>>>(
            qkvb, rpb64 + i * 16384, lscale + i * 4, attnout, shift);
        if (i == 0) {
            k_gemm_ln<128, true><<<1568, 256, 0, stream>>>(
                attnout, wprojb, proj_b, n1g, n1b, x_in, xb, shift);
        } else {
            k_gemm_ln<128, false><<<1568, 256, 0, stream>>>(
                attnout, wprojb + 16384, proj_b + 128, n1g + 128, n1b + 128,
                xb, xb, shift);
        }
        k_mlp<<<784, 256, 0, stream>>>(
            xb, wm1b + i * 65536, wm2b + i * 65536, mb1 + i * 512,
            mb2 + i * 128, n2g + i * 128, n2b + i * 128);
    }
    k_pmln<<<6272, 256, 0, stream>>>(xb, pmg, pmb, pmin);
    k_gemm<512, 0, 4><<<784, 256, 0, stream>>>(
        pmin, wpmb, nullptr, nullptr, out, 256, 0);
}

// Round 14
// 354.821 us; speedup vs baseline: 1.3430x; 1.0720x over previous
//
#include <hip/hip_runtime.h>
#include <math.h>

// ---------------------------------------------------------------------------
// SwinV2 stage: B=32, H=W=56, C=128, NH=4, hd=32, WS=7, N=49, DEPTH=2, shift=3
// Round 14: qkv GEMM fused into attention (phase-1 swapped-MFMA qkv into a
// shared LDS token image; phase-2 per-head attention reads frags from LDS).
// qkvb buffer + 2 dispatches deleted. k_mlp reverted to R12 (no W-prefetch).
// ---------------------------------------------------------------------------

namespace {
constexpr int kTok = 32 * 56 * 56;   // 100352 tokens
}

typedef __attribute__((ext_vector_type(8))) short bf16x8;
typedef __attribute__((ext_vector_type(4))) float f32x4;

union FragU {
    int4 i4;
    bf16x8 b8;
    unsigned short u[8];
};

__device__ __forceinline__ short f2bf(float f) {
    unsigned u = __float_as_uint(f);
    return (short)((u + 0x7FFFu + ((u >> 16) & 1u)) >> 16);
}
__device__ __forceinline__ float bf2f(unsigned short u) {
    return __uint_as_float(((unsigned)u) << 16);
}
__device__ __forceinline__ unsigned cvt_pk_bf16(float a, float b) {
    unsigned r;
    asm("v_cvt_pk_bf16_f32 %0, %1, %2" : "=v"(r) : "v"(a), "v"(b));
    return r;
}
// tanh-form GELU, 8 insts (exp2 + v_rcp, no IEEE div)
__device__ __forceinline__ float gelu_t(float x) {
    float x2 = x * x;
    float t0 = fmaf(0.044715f * x2, x, x);
    float e = exp2f(2.3022227f * t0);           // exp(2*0.79788456*t0)
    float r = __builtin_amdgcn_rcpf(e + 1.0f);
    return fmaf(-x, r, x);                      // x * (1 - 1/(e+1))
}

// --------------------------- CPB MLP (both layers) -------------------------
__global__ __launch_bounds__(256) void k_cpb(
    const float* __restrict__ w1, const float* __restrict__ b1,
    const float* __restrict__ w2, float* __restrict__ out169) {
    int L = blockIdx.x / 169;
    int t = blockIdx.x % 169;
    const float* w1L = w1 + L * 1024;
    const float* b1L = b1 + L * 512;
    const float* w2L = w2 + L * 2048;
    float* outL = out169 + L * 704;
    int ia = t / 13, ib = t % 13;
    float r0 = (float)(ia - 6) * (8.0f / 6.0f);
    float s0 = (r0 > 0.f) ? 1.f : (r0 < 0.f ? -1.f : 0.f);
    float t0 = s0 * log2f(fabsf(r0) + 1.0f) * (1.0f / 3.0f);
    float r1 = (float)(ib - 6) * (8.0f / 6.0f);
    float s1 = (r1 > 0.f) ? 1.f : (r1 < 0.f ? -1.f : 0.f);
    float t1 = s1 * log2f(fabsf(r1) + 1.0f) * (1.0f / 3.0f);

    int tid = threadIdx.x;
    float p0 = 0, p1 = 0, p2 = 0, p3 = 0;
    for (int c = tid; c < 512; c += 256) {
        float hv = fmaxf(t0 * w1L[c] + t1 * w1L[512 + c] + b1L[c], 0.0f);
        p0 += hv * w2L[c * 4 + 0];
        p1 += hv * w2L[c * 4 + 1];
        p2 += hv * w2L[c * 4 + 2];
        p3 += hv * w2L[c * 4 + 3];
    }
    __shared__ float red[256][4];
    red[tid][0] = p0; red[tid][1] = p1; red[tid][2] = p2; red[tid][3] = p3;
    __syncthreads();
    for (int s = 128; s > 0; s >>= 1) {
        if (tid < s) {
            red[tid][0] += red[tid + s][0];
            red[tid][1] += red[tid + s][1];
            red[tid][2] += red[tid + s][2];
            red[tid][3] += red[tid + s][3];
        }
        __syncthreads();
    }
    if (tid < 4) outL[t * 4 + tid] = red[0][tid];
}

// rpb64[L][h][qrow64][krow64]; krow>=49 -> -30000 (k-pad baked in)
__global__ void k_rpb(const float* __restrict__ out169, float* __restrict__ rpb64) {
    int e2 = blockIdx.x * 256 + threadIdx.x;   // over 2 * 16384
    int L = e2 >> 14, e = e2 & 16383;
    int h = e >> 12, r = e & 4095;
    int i = r >> 6, j = r & 63;
    float val;
    if (j >= 49) {
        val = -30000.0f;
    } else if (i >= 49) {
        val = 0.0f;
    } else {
        int dp = i / 7 - j / 7 + 6;
        int dq = i % 7 - j % 7 + 6;
        float v = out169[L * 704 + (dp * 13 + dq) * 4 + h];
        val = 16.0f / (1.0f + expf(-v));
    }
    rpb64[e2] = val;
}

// ---------------- all weights fp32 -> bf16 tiled images, one pass ----------
__device__ __forceinline__ void cvt_slot(
    const float* __restrict__ W, short* __restrict__ Wb, int slt, int Kb, int N) {
    int nn = slt & 63;
    int tmp = slt >> 6;
    int kb = tmp % Kb;
    int nt = tmp / Kb;
    int n = nt * 64 + nn;
    int k0 = kb * 8;
    union { int4 i4; short s8[8]; } u;
#pragma unroll
    for (int e = 0; e < 8; ++e) u.s8[e] = f2bf(W[(size_t)(k0 + e) * N + n]);
    int nns = (nn & ~3) | ((nn ^ kb) & 3);
    *(int4*)(Wb + (((size_t)tmp) * 64 + nns) * 8) = u.i4;
}

__global__ __launch_bounds__(256) void k_cvtall(
    const float* __restrict__ qkv_w, const float* __restrict__ proj_w,
    const float* __restrict__ mw1, const float* __restrict__ mw2,
    const float* __restrict__ pmw, const float* __restrict__ qb,
    const float* __restrict__ vb, short* __restrict__ wall,
    float* __restrict__ bias384) {
    int s = blockIdx.x * 256 + threadIdx.x;
    short* wqkvb  = wall;                      // 2 x 49152 shorts
    short* wprojb = wall + 98304;              // 2 x 16384
    short* wm1b   = wall + 131072;             // 2 x 65536
    short* wm2b   = wall + 262144;             // 2 x 65536
    short* wpmb   = wall + 393216;             // 131072
    if (s < 12288) {
        int L = s / 6144, r = s % 6144;
        cvt_slot(qkv_w + L * 49152, wqkvb + L * 49152, r, 16, 384);
    } else if (s < 16384) {
        int s2 = s - 12288;
        int L = s2 / 2048, r = s2 % 2048;
        cvt_slot(proj_w + L * 16384, wprojb + L * 16384, r, 16, 128);
    } else if (s < 32768) {
        int s2 = s - 16384;
        int L = s2 / 8192, r = s2 % 8192;
        cvt_slot(mw1 + L * 65536, wm1b + L * 65536, r, 16, 512);
    } else if (s < 49152) {
        int s2 = s - 32768;
        int L = s2 / 8192, r = s2 % 8192;
        cvt_slot(mw2 + L * 65536, wm2b + L * 65536, r, 64, 128);
    } else if (s < 65536) {
        cvt_slot(pmw, wpmb, s - 49152, 64, 256);
    } else if (s < 66304) {
        int t = s - 65536;
        int L = t / 384, f = t % 384;
        float v = (f < 128) ? qb[L * 128 + f]
                            : ((f < 256) ? 0.0f : vb[L * 128 + f - 256]);
        bias384[t] = v;
    }
}

// ------------------- activation fp32 -> bf16 rows --------------------------
__global__ __launch_bounds__(256) void k_cvtx(
    const float* __restrict__ x, short* __restrict__ xb) {
    size_t e = ((size_t)blockIdx.x * 256 + threadIdx.x) * 8;
    const float* src = x + e;
    float4 f0 = *(const float4*)src;
    float4 f1 = *(const float4*)(src + 4);
    union { int4 i4; short s8[8]; } u;
    u.s8[0] = f2bf(f0.x); u.s8[1] = f2bf(f0.y);
    u.s8[2] = f2bf(f0.z); u.s8[3] = f2bf(f0.w);
    u.s8[4] = f2bf(f1.x); u.s8[5] = f2bf(f1.y);
    u.s8[6] = f2bf(f1.z); u.s8[7] = f2bf(f1.w);
    *(int4*)(xb + e) = u.i4;
}

// --------------------------- MFMA GEMM (bf16 A) ----------------------------
// Used for the PatchMerging tail (EPI=0, fp32 out).
template <int K, int NT>
__global__ __launch_bounds__(256) void k_gemm(
    const short* __restrict__ Ain, const short* __restrict__ Wb,
    float* __restrict__ Out, int ostride) {
    constexpr int Kb = K / 8;
    constexpr int NC = K / 128;
    __shared__ int4 As4[2048];
    __shared__ int4 Ws4[1024];
    int tid = threadIdx.x;
    int nwg = gridDim.x;
    int chunk = nwg >> 3;
    int lid = (blockIdx.x & 7) * chunk + (blockIdx.x >> 3);
    int mt = lid / NT, nt = lid - mt * NT;
    int mb = mt * 128;
    int w = tid >> 6, l = tid & 63, lr = l & 15, lg = l >> 4;
    const f32x4 fz = {0.f, 0.f, 0.f, 0.f};
    f32x4 acc[2][4];
#pragma unroll
    for (int mi = 0; mi < 2; ++mi)
#pragma unroll
        for (int ni = 0; ni < 4; ++ni) acc[mi][ni] = fz;

    for (int c = 0; c < NC; ++c) {
        if (c) __syncthreads();
#pragma unroll
        for (int it = 0; it < 8; ++it) {
            int s = it * 256 + tid;
            int m = s >> 4, kb = s & 15;
            int slot = kb * 128 + ((m & ~7) | ((m ^ kb) & 7));
            As4[slot] = *(const int4*)(Ain + (size_t)(mb + m) * K + c * 128 + kb * 8);
        }
        {
            const int4* wsrc = (const int4*)(Wb + ((size_t)nt * Kb + c * 16) * 64 * 8);
#pragma unroll
            for (int it = 0; it < 4; ++it) Ws4[it * 256 + tid] = wsrc[it * 256 + tid];
        }
        __syncthreads();
#pragma unroll
        for (int kk = 0; kk < 4; ++kk) {
            int kbl = kk * 4 + lg;
            int m0 = w * 32 + lr;
            bf16x8 a0 = *(const bf16x8*)&As4[kbl * 128 + ((m0 & ~7) | ((m0 ^ kbl) & 7))];
            int m1 = m0 + 16;
            bf16x8 a1 = *(const bf16x8*)&As4[kbl * 128 + ((m1 & ~7) | ((m1 ^ kbl) & 7))];
#pragma unroll
            for (int ni = 0; ni < 4; ++ni) {
                int nn = lr + 16 * ni;
                bf16x8 bfr = *(const bf16x8*)&Ws4[kbl * 64 + ((nn & ~3) | ((nn ^ kbl) & 3))];
                acc[0][ni] = __builtin_amdgcn_mfma_f32_16x16x32_bf16(a0, bfr, acc[0][ni], 0, 0, 0);
                acc[1][ni] = __builtin_amdgcn_mfma_f32_16x16x32_bf16(a1, bfr, acc[1][ni], 0, 0, 0);
            }
        }
    }
#pragma unroll
    for (int ni = 0; ni < 4; ++ni) {
        int col = nt * 64 + ni * 16 + lr;
#pragma unroll
        for (int mi = 0; mi < 2; ++mi) {
#pragma unroll
            for (int r = 0; r < 4; ++r) {
                int row = mb + w * 32 + mi * 16 + lg * 4 + r;
                Out[(size_t)row * ostride + col] = acc[mi][ni][r];
            }
        }
    }
}

// ------------- MFMA GEMM + bias + LN + residual (+roll-back) ---------------
template <int K, bool RF32>
__global__ __launch_bounds__(256) void k_gemm_ln(
    const short* __restrict__ Ain, const short* __restrict__ Wb,
    const float* __restrict__ bias, const float* __restrict__ g,
    const float* __restrict__ bt, const void* __restrict__ resid,
    short* __restrict__ xoutb, int shift) {
    constexpr int Kb = K / 8;
    constexpr int NC = K / 128;
    __shared__ int4 As4[1024];
    __shared__ int4 Ws4[2048];
    int tid = threadIdx.x;
    int mb = blockIdx.x * 64;
    int w = tid >> 6, l = tid & 63, lr = l & 15, lg = l >> 4;
    const f32x4 fz = {0.f, 0.f, 0.f, 0.f};
    f32x4 acc[8];
#pragma unroll
    for (int ni = 0; ni < 8; ++ni) acc[ni] = fz;

    for (int c = 0; c < NC; ++c) {
        if (c) __syncthreads();
#pragma unroll
        for (int it = 0; it < 4; ++it) {
            int s = it * 256 + tid;
            int m = s >> 4, kb = s & 15;
            int slot = kb * 64 + ((m & ~7) | ((m ^ kb) & 7));
            As4[slot] = *(const int4*)(Ain + (size_t)(mb + m) * K + c * 128 + kb * 8);
        }
        {
            const int4* w0 = (const int4*)(Wb + ((size_t)(c * 16)) * 64 * 8);
            const int4* w1 = (const int4*)(Wb + ((size_t)(Kb + c * 16)) * 64 * 8);
#pragma unroll
            for (int it = 0; it < 4; ++it) {
                Ws4[it * 256 + tid] = w0[it * 256 + tid];
                Ws4[1024 + it * 256 + tid] = w1[it * 256 + tid];
            }
        }
        __syncthreads();
#pragma unroll
        for (int kk = 0; kk < 4; ++kk) {
            int kbl = kk * 4 + lg;
            int m0 = w * 16 + lr;
            bf16x8 a0 = *(const bf16x8*)&As4[kbl * 64 + ((m0 & ~7) | ((m0 ^ kbl) & 7))];
#pragma unroll
            for (int ni = 0; ni < 8; ++ni) {
                int nn = lr + 16 * (ni & 3);
                bf16x8 bfr = *(const bf16x8*)&Ws4[(ni >> 2) * 1024 + kbl * 64 +
                                                  ((nn & ~3) | ((nn ^ kbl) & 3))];
                acc[ni] = __builtin_amdgcn_mfma_f32_16x16x32_bf16(a0, bfr, acc[ni], 0, 0, 0);
            }
        }
    }
    float bv[8], gv[8], btv[8];
#pragma unroll
    for (int ni = 0; ni < 8; ++ni) {
        int col = ni * 16 + lr;
        bv[ni] = bias[col]; gv[ni] = g[col]; btv[ni] = bt[col];
    }
#pragma unroll
    for (int r = 0; r < 4; ++r) {
        int row = mb + w * 16 + lg * 4 + r;
        float v[8];
        float s1 = 0.f, s2 = 0.f;
#pragma unroll
        for (int ni = 0; ni < 8; ++ni) {
            v[ni] = acc[ni][r] + bv[ni];
            s1 += v[ni];
            s2 = fmaf(v[ni], v[ni], s2);
        }
#pragma unroll
        for (int off = 8; off >= 1; off >>= 1) {
            s1 += __shfl_xor(s1, off);
            s2 += __shfl_xor(s2, off);
        }
        float mean = s1 * (1.0f / 128.0f);
        float var = s2 * (1.0f / 128.0f) - mean * mean;
        float rstd = rsqrtf(var + 1e-5f);
        int mo = row;
        if (shift) {
            int b = row / 3136, rr = row % 3136;
            int hh = rr / 56 + shift; if (hh >= 56) hh -= 56;
            int ww = rr % 56 + shift; if (ww >= 56) ww -= 56;
            mo = b * 3136 + hh * 56 + ww;
        }
        size_t base = (size_t)mo * 128;
#pragma unroll
        for (int ni = 0; ni < 8; ++ni) {
            int col = ni * 16 + lr;
            float rv = RF32 ? ((const float*)resid)[base + col]
                            : bf2f(((const unsigned short*)resid)[base + col]);
            float o = rv + (v[ni] - mean) * rstd * gv[ni] + btv[ni];
            xoutb[base + col] = f2bf(o);
        }
    }
}

// -------------------- Fused MLP: fc1 + GELU + fc2 + LN + residual ----------
// In-place on xb. BM=128, 4 waves x 32 rows (R12 structure).
__global__ __launch_bounds__(256) void k_mlp(
    short* __restrict__ xb, const short* __restrict__ W1b,
    const short* __restrict__ W2b, const float* __restrict__ b1,
    const float* __restrict__ b2, const float* __restrict__ g,
    const float* __restrict__ bt) {
    __shared__ int4 W1s[1024];
    __shared__ int4 W2s[1024];
    __shared__ short Hs[4 * 2304];
    int tid = threadIdx.x;
    int mb = blockIdx.x * 128;
    int w = tid >> 6, l = tid & 63, lr = l & 15, lg = l >> 4;
    const f32x4 fz = {0.f, 0.f, 0.f, 0.f};
    short* Hw = Hs + w * 2304;

    int4 xfrag[2][4];
#pragma unroll
    for (int mi = 0; mi < 2; ++mi)
#pragma unroll
        for (int kk = 0; kk < 4; ++kk)
            xfrag[mi][kk] = *(const int4*)(
                xb + (size_t)(mb + w * 32 + mi * 16 + lr) * 128 + kk * 32 + lg * 8);

    f32x4 acc2[2][8];
#pragma unroll
    for (int mi = 0; mi < 2; ++mi)
#pragma unroll
        for (int ni = 0; ni < 8; ++ni) acc2[mi][ni] = fz;

    for (int c = 0; c < 8; ++c) {
        __syncthreads();
        {
            const int4* w1src = (const int4*)(W1b + (size_t)c * 8192);
#pragma unroll
            for (int it = 0; it < 4; ++it) W1s[it * 256 + tid] = w1src[it * 256 + tid];
            const int4* w2a = (const int4*)(W2b + (size_t)(c * 8) * 512);
            const int4* w2c = (const int4*)(W2b + (size_t)(64 + c * 8) * 512);
#pragma unroll
            for (int it = 0; it < 2; ++it) {
                W2s[it * 256 + tid] = w2a[it * 256 + tid];
                W2s[512 + it * 256 + tid] = w2c[it * 256 + tid];
            }
        }
        __syncthreads();
        f32x4 a1[2][4];
#pragma unroll
        for (int mi = 0; mi < 2; ++mi)
#pragma unroll
            for (int ct = 0; ct < 4; ++ct) a1[mi][ct] = fz;
        __builtin_amdgcn_s_setprio(1);
#pragma unroll
        for (int kk = 0; kk < 4; ++kk) {
            int kbl = kk * 4 + lg;
            FragU xa0; xa0.i4 = xfrag[0][kk];
            FragU xa1; xa1.i4 = xfrag[1][kk];
#pragma unroll
            for (int ct = 0; ct < 4; ++ct) {
                int nn = lr + 16 * ct;
                bf16x8 w1f = *(const bf16x8*)&W1s[kbl * 64 + ((nn & ~3) | ((nn ^ kbl) & 3))];
                a1[0][ct] = __builtin_amdgcn_mfma_f32_16x16x32_bf16(w1f, xa0.b8, a1[0][ct], 0, 0, 0);
                a1[1][ct] = __builtin_amdgcn_mfma_f32_16x16x32_bf16(w1f, xa1.b8, a1[1][ct], 0, 0, 0);
            }
        }
        __builtin_amdgcn_s_setprio(0);
#pragma unroll
        for (int mi = 0; mi < 2; ++mi) {
#pragma unroll
            for (int ct = 0; ct < 4; ++ct) {
                float4 bb = *(const float4*)(b1 + c * 64 + ct * 16 + lg * 4);
                float h0 = gelu_t(a1[mi][ct][0] + bb.x);
                float h1 = gelu_t(a1[mi][ct][1] + bb.y);
                float h2 = gelu_t(a1[mi][ct][2] + bb.z);
                float h3 = gelu_t(a1[mi][ct][3] + bb.w);
                unsigned p0 = cvt_pk_bf16(h0, h1);
                unsigned p1 = cvt_pk_bf16(h2, h3);
                *(int2*)&Hw[(mi * 16 + lr) * 72 + ct * 16 + lg * 4] =
                    make_int2((int)p0, (int)p1);
            }
        }
        __builtin_amdgcn_s_setprio(1);
#pragma unroll
        for (int kc = 0; kc < 2; ++kc) {
            int kbl = kc * 4 + lg;
            FragU ha0; ha0.i4 = *(const int4*)&Hw[lr * 72 + kc * 32 + lg * 8];
            FragU ha1; ha1.i4 = *(const int4*)&Hw[(16 + lr) * 72 + kc * 32 + lg * 8];
#pragma unroll
            for (int ni = 0; ni < 8; ++ni) {
                int nn = lr + 16 * (ni & 3);
                bf16x8 w2f = *(const bf16x8*)&W2s[(ni >> 2) * 512 + kbl * 64 +
                                                  ((nn & ~3) | ((nn ^ kbl) & 3))];
                acc2[0][ni] = __builtin_amdgcn_mfma_f32_16x16x32_bf16(ha0.b8, w2f, acc2[0][ni], 0, 0, 0);
                acc2[1][ni] = __builtin_amdgcn_mfma_f32_16x16x32_bf16(ha1.b8, w2f, acc2[1][ni], 0, 0, 0);
            }
        }
        __builtin_amdgcn_s_setprio(0);
    }

    float bv[8], gv[8], btv[8];
#pragma unroll
    for (int ni = 0; ni < 8; ++ni) {
        int col = ni * 16 + lr;
        bv[ni] = b2[col]; gv[ni] = g[col]; btv[ni] = bt[col];
    }
#pragma unroll
    for (int mi = 0; mi < 2; ++mi) {
#pragma unroll
        for (int r = 0; r < 4; ++r) {
            int row = mb + w * 32 + mi * 16 + lg * 4 + r;
            float v[8];
            float s1 = 0.f, s2 = 0.f;
#pragma unroll
            for (int ni = 0; ni < 8; ++ni) {
                v[ni] = acc2[mi][ni][r] + bv[ni];
                s1 += v[ni];
                s2 = fmaf(v[ni], v[ni], s2);
            }
#pragma unroll
            for (int off = 8; off >= 1; off >>= 1) {
                s1 += __shfl_xor(s1, off);
                s2 += __shfl_xor(s2, off);
            }
            float mean = s1 * (1.0f / 128.0f);
            float var = s2 * (1.0f / 128.0f) - mean * mean;
            float rstd = rsqrtf(var + 1e-5f);
            size_t base = (size_t)row * 128;
#pragma unroll
            for (int ni = 0; ni < 8; ++ni) {
                int col = ni * 16 + lr;
                float rv = bf2f(((const unsigned short*)xb)[base + col]);
                float o = rv + (v[ni] - mean) * rstd * gv[ni] + btv[ni];
                xb[base + col] = f2bf(o);
            }
        }
    }
}

// ---------------- Fused qkv + windowed attention ---------------------------
// grid 2048, 4 waves. Phase 1: wave w computes qkv^T for tokens w*16..+15
// via swapped MFMA (W-image frags from L2), packs into shared qkvs LDS.
// Phase 2: wave h runs the per-head attention, reading frags from qkvs.
__global__ __launch_bounds__(256) void k_attn(
    const short* __restrict__ xb, const short* __restrict__ Wq,
    const float* __restrict__ bias384, const float* __restrict__ rpb64,
    const float* __restrict__ ls, short* __restrict__ aout, int shift) {
    __shared__ short qkvs[64 * 392];          // [tok][384+8]
    __shared__ short pvt[4 * 3584];           // per-wave Pt/Vt/invks
    int wid = blockIdx.x;
    int b = wid >> 6, wrem = wid & 63;
    int wh = wrem >> 3, ww_ = wrem & 7;
    int tid = threadIdx.x;
    int w = tid >> 6;
    int l = tid & 63, lr = l & 15, lg = l >> 4;
    int tokbase = b * 3136 + wh * 7 * 56 + ww_ * 7;
    const f32x4 fz = {0.f, 0.f, 0.f, 0.f};

    // ---------------- phase 1: qkv for tokens w*16+lr ----------------
    {
        int ti = w * 16 + lr;
        bool valid = (ti < 49);
        int4 xfrag[4];
        const int4 zero4 = make_int4(0, 0, 0, 0);
        if (valid) {
            int m = tokbase + (ti / 7) * 56 + (ti % 7);
            if (shift) {
                int bb2 = m / 3136, rr = m % 3136;
                int hh = rr / 56 + shift; if (hh >= 56) hh -= 56;
                int ww2 = rr % 56 + shift; if (ww2 >= 56) ww2 -= 56;
                m = bb2 * 3136 + hh * 56 + ww2;
            }
#pragma unroll
            for (int kk = 0; kk < 4; ++kk)
                xfrag[kk] = *(const int4*)(xb + (size_t)m * 128 + kk * 32 + lg * 8);
        } else {
#pragma unroll
            for (int kk = 0; kk < 4; ++kk) xfrag[kk] = zero4;
        }
        short* orow = qkvs + (w * 16 + lr) * 392;
#pragma unroll
        for (int ft = 0; ft < 24; ++ft) {
            f32x4 a = fz;
            int n = ft * 16 + lr;
            int nt = n >> 6, nn = n & 63;
#pragma unroll
            for (int kk = 0; kk < 4; ++kk) {
                int kbl = kk * 4 + lg;
                int nns = (nn & ~3) | ((nn ^ kbl) & 3);
                bf16x8 wf = *(const bf16x8*)(Wq + (((size_t)nt * 16 + kbl) * 64 + nns) * 8);
                FragU xa; xa.i4 = xfrag[kk];
                a = __builtin_amdgcn_mfma_f32_16x16x32_bf16(wf, xa.b8, a, 0, 0, 0);
            }
            float4 bb = *(const float4*)(bias384 + ft * 16 + lg * 4);
            unsigned p0 = cvt_pk_bf16(a[0] + bb.x, a[1] + bb.y);
            unsigned p1 = cvt_pk_bf16(a[2] + bb.z, a[3] + bb.w);
            *(int2*)&orow[ft * 16 + lg * 4] = make_int2((int)p0, (int)p1);
        }
    }
    __syncthreads();

    // ---------------- phase 2: attention, wave = head ----------------
    int h = w;
    short* Pt = pvt + h * 3584;              // [16 qrow][72]
    short* Vt = Pt + 1152;                   // [32 d][72]
    float* invks = (float*)(Vt + 2304);      // [64]

    float scale = __expf(fminf(ls[h], 4.6051702f));  // ln(100)
    int4 qf[4], kf[4];
#pragma unroll
    for (int t = 0; t < 4; ++t) {
        const short* base = qkvs + (t * 16 + lr) * 392 + h * 32 + lg * 8;
        qf[t] = *(const int4*)base;
        kf[t] = *(const int4*)(base + 128);
    }

    float invq[4];
#pragma unroll
    for (int t = 0; t < 4; ++t) {
        {
            FragU u; u.i4 = qf[t];
            float ss = 0.f;
#pragma unroll
            for (int e = 0; e < 8; ++e) { float x = bf2f(u.u[e]); ss = fmaf(x, x, ss); }
            ss += __shfl_xor(ss, 16);
            ss += __shfl_xor(ss, 32);
            invq[t] = scale / fmaxf(sqrtf(ss), 1e-12f);
        }
        {
            FragU u; u.i4 = kf[t];
            float ss = 0.f;
#pragma unroll
            for (int e = 0; e < 8; ++e) { float x = bf2f(u.u[e]); ss = fmaf(x, x, ss); }
            ss += __shfl_xor(ss, 16);
            ss += __shfl_xor(ss, 32);
            float ik = 1.0f / fmaxf(sqrtf(ss), 1e-12f);
            if (l < 16) invks[t * 16 + l] = ik;
        }
    }

    for (int t = l; t < 480; t += 64) {
        Vt[(t / 15) * 72 + 49 + (t % 15)] = 0;
    }
#pragma unroll
    for (int t = 0; t < 4; ++t) {
        int e = t * 64 + l;
        int j = e >> 2, dq = e & 3;
        if (j < 49) {
            FragU u;
            u.i4 = *(const int4*)(qkvs + j * 392 + 256 + h * 32 + dq * 8);
#pragma unroll
            for (int ee = 0; ee < 8; ++ee) Vt[(dq * 8 + ee) * 72 + j] = (short)u.u[ee];
        }
    }

    float ika[4][4];
#pragma unroll
    for (int jt = 0; jt < 4; ++jt) {
        float4 v4 = *(const float4*)&invks[jt * 16 + lg * 4];
        ika[jt][0] = v4.x; ika[jt][1] = v4.y; ika[jt][2] = v4.z; ika[jt][3] = v4.w;
    }

    bool edge = (shift != 0) && ((wh == 7) || (ww_ == 7));
    const float* rbase = rpb64 + h * 4096;
    f32x4 oacc[2][4];
#pragma unroll
    for (int mi = 0; mi < 2; ++mi)
#pragma unroll
        for (int ni = 0; ni < 4; ++ni) oacc[mi][ni] = fz;

#pragma unroll
    for (int qt = 0; qt < 4; ++qt) {
        f32x4 at[4];
        __builtin_amdgcn_s_setprio(1);
#pragma unroll
        for (int jt = 0; jt < 4; ++jt) {
            FragU a; a.i4 = kf[jt];
            FragU bq; bq.i4 = qf[qt];
            at[jt] = __builtin_amdgcn_mfma_f32_16x16x32_bf16(a.b8, bq.b8, fz, 0, 0, 0);
        }
        __builtin_amdgcn_s_setprio(0);

        float iq = invq[qt];
        int qi = qt * 16 + lr;
        int qc = (qi < 49) ? qi : 48;
        int rlq = 0, clq = 0;
        if (edge) {
            rlq = (wh == 7) ? ((qc / 7) < 4 ? 1 : 2) : 0;
            clq = (ww_ == 7) ? ((qc % 7) < 4 ? 1 : 2) : 0;
        }
#pragma unroll
        for (int jt = 0; jt < 4; ++jt) {
            float4 rv = *(const float4*)(rbase + qc * 64 + jt * 16 + lg * 4);
            float rr[4] = {rv.x, rv.y, rv.z, rv.w};
#pragma unroll
            for (int r = 0; r < 4; ++r) {
                float v = fmaf(at[jt][r] * ika[jt][r], iq, rr[r]);
                if (edge) {
                    int j = jt * 16 + lg * 4 + r;
                    int jc = (j < 49) ? j : 48;
                    int rlk = (wh == 7) ? ((jc / 7) < 4 ? 1 : 2) : 0;
                    int clk = (ww_ == 7) ? ((jc % 7) < 4 ? 1 : 2) : 0;
                    if (rlk != rlq || clk != clq) v -= 100.0f;
                }
                at[jt][r] = v;
            }
        }
        float m = -1e30f;
#pragma unroll
        for (int jt = 0; jt < 4; ++jt)
#pragma unroll
            for (int r = 0; r < 4; ++r) m = fmaxf(m, at[jt][r]);
        m = fmaxf(m, __shfl_xor(m, 16));
        m = fmaxf(m, __shfl_xor(m, 32));
        float s = 0.f;
#pragma unroll
        for (int jt = 0; jt < 4; ++jt)
#pragma unroll
            for (int r = 0; r < 4; ++r) {
                float p = __expf(at[jt][r] - m);
                at[jt][r] = p;
                s += p;
            }
        s += __shfl_xor(s, 16);
        s += __shfl_xor(s, 32);
        float inv = 1.0f / s;
#pragma unroll
        for (int jt = 0; jt < 4; ++jt) {
            unsigned lo = cvt_pk_bf16(at[jt][0] * inv, at[jt][1] * inv);
            unsigned hi = cvt_pk_bf16(at[jt][2] * inv, at[jt][3] * inv);
            *(int2*)&Pt[lr * 72 + jt * 16 + lg * 4] = make_int2((int)lo, (int)hi);
        }
        __builtin_amdgcn_s_setprio(1);
#pragma unroll
        for (int kc = 0; kc < 2; ++kc) {
            FragU pb;
            pb.i4 = *(const int4*)&Pt[lr * 72 + kc * 32 + lg * 8];
#pragma unroll
            for (int mi = 0; mi < 2; ++mi) {
                FragU va;
                va.i4 = *(const int4*)&Vt[(mi * 16 + lr) * 72 + kc * 32 + lg * 8];
                oacc[mi][qt] = __builtin_amdgcn_mfma_f32_16x16x32_bf16(
                    va.b8, pb.b8, oacc[mi][qt], 0, 0, 0);
            }
        }
        __builtin_amdgcn_s_setprio(0);
    }

#pragma unroll
    for (int ni = 0; ni < 4; ++ni) {
        int qrow = ni * 16 + lr;
        if (qrow < 49) {
            int tok = tokbase + (qrow / 7) * 56 + (qrow % 7);
#pragma unroll
            for (int mi = 0; mi < 2; ++mi) {
                unsigned lo = cvt_pk_bf16(oacc[mi][ni][0], oacc[mi][ni][1]);
                unsigned hi = cvt_pk_bf16(oacc[mi][ni][2], oacc[mi][ni][3]);
                *(int2*)&aout[(size_t)tok * 128 + h * 32 + mi * 16 + lg * 4] =
                    make_int2((int)lo, (int)hi);
            }
        }
    }
}

// ------------- PatchMerging gather + LN -> bf16 rows [25088][512] ----------
__global__ __launch_bounds__(256) void k_pmln(
    const short* __restrict__ x, const float* __restrict__ g,
    const float* __restrict__ bt, short* __restrict__ outb) {
    int m2 = blockIdx.x * 4 + (threadIdx.x >> 6);
    int l = threadIdx.x & 63;
    int b = m2 / 784, r = m2 % 784;
    int h2 = r / 28, w2 = r % 28;
    int q0 = l * 8;
    int i2 = q0 >> 8, j2 = (q0 >> 7) & 1, c = q0 & 127;
    const short* src = x + (size_t)((b * 56 + 2 * h2 + i2) * 56 + 2 * w2 + j2) * 128 + c;
    FragU u; u.i4 = *(const int4*)src;
    float v[8];
#pragma unroll
    for (int e = 0; e < 8; ++e) v[e] = bf2f(u.u[e]);
    float s1 = 0.f, s2 = 0.f;
#pragma unroll
    for (int e = 0; e < 8; ++e) { s1 += v[e]; s2 = fmaf(v[e], v[e], s2); }
#pragma unroll
    for (int off = 32; off >= 1; off >>= 1) {
        s1 += __shfl_xor(s1, off);
        s2 += __shfl_xor(s2, off);
    }
    float mean = s1 * (1.0f / 512.0f);
    float var = s2 * (1.0f / 512.0f) - mean * mean;
    float rstd = rsqrtf(var + 1e-5f);
    union { int4 i4; short s8[8]; } o;
#pragma unroll
    for (int e = 0; e < 8; ++e)
        o.s8[e] = f2bf((v[e] - mean) * rstd * g[q0 + e] + bt[q0 + e]);
    *(int4*)(outb + (size_t)m2 * 512 + q0) = o.i4;
}

// ---------------------------------------------------------------------------
extern "C" void kernel_launch(void* const* d_in, const int* in_sizes, int n_in,
                              void* d_out, int out_size, void* d_ws, size_t ws_size,
                              hipStream_t stream) {
    const float* x_in   = (const float*)d_in[0];
    const float* qkv_w  = (const float*)d_in[1];
    const float* q_bias = (const float*)d_in[2];
    const float* v_bias = (const float*)d_in[3];
    const float* lscale = (const float*)d_in[4];
    const float* cpb_w1 = (const float*)d_in[5];
    const float* cpb_b1 = (const float*)d_in[6];
    const float* cpb_w2 = (const float*)d_in[7];
    const float* proj_w = (const float*)d_in[8];
    const float* proj_b = (const float*)d_in[9];
    const float* n1g    = (const float*)d_in[10];
    const float* n1b    = (const float*)d_in[11];
    const float* mw1    = (const float*)d_in[12];
    const float* mb1    = (const float*)d_in[13];
    const float* mw2    = (const float*)d_in[14];
    const float* mb2    = (const float*)d_in[15];
    const float* n2g    = (const float*)d_in[16];
    const float* n2b    = (const float*)d_in[17];
    const float* pmg    = (const float*)d_in[18];
    const float* pmb    = (const float*)d_in[19];
    const float* pmw    = (const float*)d_in[20];
    float* out = (float*)d_out;

    float* wsf    = (float*)d_ws;
    short* wall   = (short*)wsf;                 // 524,288 shorts
    short* wqkvb  = wall;                        // 2 x 49,152
    short* wprojb = wall + 98304;                // 2 x 16,384
    short* wm1b   = wall + 131072;               // 2 x 65,536
    short* wm2b   = wall + 262144;               // 2 x 65,536
    short* wpmb   = wall + 393216;               // 131,072
    float* out169 = wsf + 262144;                // 2 x 704
    float* rpb64  = out169 + 1408;               // 2 x 16,384
    float* bias384 = rpb64 + 32768;              // 2 x 384

    float* R1      = wsf + (size_t)12845056;
    short* attnout = (short*)(R1 + (size_t)19267584);   // kTok*128 bf16
    short* pmin    = (short*)R1;                        // 25088*512 bf16
    short* xb      = (short*)(R1 + (size_t)25690112);   // kTok*128 bf16

    k_cvtall<<<260, 256, 0, stream>>>(qkv_w, proj_w, mw1, mw2, pmw,
                                      q_bias, v_bias, wall, bias384);
    k_cpb<<<338, 256, 0, stream>>>(cpb_w1, cpb_b1, cpb_w2, out169);
    k_rpb<<<128, 256, 0, stream>>>(out169, rpb64);
    k_cvtx<<<6272, 256, 0, stream>>>(x_in, xb);

    for (int i = 0; i < 2; ++i) {
        int shift = i ? 3 : 0;
        k_attn<<<2048, 256, 0, stream>>>(
            xb, wqkvb + i * 49152, bias384 + i * 384, rpb64 + i * 16384,
            lscale + i * 4, attnout, shift);
        if (i == 0) {
            k_gemm_ln<128, true><<<1568, 256, 0, stream>>>(
                attnout, wprojb, proj_b, n1g, n1b, x_in, xb, shift);
        } else {
            k_gemm_ln<128, false><<<1568, 256, 0, stream>>>(
                attnout, wprojb + 16384, proj_b + 128, n1g + 128, n1b + 128,
                xb, xb, shift);
        }
        k_mlp<<<784, 256, 0, stream>>>(
            xb, wm1b + i * 65536, wm2b + i * 65536, mb1 + i * 512,
            mb2 + i * 128, n2g + i * 128, n2b + i * 128);
    }
    k_pmln<<<6272, 256, 0, stream>>>(xb, pmg, pmb, pmin);
    k_gemm<512, 4><<<784, 256, 0, stream>>>(pmin, wpmb, out, 256);
}

// Round 15
// 336.038 us; speedup vs baseline: 1.4181x; 1.0559x over previous
//
#include <hip/hip_runtime.h>
#include <math.h>

// ---------------------------------------------------------------------------
// SwinV2 stage: B=32, H=W=56, C=128, NH=4, hd=32, WS=7, N=49, DEPTH=2, shift=3
// Round 15: k_attn LDS diet — V written transposed directly from phase 1,
// qkvs holds q/k only, Pt aliases qkvs after q/k register load, invk via
// shuffle. 78.8 -> 52.2 KB LDS => 3 blocks/CU. Rest unchanged from R14.
// ---------------------------------------------------------------------------

namespace {
constexpr int kTok = 32 * 56 * 56;   // 100352 tokens
}

typedef __attribute__((ext_vector_type(8))) short bf16x8;
typedef __attribute__((ext_vector_type(4))) float f32x4;

union FragU {
    int4 i4;
    bf16x8 b8;
    unsigned short u[8];
};

__device__ __forceinline__ short f2bf(float f) {
    unsigned u = __float_as_uint(f);
    return (short)((u + 0x7FFFu + ((u >> 16) & 1u)) >> 16);
}
__device__ __forceinline__ float bf2f(unsigned short u) {
    return __uint_as_float(((unsigned)u) << 16);
}
__device__ __forceinline__ unsigned cvt_pk_bf16(float a, float b) {
    unsigned r;
    asm("v_cvt_pk_bf16_f32 %0, %1, %2" : "=v"(r) : "v"(a), "v"(b));
    return r;
}
// tanh-form GELU, 8 insts (exp2 + v_rcp, no IEEE div)
__device__ __forceinline__ float gelu_t(float x) {
    float x2 = x * x;
    float t0 = fmaf(0.044715f * x2, x, x);
    float e = exp2f(2.3022227f * t0);           // exp(2*0.79788456*t0)
    float r = __builtin_amdgcn_rcpf(e + 1.0f);
    return fmaf(-x, r, x);                      // x * (1 - 1/(e+1))
}

// --------------------------- CPB MLP (both layers) -------------------------
__global__ __launch_bounds__(256) void k_cpb(
    const float* __restrict__ w1, const float* __restrict__ b1,
    const float* __restrict__ w2, float* __restrict__ out169) {
    int L = blockIdx.x / 169;
    int t = blockIdx.x % 169;
    const float* w1L = w1 + L * 1024;
    const float* b1L = b1 + L * 512;
    const float* w2L = w2 + L * 2048;
    float* outL = out169 + L * 704;
    int ia = t / 13, ib = t % 13;
    float r0 = (float)(ia - 6) * (8.0f / 6.0f);
    float s0 = (r0 > 0.f) ? 1.f : (r0 < 0.f ? -1.f : 0.f);
    float t0 = s0 * log2f(fabsf(r0) + 1.0f) * (1.0f / 3.0f);
    float r1 = (float)(ib - 6) * (8.0f / 6.0f);
    float s1 = (r1 > 0.f) ? 1.f : (r1 < 0.f ? -1.f : 0.f);
    float t1 = s1 * log2f(fabsf(r1) + 1.0f) * (1.0f / 3.0f);

    int tid = threadIdx.x;
    float p0 = 0, p1 = 0, p2 = 0, p3 = 0;
    for (int c = tid; c < 512; c += 256) {
        float hv = fmaxf(t0 * w1L[c] + t1 * w1L[512 + c] + b1L[c], 0.0f);
        p0 += hv * w2L[c * 4 + 0];
        p1 += hv * w2L[c * 4 + 1];
        p2 += hv * w2L[c * 4 + 2];
        p3 += hv * w2L[c * 4 + 3];
    }
    __shared__ float red[256][4];
    red[tid][0] = p0; red[tid][1] = p1; red[tid][2] = p2; red[tid][3] = p3;
    __syncthreads();
    for (int s = 128; s > 0; s >>= 1) {
        if (tid < s) {
            red[tid][0] += red[tid + s][0];
            red[tid][1] += red[tid + s][1];
            red[tid][2] += red[tid + s][2];
            red[tid][3] += red[tid + s][3];
        }
        __syncthreads();
    }
    if (tid < 4) outL[t * 4 + tid] = red[0][tid];
}

// rpb64[L][h][qrow64][krow64]; krow>=49 -> -30000 (k-pad baked in)
__global__ void k_rpb(const float* __restrict__ out169, float* __restrict__ rpb64) {
    int e2 = blockIdx.x * 256 + threadIdx.x;   // over 2 * 16384
    int L = e2 >> 14, e = e2 & 16383;
    int h = e >> 12, r = e & 4095;
    int i = r >> 6, j = r & 63;
    float val;
    if (j >= 49) {
        val = -30000.0f;
    } else if (i >= 49) {
        val = 0.0f;
    } else {
        int dp = i / 7 - j / 7 + 6;
        int dq = i % 7 - j % 7 + 6;
        float v = out169[L * 704 + (dp * 13 + dq) * 4 + h];
        val = 16.0f / (1.0f + expf(-v));
    }
    rpb64[e2] = val;
}

// ---------------- all weights fp32 -> bf16 tiled images, one pass ----------
__device__ __forceinline__ void cvt_slot(
    const float* __restrict__ W, short* __restrict__ Wb, int slt, int Kb, int N) {
    int nn = slt & 63;
    int tmp = slt >> 6;
    int kb = tmp % Kb;
    int nt = tmp / Kb;
    int n = nt * 64 + nn;
    int k0 = kb * 8;
    union { int4 i4; short s8[8]; } u;
#pragma unroll
    for (int e = 0; e < 8; ++e) u.s8[e] = f2bf(W[(size_t)(k0 + e) * N + n]);
    int nns = (nn & ~3) | ((nn ^ kb) & 3);
    *(int4*)(Wb + (((size_t)tmp) * 64 + nns) * 8) = u.i4;
}

__global__ __launch_bounds__(256) void k_cvtall(
    const float* __restrict__ qkv_w, const float* __restrict__ proj_w,
    const float* __restrict__ mw1, const float* __restrict__ mw2,
    const float* __restrict__ pmw, const float* __restrict__ qb,
    const float* __restrict__ vb, short* __restrict__ wall,
    float* __restrict__ bias384) {
    int s = blockIdx.x * 256 + threadIdx.x;
    short* wqkvb  = wall;                      // 2 x 49152 shorts
    short* wprojb = wall + 98304;              // 2 x 16384
    short* wm1b   = wall + 131072;             // 2 x 65536
    short* wm2b   = wall + 262144;             // 2 x 65536
    short* wpmb   = wall + 393216;             // 131072
    if (s < 12288) {
        int L = s / 6144, r = s % 6144;
        cvt_slot(qkv_w + L * 49152, wqkvb + L * 49152, r, 16, 384);
    } else if (s < 16384) {
        int s2 = s - 12288;
        int L = s2 / 2048, r = s2 % 2048;
        cvt_slot(proj_w + L * 16384, wprojb + L * 16384, r, 16, 128);
    } else if (s < 32768) {
        int s2 = s - 16384;
        int L = s2 / 8192, r = s2 % 8192;
        cvt_slot(mw1 + L * 65536, wm1b + L * 65536, r, 16, 512);
    } else if (s < 49152) {
        int s2 = s - 32768;
        int L = s2 / 8192, r = s2 % 8192;
        cvt_slot(mw2 + L * 65536, wm2b + L * 65536, r, 64, 128);
    } else if (s < 65536) {
        cvt_slot(pmw, wpmb, s - 49152, 64, 256);
    } else if (s < 66304) {
        int t = s - 65536;
        int L = t / 384, f = t % 384;
        float v = (f < 128) ? qb[L * 128 + f]
                            : ((f < 256) ? 0.0f : vb[L * 128 + f - 256]);
        bias384[t] = v;
    }
}

// ------------------- activation fp32 -> bf16 rows --------------------------
__global__ __launch_bounds__(256) void k_cvtx(
    const float* __restrict__ x, short* __restrict__ xb) {
    size_t e = ((size_t)blockIdx.x * 256 + threadIdx.x) * 8;
    const float* src = x + e;
    float4 f0 = *(const float4*)src;
    float4 f1 = *(const float4*)(src + 4);
    union { int4 i4; short s8[8]; } u;
    u.s8[0] = f2bf(f0.x); u.s8[1] = f2bf(f0.y);
    u.s8[2] = f2bf(f0.z); u.s8[3] = f2bf(f0.w);
    u.s8[4] = f2bf(f1.x); u.s8[5] = f2bf(f1.y);
    u.s8[6] = f2bf(f1.z); u.s8[7] = f2bf(f1.w);
    *(int4*)(xb + e) = u.i4;
}

// --------------------------- MFMA GEMM (bf16 A) ----------------------------
// PatchMerging tail (fp32 out).
template <int K, int NT>
__global__ __launch_bounds__(256) void k_gemm(
    const short* __restrict__ Ain, const short* __restrict__ Wb,
    float* __restrict__ Out, int ostride) {
    constexpr int Kb = K / 8;
    constexpr int NC = K / 128;
    __shared__ int4 As4[2048];
    __shared__ int4 Ws4[1024];
    int tid = threadIdx.x;
    int nwg = gridDim.x;
    int chunk = nwg >> 3;
    int lid = (blockIdx.x & 7) * chunk + (blockIdx.x >> 3);
    int mt = lid / NT, nt = lid - mt * NT;
    int mb = mt * 128;
    int w = tid >> 6, l = tid & 63, lr = l & 15, lg = l >> 4;
    const f32x4 fz = {0.f, 0.f, 0.f, 0.f};
    f32x4 acc[2][4];
#pragma unroll
    for (int mi = 0; mi < 2; ++mi)
#pragma unroll
        for (int ni = 0; ni < 4; ++ni) acc[mi][ni] = fz;

    for (int c = 0; c < NC; ++c) {
        if (c) __syncthreads();
#pragma unroll
        for (int it = 0; it < 8; ++it) {
            int s = it * 256 + tid;
            int m = s >> 4, kb = s & 15;
            int slot = kb * 128 + ((m & ~7) | ((m ^ kb) & 7));
            As4[slot] = *(const int4*)(Ain + (size_t)(mb + m) * K + c * 128 + kb * 8);
        }
        {
            const int4* wsrc = (const int4*)(Wb + ((size_t)nt * Kb + c * 16) * 64 * 8);
#pragma unroll
            for (int it = 0; it < 4; ++it) Ws4[it * 256 + tid] = wsrc[it * 256 + tid];
        }
        __syncthreads();
#pragma unroll
        for (int kk = 0; kk < 4; ++kk) {
            int kbl = kk * 4 + lg;
            int m0 = w * 32 + lr;
            bf16x8 a0 = *(const bf16x8*)&As4[kbl * 128 + ((m0 & ~7) | ((m0 ^ kbl) & 7))];
            int m1 = m0 + 16;
            bf16x8 a1 = *(const bf16x8*)&As4[kbl * 128 + ((m1 & ~7) | ((m1 ^ kbl) & 7))];
#pragma unroll
            for (int ni = 0; ni < 4; ++ni) {
                int nn = lr + 16 * ni;
                bf16x8 bfr = *(const bf16x8*)&Ws4[kbl * 64 + ((nn & ~3) | ((nn ^ kbl) & 3))];
                acc[0][ni] = __builtin_amdgcn_mfma_f32_16x16x32_bf16(a0, bfr, acc[0][ni], 0, 0, 0);
                acc[1][ni] = __builtin_amdgcn_mfma_f32_16x16x32_bf16(a1, bfr, acc[1][ni], 0, 0, 0);
            }
        }
    }
#pragma unroll
    for (int ni = 0; ni < 4; ++ni) {
        int col = nt * 64 + ni * 16 + lr;
#pragma unroll
        for (int mi = 0; mi < 2; ++mi) {
#pragma unroll
            for (int r = 0; r < 4; ++r) {
                int row = mb + w * 32 + mi * 16 + lg * 4 + r;
                Out[(size_t)row * ostride + col] = acc[mi][ni][r];
            }
        }
    }
}

// ------------- MFMA GEMM + bias + LN + residual (+roll-back) ---------------
template <int K, bool RF32>
__global__ __launch_bounds__(256) void k_gemm_ln(
    const short* __restrict__ Ain, const short* __restrict__ Wb,
    const float* __restrict__ bias, const float* __restrict__ g,
    const float* __restrict__ bt, const void* __restrict__ resid,
    short* __restrict__ xoutb, int shift) {
    constexpr int Kb = K / 8;
    constexpr int NC = K / 128;
    __shared__ int4 As4[1024];
    __shared__ int4 Ws4[2048];
    int tid = threadIdx.x;
    int mb = blockIdx.x * 64;
    int w = tid >> 6, l = tid & 63, lr = l & 15, lg = l >> 4;
    const f32x4 fz = {0.f, 0.f, 0.f, 0.f};
    f32x4 acc[8];
#pragma unroll
    for (int ni = 0; ni < 8; ++ni) acc[ni] = fz;

    for (int c = 0; c < NC; ++c) {
        if (c) __syncthreads();
#pragma unroll
        for (int it = 0; it < 4; ++it) {
            int s = it * 256 + tid;
            int m = s >> 4, kb = s & 15;
            int slot = kb * 64 + ((m & ~7) | ((m ^ kb) & 7));
            As4[slot] = *(const int4*)(Ain + (size_t)(mb + m) * K + c * 128 + kb * 8);
        }
        {
            const int4* w0 = (const int4*)(Wb + ((size_t)(c * 16)) * 64 * 8);
            const int4* w1 = (const int4*)(Wb + ((size_t)(Kb + c * 16)) * 64 * 8);
#pragma unroll
            for (int it = 0; it < 4; ++it) {
                Ws4[it * 256 + tid] = w0[it * 256 + tid];
                Ws4[1024 + it * 256 + tid] = w1[it * 256 + tid];
            }
        }
        __syncthreads();
#pragma unroll
        for (int kk = 0; kk < 4; ++kk) {
            int kbl = kk * 4 + lg;
            int m0 = w * 16 + lr;
            bf16x8 a0 = *(const bf16x8*)&As4[kbl * 64 + ((m0 & ~7) | ((m0 ^ kbl) & 7))];
#pragma unroll
            for (int ni = 0; ni < 8; ++ni) {
                int nn = lr + 16 * (ni & 3);
                bf16x8 bfr = *(const bf16x8*)&Ws4[(ni >> 2) * 1024 + kbl * 64 +
                                                  ((nn & ~3) | ((nn ^ kbl) & 3))];
                acc[ni] = __builtin_amdgcn_mfma_f32_16x16x32_bf16(a0, bfr, acc[ni], 0, 0, 0);
            }
        }
    }
    float bv[8], gv[8], btv[8];
#pragma unroll
    for (int ni = 0; ni < 8; ++ni) {
        int col = ni * 16 + lr;
        bv[ni] = bias[col]; gv[ni] = g[col]; btv[ni] = bt[col];
    }
#pragma unroll
    for (int r = 0; r < 4; ++r) {
        int row = mb + w * 16 + lg * 4 + r;
        float v[8];
        float s1 = 0.f, s2 = 0.f;
#pragma unroll
        for (int ni = 0; ni < 8; ++ni) {
            v[ni] = acc[ni][r] + bv[ni];
            s1 += v[ni];
            s2 = fmaf(v[ni], v[ni], s2);
        }
#pragma unroll
        for (int off = 8; off >= 1; off >>= 1) {
            s1 += __shfl_xor(s1, off);
            s2 += __shfl_xor(s2, off);
        }
        float mean = s1 * (1.0f / 128.0f);
        float var = s2 * (1.0f / 128.0f) - mean * mean;
        float rstd = rsqrtf(var + 1e-5f);
        int mo = row;
        if (shift) {
            int b = row / 3136, rr = row % 3136;
            int hh = rr / 56 + shift; if (hh >= 56) hh -= 56;
            int ww = rr % 56 + shift; if (ww >= 56) ww -= 56;
            mo = b * 3136 + hh * 56 + ww;
        }
        size_t base = (size_t)mo * 128;
#pragma unroll
        for (int ni = 0; ni < 8; ++ni) {
            int col = ni * 16 + lr;
            float rv = RF32 ? ((const float*)resid)[base + col]
                            : bf2f(((const unsigned short*)resid)[base + col]);
            float o = rv + (v[ni] - mean) * rstd * gv[ni] + btv[ni];
            xoutb[base + col] = f2bf(o);
        }
    }
}

// -------------------- Fused MLP: fc1 + GELU + fc2 + LN + residual ----------
__global__ __launch_bounds__(256) void k_mlp(
    short* __restrict__ xb, const short* __restrict__ W1b,
    const short* __restrict__ W2b, const float* __restrict__ b1,
    const float* __restrict__ b2, const float* __restrict__ g,
    const float* __restrict__ bt) {
    __shared__ int4 W1s[1024];
    __shared__ int4 W2s[1024];
    __shared__ short Hs[4 * 2304];
    int tid = threadIdx.x;
    int mb = blockIdx.x * 128;
    int w = tid >> 6, l = tid & 63, lr = l & 15, lg = l >> 4;
    const f32x4 fz = {0.f, 0.f, 0.f, 0.f};
    short* Hw = Hs + w * 2304;

    int4 xfrag[2][4];
#pragma unroll
    for (int mi = 0; mi < 2; ++mi)
#pragma unroll
        for (int kk = 0; kk < 4; ++kk)
            xfrag[mi][kk] = *(const int4*)(
                xb + (size_t)(mb + w * 32 + mi * 16 + lr) * 128 + kk * 32 + lg * 8);

    f32x4 acc2[2][8];
#pragma unroll
    for (int mi = 0; mi < 2; ++mi)
#pragma unroll
        for (int ni = 0; ni < 8; ++ni) acc2[mi][ni] = fz;

    for (int c = 0; c < 8; ++c) {
        __syncthreads();
        {
            const int4* w1src = (const int4*)(W1b + (size_t)c * 8192);
#pragma unroll
            for (int it = 0; it < 4; ++it) W1s[it * 256 + tid] = w1src[it * 256 + tid];
            const int4* w2a = (const int4*)(W2b + (size_t)(c * 8) * 512);
            const int4* w2c = (const int4*)(W2b + (size_t)(64 + c * 8) * 512);
#pragma unroll
            for (int it = 0; it < 2; ++it) {
                W2s[it * 256 + tid] = w2a[it * 256 + tid];
                W2s[512 + it * 256 + tid] = w2c[it * 256 + tid];
            }
        }
        __syncthreads();
        f32x4 a1[2][4];
#pragma unroll
        for (int mi = 0; mi < 2; ++mi)
#pragma unroll
            for (int ct = 0; ct < 4; ++ct) a1[mi][ct] = fz;
        __builtin_amdgcn_s_setprio(1);
#pragma unroll
        for (int kk = 0; kk < 4; ++kk) {
            int kbl = kk * 4 + lg;
            FragU xa0; xa0.i4 = xfrag[0][kk];
            FragU xa1; xa1.i4 = xfrag[1][kk];
#pragma unroll
            for (int ct = 0; ct < 4; ++ct) {
                int nn = lr + 16 * ct;
                bf16x8 w1f = *(const bf16x8*)&W1s[kbl * 64 + ((nn & ~3) | ((nn ^ kbl) & 3))];
                a1[0][ct] = __builtin_amdgcn_mfma_f32_16x16x32_bf16(w1f, xa0.b8, a1[0][ct], 0, 0, 0);
                a1[1][ct] = __builtin_amdgcn_mfma_f32_16x16x32_bf16(w1f, xa1.b8, a1[1][ct], 0, 0, 0);
            }
        }
        __builtin_amdgcn_s_setprio(0);
#pragma unroll
        for (int mi = 0; mi < 2; ++mi) {
#pragma unroll
            for (int ct = 0; ct < 4; ++ct) {
                float4 bb = *(const float4*)(b1 + c * 64 + ct * 16 + lg * 4);
                float h0 = gelu_t(a1[mi][ct][0] + bb.x);
                float h1 = gelu_t(a1[mi][ct][1] + bb.y);
                float h2 = gelu_t(a1[mi][ct][2] + bb.z);
                float h3 = gelu_t(a1[mi][ct][3] + bb.w);
                unsigned p0 = cvt_pk_bf16(h0, h1);
                unsigned p1 = cvt_pk_bf16(h2, h3);
                *(int2*)&Hw[(mi * 16 + lr) * 72 + ct * 16 + lg * 4] =
                    make_int2((int)p0, (int)p1);
            }
        }
        __builtin_amdgcn_s_setprio(1);
#pragma unroll
        for (int kc = 0; kc < 2; ++kc) {
            int kbl = kc * 4 + lg;
            FragU ha0; ha0.i4 = *(const int4*)&Hw[lr * 72 + kc * 32 + lg * 8];
            FragU ha1; ha1.i4 = *(const int4*)&Hw[(16 + lr) * 72 + kc * 32 + lg * 8];
#pragma unroll
            for (int ni = 0; ni < 8; ++ni) {
                int nn = lr + 16 * (ni & 3);
                bf16x8 w2f = *(const bf16x8*)&W2s[(ni >> 2) * 512 + kbl * 64 +
                                                  ((nn & ~3) | ((nn ^ kbl) & 3))];
                acc2[0][ni] = __builtin_amdgcn_mfma_f32_16x16x32_bf16(ha0.b8, w2f, acc2[0][ni], 0, 0, 0);
                acc2[1][ni] = __builtin_amdgcn_mfma_f32_16x16x32_bf16(ha1.b8, w2f, acc2[1][ni], 0, 0, 0);
            }
        }
        __builtin_amdgcn_s_setprio(0);
    }

    float bv[8], gv[8], btv[8];
#pragma unroll
    for (int ni = 0; ni < 8; ++ni) {
        int col = ni * 16 + lr;
        bv[ni] = b2[col]; gv[ni] = g[col]; btv[ni] = bt[col];
    }
#pragma unroll
    for (int mi = 0; mi < 2; ++mi) {
#pragma unroll
        for (int r = 0; r < 4; ++r) {
            int row = mb + w * 32 + mi * 16 + lg * 4 + r;
            float v[8];
            float s1 = 0.f, s2 = 0.f;
#pragma unroll
            for (int ni = 0; ni < 8; ++ni) {
                v[ni] = acc2[mi][ni][r] + bv[ni];
                s1 += v[ni];
                s2 = fmaf(v[ni], v[ni], s2);
            }
#pragma unroll
            for (int off = 8; off >= 1; off >>= 1) {
                s1 += __shfl_xor(s1, off);
                s2 += __shfl_xor(s2, off);
            }
            float mean = s1 * (1.0f / 128.0f);
            float var = s2 * (1.0f / 128.0f) - mean * mean;
            float rstd = rsqrtf(var + 1e-5f);
            size_t base = (size_t)row * 128;
#pragma unroll
            for (int ni = 0; ni < 8; ++ni) {
                int col = ni * 16 + lr;
                float rv = bf2f(((const unsigned short*)xb)[base + col]);
                float o = rv + (v[ni] - mean) * rstd * gv[ni] + btv[ni];
                xb[base + col] = f2bf(o);
            }
        }
    }
}

// ---------------- Fused qkv + windowed attention (lean LDS) ----------------
// grid 2048, 4 waves. Phase 1: wave w computes qkv^T for tokens w*16..+15;
// q,k -> qkvs[64][264]; v -> per-head Vt[32][72] DIRECTLY (already
// transposed). Phase 2: wave h loads q/k frags to regs; Pt aliases qkvs.
__global__ __launch_bounds__(256) void k_attn(
    const short* __restrict__ xb, const short* __restrict__ Wq,
    const float* __restrict__ bias384, const float* __restrict__ rpb64,
    const float* __restrict__ ls, short* __restrict__ aout, int shift) {
    __shared__ short qkvs[64 * 264];          // [tok][256+8] q,k; later Pt
    __shared__ short Vth[4 * 2304];           // [head][32 d][72]
    int wid = blockIdx.x;
    int b = wid >> 6, wrem = wid & 63;
    int wh = wrem >> 3, ww_ = wrem & 7;
    int tid = threadIdx.x;
    int w = tid >> 6;
    int l = tid & 63, lr = l & 15, lg = l >> 4;
    int tokbase = b * 3136 + wh * 7 * 56 + ww_ * 7;
    const f32x4 fz = {0.f, 0.f, 0.f, 0.f};

    // ---------------- phase 1: qkv for tokens w*16+lr ----------------
    {
        int ti = w * 16 + lr;
        bool valid = (ti < 49);
        int4 xfrag[4];
        const int4 zero4 = make_int4(0, 0, 0, 0);
        if (valid) {
            int m = tokbase + (ti / 7) * 56 + (ti % 7);
            if (shift) {
                int bb2 = m / 3136, rr = m % 3136;
                int hh = rr / 56 + shift; if (hh >= 56) hh -= 56;
                int ww2 = rr % 56 + shift; if (ww2 >= 56) ww2 -= 56;
                m = bb2 * 3136 + hh * 56 + ww2;
            }
#pragma unroll
            for (int kk = 0; kk < 4; ++kk)
                xfrag[kk] = *(const int4*)(xb + (size_t)m * 128 + kk * 32 + lg * 8);
        } else {
#pragma unroll
            for (int kk = 0; kk < 4; ++kk) xfrag[kk] = zero4;
        }
        short* orow = qkvs + (w * 16 + lr) * 264;
#pragma unroll
        for (int ft = 0; ft < 24; ++ft) {
            f32x4 a = fz;
            int n = ft * 16 + lr;
            int nt = n >> 6, nn = n & 63;
#pragma unroll
            for (int kk = 0; kk < 4; ++kk) {
                int kbl = kk * 4 + lg;
                int nns = (nn & ~3) | ((nn ^ kbl) & 3);
                bf16x8 wf = *(const bf16x8*)(Wq + (((size_t)nt * 16 + kbl) * 64 + nns) * 8);
                FragU xa; xa.i4 = xfrag[kk];
                a = __builtin_amdgcn_mfma_f32_16x16x32_bf16(wf, xa.b8, a, 0, 0, 0);
            }
            float4 bb = *(const float4*)(bias384 + ft * 16 + lg * 4);
            if (ft < 16) {
                // q,k: D col=tok(lr), row=n-offset(lg*4+r) -> pack to qkvs rows
                unsigned p0 = cvt_pk_bf16(a[0] + bb.x, a[1] + bb.y);
                unsigned p1 = cvt_pk_bf16(a[2] + bb.z, a[3] + bb.w);
                *(int2*)&orow[ft * 16 + lg * 4] = make_int2((int)p0, (int)p1);
            } else {
                // v: already transposed (row=d, col=tok) -> straight into Vth
                int f = ft - 16;
                int h2 = f >> 1;
                int dbase = (f & 1) * 16 + lg * 4;
                int tok = w * 16 + lr;
                short* vdst = Vth + h2 * 2304 + dbase * 72 + tok;
                float av[4] = {a[0] + bb.x, a[1] + bb.y, a[2] + bb.z, a[3] + bb.w};
#pragma unroll
                for (int r = 0; r < 4; ++r) vdst[r * 72] = f2bf(av[r]);
            }
        }
    }
    __syncthreads();

    // ---------------- phase 2: attention, wave = head ----------------
    int h = w;
    short* Vt = Vth + h * 2304;              // [32 d][72]

    float scale = __expf(fminf(ls[h], 4.6051702f));  // ln(100)
    int4 qf[4], kf[4];
#pragma unroll
    for (int t = 0; t < 4; ++t) {
        const short* base = qkvs + (t * 16 + lr) * 264 + h * 32 + lg * 8;
        qf[t] = *(const int4*)base;
        kf[t] = *(const int4*)(base + 128);
    }
    __syncthreads();   // all waves done reading q/k; qkvs now reusable as Pt
    short* Pt = qkvs + h * 1152;             // [16 qrow][72]

    float invq[4], ikreg[4];
#pragma unroll
    for (int t = 0; t < 4; ++t) {
        {
            FragU u; u.i4 = qf[t];
            float ss = 0.f;
#pragma unroll
            for (int e = 0; e < 8; ++e) { float x = bf2f(u.u[e]); ss = fmaf(x, x, ss); }
            ss += __shfl_xor(ss, 16);
            ss += __shfl_xor(ss, 32);
            invq[t] = scale / fmaxf(sqrtf(ss), 1e-12f);
        }
        {
            FragU u; u.i4 = kf[t];
            float ss = 0.f;
#pragma unroll
            for (int e = 0; e < 8; ++e) { float x = bf2f(u.u[e]); ss = fmaf(x, x, ss); }
            ss += __shfl_xor(ss, 16);
            ss += __shfl_xor(ss, 32);
            ikreg[t] = 1.0f / fmaxf(sqrtf(ss), 1e-12f);   // valid per row t*16+lr
        }
    }
    // redistribute invk: element (jt, r) needs row jt*16 + lg*4 + r
    float ika[4][4];
#pragma unroll
    for (int jt = 0; jt < 4; ++jt)
#pragma unroll
        for (int r = 0; r < 4; ++r)
            ika[jt][r] = __shfl(ikreg[jt], lg * 4 + r);

    bool edge = (shift != 0) && ((wh == 7) || (ww_ == 7));
    const float* rbase = rpb64 + h * 4096;
    f32x4 oacc[2][4];
#pragma unroll
    for (int mi = 0; mi < 2; ++mi)
#pragma unroll
        for (int ni = 0; ni < 4; ++ni) oacc[mi][ni] = fz;

#pragma unroll
    for (int qt = 0; qt < 4; ++qt) {
        f32x4 at[4];
        __builtin_amdgcn_s_setprio(1);
#pragma unroll
        for (int jt = 0; jt < 4; ++jt) {
            FragU a; a.i4 = kf[jt];
            FragU bq; bq.i4 = qf[qt];
            at[jt] = __builtin_amdgcn_mfma_f32_16x16x32_bf16(a.b8, bq.b8, fz, 0, 0, 0);
        }
        __builtin_amdgcn_s_setprio(0);

        float iq = invq[qt];
        int qi = qt * 16 + lr;
        int qc = (qi < 49) ? qi : 48;
        int rlq = 0, clq = 0;
        if (edge) {
            rlq = (wh == 7) ? ((qc / 7) < 4 ? 1 : 2) : 0;
            clq = (ww_ == 7) ? ((qc % 7) < 4 ? 1 : 2) : 0;
        }
#pragma unroll
        for (int jt = 0; jt < 4; ++jt) {
            float4 rv = *(const float4*)(rbase + qc * 64 + jt * 16 + lg * 4);
            float rr[4] = {rv.x, rv.y, rv.z, rv.w};
#pragma unroll
            for (int r = 0; r < 4; ++r) {
                float v = fmaf(at[jt][r] * ika[jt][r], iq, rr[r]);
                if (edge) {
                    int j = jt * 16 + lg * 4 + r;
                    int jc = (j < 49) ? j : 48;
                    int rlk = (wh == 7) ? ((jc / 7) < 4 ? 1 : 2) : 0;
                    int clk = (ww_ == 7) ? ((jc % 7) < 4 ? 1 : 2) : 0;
                    if (rlk != rlq || clk != clq) v -= 100.0f;
                }
                at[jt][r] = v;
            }
        }
        float m = -1e30f;
#pragma unroll
        for (int jt = 0; jt < 4; ++jt)
#pragma unroll
            for (int r = 0; r < 4; ++r) m = fmaxf(m, at[jt][r]);
        m = fmaxf(m, __shfl_xor(m, 16));
        m = fmaxf(m, __shfl_xor(m, 32));
        float s = 0.f;
#pragma unroll
        for (int jt = 0; jt < 4; ++jt)
#pragma unroll
            for (int r = 0; r < 4; ++r) {
                float p = __expf(at[jt][r] - m);
                at[jt][r] = p;
                s += p;
            }
        s += __shfl_xor(s, 16);
        s += __shfl_xor(s, 32);
        float inv = 1.0f / s;
#pragma unroll
        for (int jt = 0; jt < 4; ++jt) {
            unsigned lo = cvt_pk_bf16(at[jt][0] * inv, at[jt][1] * inv);
            unsigned hi = cvt_pk_bf16(at[jt][2] * inv, at[jt][3] * inv);
            *(int2*)&Pt[lr * 72 + jt * 16 + lg * 4] = make_int2((int)lo, (int)hi);
        }
        __builtin_amdgcn_s_setprio(1);
#pragma unroll
        for (int kc = 0; kc < 2; ++kc) {
            FragU pb;
            pb.i4 = *(const int4*)&Pt[lr * 72 + kc * 32 + lg * 8];
#pragma unroll
            for (int mi = 0; mi < 2; ++mi) {
                FragU va;
                va.i4 = *(const int4*)&Vt[(mi * 16 + lr) * 72 + kc * 32 + lg * 8];
                oacc[mi][qt] = __builtin_amdgcn_mfma_f32_16x16x32_bf16(
                    va.b8, pb.b8, oacc[mi][qt], 0, 0, 0);
            }
        }
        __builtin_amdgcn_s_setprio(0);
    }

#pragma unroll
    for (int ni = 0; ni < 4; ++ni) {
        int qrow = ni * 16 + lr;
        if (qrow < 49) {
            int tok = tokbase + (qrow / 7) * 56 + (qrow % 7);
#pragma unroll
            for (int mi = 0; mi < 2; ++mi) {
                unsigned lo = cvt_pk_bf16(oacc[mi][ni][0], oacc[mi][ni][1]);
                unsigned hi = cvt_pk_bf16(oacc[mi][ni][2], oacc[mi][ni][3]);
                *(int2*)&aout[(size_t)tok * 128 + h * 32 + mi * 16 + lg * 4] =
                    make_int2((int)lo, (int)hi);
            }
        }
    }
}

// ------------- PatchMerging gather + LN -> bf16 rows [25088][512] ----------
__global__ __launch_bounds__(256) void k_pmln(
    const short* __restrict__ x, const float* __restrict__ g,
    const float* __restrict__ bt, short* __restrict__ outb) {
    int m2 = blockIdx.x * 4 + (threadIdx.x >> 6);
    int l = threadIdx.x & 63;
    int b = m2 / 784, r = m2 % 784;
    int h2 = r / 28, w2 = r % 28;
    int q0 = l * 8;
    int i2 = q0 >> 8, j2 = (q0 >> 7) & 1, c = q0 & 127;
    const short* src = x + (size_t)((b * 56 + 2 * h2 + i2) * 56 + 2 * w2 + j2) * 128 + c;
    FragU u; u.i4 = *(const int4*)src;
    float v[8];
#pragma unroll
    for (int e = 0; e < 8; ++e) v[e] = bf2f(u.u[e]);
    float s1 = 0.f, s2 = 0.f;
#pragma unroll
    for (int e = 0; e < 8; ++e) { s1 += v[e]; s2 = fmaf(v[e], v[e], s2); }
#pragma unroll
    for (int off = 32; off >= 1; off >>= 1) {
        s1 += __shfl_xor(s1, off);
        s2 += __shfl_xor(s2, off);
    }
    float mean = s1 * (1.0f / 512.0f);
    float var = s2 * (1.0f / 512.0f) - mean * mean;
    float rstd = rsqrtf(var + 1e-5f);
    union { int4 i4; short s8[8]; } o;
#pragma unroll
    for (int e = 0; e < 8; ++e)
        o.s8[e] = f2bf((v[e] - mean) * rstd * g[q0 + e] + bt[q0 + e]);
    *(int4*)(outb + (size_t)m2 * 512 + q0) = o.i4;
}

// ---------------------------------------------------------------------------
extern "C" void kernel_launch(void* const* d_in, const int* in_sizes, int n_in,
                              void* d_out, int out_size, void* d_ws, size_t ws_size,
                              hipStream_t stream) {
    const float* x_in   = (const float*)d_in[0];
    const float* qkv_w  = (const float*)d_in[1];
    const float* q_bias = (const float*)d_in[2];
    const float* v_bias = (const float*)d_in[3];
    const float* lscale = (const float*)d_in[4];
    const float* cpb_w1 = (const float*)d_in[5];
    const float* cpb_b1 = (const float*)d_in[6];
    const float* cpb_w2 = (const float*)d_in[7];
    const float* proj_w = (const float*)d_in[8];
    const float* proj_b = (const float*)d_in[9];
    const float* n1g    = (const float*)d_in[10];
    const float* n1b    = (const float*)d_in[11];
    const float* mw1    = (const float*)d_in[12];
    const float* mb1    = (const float*)d_in[13];
    const float* mw2    = (const float*)d_in[14];
    const float* mb2    = (const float*)d_in[15];
    const float* n2g    = (const float*)d_in[16];
    const float* n2b    = (const float*)d_in[17];
    const float* pmg    = (const float*)d_in[18];
    const float* pmb    = (const float*)d_in[19];
    const float* pmw    = (const float*)d_in[20];
    float* out = (float*)d_out;

    float* wsf    = (float*)d_ws;
    short* wall   = (short*)wsf;                 // 524,288 shorts
    short* wqkvb  = wall;                        // 2 x 49,152
    short* wprojb = wall + 98304;                // 2 x 16,384
    short* wm1b   = wall + 131072;               // 2 x 65,536
    short* wm2b   = wall + 262144;               // 2 x 65,536
    short* wpmb   = wall + 393216;               // 131,072
    float* out169 = wsf + 262144;                // 2 x 704
    float* rpb64  = out169 + 1408;               // 2 x 16,384
    float* bias384 = rpb64 + 32768;              // 2 x 384

    float* R1      = wsf + (size_t)12845056;
    short* attnout = (short*)(R1 + (size_t)19267584);   // kTok*128 bf16
    short* pmin    = (short*)R1;                        // 25088*512 bf16
    short* xb      = (short*)(R1 + (size_t)25690112);   // kTok*128 bf16

    k_cvtall<<<260, 256, 0, stream>>>(qkv_w, proj_w, mw1, mw2, pmw,
                                      q_bias, v_bias, wall, bias384);
    k_cpb<<<338, 256, 0, stream>>>(cpb_w1, cpb_b1, cpb_w2, out169);
    k_rpb<<<128, 256, 0, stream>>>(out169, rpb64);
    k_cvtx<<<6272, 256, 0, stream>>>(x_in, xb);

    for (int i = 0; i < 2; ++i) {
        int shift = i ? 3 : 0;
        k_attn<<<2048, 256, 0, stream>>>(
            xb, wqkvb + i * 49152, bias384 + i * 384, rpb64 + i * 16384,
            lscale + i * 4, attnout, shift);
        if (i == 0) {
            k_gemm_ln<128, true><<<1568, 256, 0, stream>>>(
                attnout, wprojb, proj_b, n1g, n1b, x_in, xb, shift);
        } else {
            k_gemm_ln<128, false><<<1568, 256, 0, stream>>>(
                attnout, wprojb + 16384, proj_b + 128, n1g + 128, n1b + 128,
                xb, xb, shift);
        }
        k_mlp<<<784, 256, 0, stream>>>(
            xb, wm1b + i * 65536, wm2b + i * 65536, mb1 + i * 512,
            mb2 + i * 128, n2g + i * 128, n2b + i * 128);
    }
    k_pmln<<<6272, 256, 0, stream>>>(xb, pmg, pmb, pmin);
    k_gemm<512, 4><<<784, 256, 0, stream>>>(pmin, wpmb, out, 256);
}

// Round 16
// 323.045 us; speedup vs baseline: 1.4752x; 1.0402x over previous
//
#include <hip/hip_runtime.h>
#include <math.h>

// ---------------------------------------------------------------------------
// SwinV2 stage: B=32, H=W=56, C=128, NH=4, hd=32, WS=7, N=49, DEPTH=2, shift=3
// Round 16: k_mlp -> 8 waves x 16 rows (512 threads): same LDS, ~2x waves/SIMD
// to hide the serial fc1->GELU->fc2 chain. Rest unchanged from R15.
// ---------------------------------------------------------------------------

namespace {
constexpr int kTok = 32 * 56 * 56;   // 100352 tokens
}

typedef __attribute__((ext_vector_type(8))) short bf16x8;
typedef __attribute__((ext_vector_type(4))) float f32x4;

union FragU {
    int4 i4;
    bf16x8 b8;
    unsigned short u[8];
};

__device__ __forceinline__ short f2bf(float f) {
    unsigned u = __float_as_uint(f);
    return (short)((u + 0x7FFFu + ((u >> 16) & 1u)) >> 16);
}
__device__ __forceinline__ float bf2f(unsigned short u) {
    return __uint_as_float(((unsigned)u) << 16);
}
__device__ __forceinline__ unsigned cvt_pk_bf16(float a, float b) {
    unsigned r;
    asm("v_cvt_pk_bf16_f32 %0, %1, %2" : "=v"(r) : "v"(a), "v"(b));
    return r;
}
// tanh-form GELU, 8 insts (exp2 + v_rcp, no IEEE div)
__device__ __forceinline__ float gelu_t(float x) {
    float x2 = x * x;
    float t0 = fmaf(0.044715f * x2, x, x);
    float e = exp2f(2.3022227f * t0);           // exp(2*0.79788456*t0)
    float r = __builtin_amdgcn_rcpf(e + 1.0f);
    return fmaf(-x, r, x);                      // x * (1 - 1/(e+1))
}

// --------------------------- CPB MLP (both layers) -------------------------
__global__ __launch_bounds__(256) void k_cpb(
    const float* __restrict__ w1, const float* __restrict__ b1,
    const float* __restrict__ w2, float* __restrict__ out169) {
    int L = blockIdx.x / 169;
    int t = blockIdx.x % 169;
    const float* w1L = w1 + L * 1024;
    const float* b1L = b1 + L * 512;
    const float* w2L = w2 + L * 2048;
    float* outL = out169 + L * 704;
    int ia = t / 13, ib = t % 13;
    float r0 = (float)(ia - 6) * (8.0f / 6.0f);
    float s0 = (r0 > 0.f) ? 1.f : (r0 < 0.f ? -1.f : 0.f);
    float t0 = s0 * log2f(fabsf(r0) + 1.0f) * (1.0f / 3.0f);
    float r1 = (float)(ib - 6) * (8.0f / 6.0f);
    float s1 = (r1 > 0.f) ? 1.f : (r1 < 0.f ? -1.f : 0.f);
    float t1 = s1 * log2f(fabsf(r1) + 1.0f) * (1.0f / 3.0f);

    int tid = threadIdx.x;
    float p0 = 0, p1 = 0, p2 = 0, p3 = 0;
    for (int c = tid; c < 512; c += 256) {
        float hv = fmaxf(t0 * w1L[c] + t1 * w1L[512 + c] + b1L[c], 0.0f);
        p0 += hv * w2L[c * 4 + 0];
        p1 += hv * w2L[c * 4 + 1];
        p2 += hv * w2L[c * 4 + 2];
        p3 += hv * w2L[c * 4 + 3];
    }
    __shared__ float red[256][4];
    red[tid][0] = p0; red[tid][1] = p1; red[tid][2] = p2; red[tid][3] = p3;
    __syncthreads();
    for (int s = 128; s > 0; s >>= 1) {
        if (tid < s) {
            red[tid][0] += red[tid + s][0];
            red[tid][1] += red[tid + s][1];
            red[tid][2] += red[tid + s][2];
            red[tid][3] += red[tid + s][3];
        }
        __syncthreads();
    }
    if (tid < 4) outL[t * 4 + tid] = red[0][tid];
}

// rpb64[L][h][qrow64][krow64]; krow>=49 -> -30000 (k-pad baked in)
__global__ void k_rpb(const float* __restrict__ out169, float* __restrict__ rpb64) {
    int e2 = blockIdx.x * 256 + threadIdx.x;   // over 2 * 16384
    int L = e2 >> 14, e = e2 & 16383;
    int h = e >> 12, r = e & 4095;
    int i = r >> 6, j = r & 63;
    float val;
    if (j >= 49) {
        val = -30000.0f;
    } else if (i >= 49) {
        val = 0.0f;
    } else {
        int dp = i / 7 - j / 7 + 6;
        int dq = i % 7 - j % 7 + 6;
        float v = out169[L * 704 + (dp * 13 + dq) * 4 + h];
        val = 16.0f / (1.0f + expf(-v));
    }
    rpb64[e2] = val;
}

// ---------------- all weights fp32 -> bf16 tiled images, one pass ----------
__device__ __forceinline__ void cvt_slot(
    const float* __restrict__ W, short* __restrict__ Wb, int slt, int Kb, int N) {
    int nn = slt & 63;
    int tmp = slt >> 6;
    int kb = tmp % Kb;
    int nt = tmp / Kb;
    int n = nt * 64 + nn;
    int k0 = kb * 8;
    union { int4 i4; short s8[8]; } u;
#pragma unroll
    for (int e = 0; e < 8; ++e) u.s8[e] = f2bf(W[(size_t)(k0 + e) * N + n]);
    int nns = (nn & ~3) | ((nn ^ kb) & 3);
    *(int4*)(Wb + (((size_t)tmp) * 64 + nns) * 8) = u.i4;
}

__global__ __launch_bounds__(256) void k_cvtall(
    const float* __restrict__ qkv_w, const float* __restrict__ proj_w,
    const float* __restrict__ mw1, const float* __restrict__ mw2,
    const float* __restrict__ pmw, const float* __restrict__ qb,
    const float* __restrict__ vb, short* __restrict__ wall,
    float* __restrict__ bias384) {
    int s = blockIdx.x * 256 + threadIdx.x;
    short* wqkvb  = wall;                      // 2 x 49152 shorts
    short* wprojb = wall + 98304;              // 2 x 16384
    short* wm1b   = wall + 131072;             // 2 x 65536
    short* wm2b   = wall + 262144;             // 2 x 65536
    short* wpmb   = wall + 393216;             // 131072
    if (s < 12288) {
        int L = s / 6144, r = s % 6144;
        cvt_slot(qkv_w + L * 49152, wqkvb + L * 49152, r, 16, 384);
    } else if (s < 16384) {
        int s2 = s - 12288;
        int L = s2 / 2048, r = s2 % 2048;
        cvt_slot(proj_w + L * 16384, wprojb + L * 16384, r, 16, 128);
    } else if (s < 32768) {
        int s2 = s - 16384;
        int L = s2 / 8192, r = s2 % 8192;
        cvt_slot(mw1 + L * 65536, wm1b + L * 65536, r, 16, 512);
    } else if (s < 49152) {
        int s2 = s - 32768;
        int L = s2 / 8192, r = s2 % 8192;
        cvt_slot(mw2 + L * 65536, wm2b + L * 65536, r, 64, 128);
    } else if (s < 65536) {
        cvt_slot(pmw, wpmb, s - 49152, 64, 256);
    } else if (s < 66304) {
        int t = s - 65536;
        int L = t / 384, f = t % 384;
        float v = (f < 128) ? qb[L * 128 + f]
                            : ((f < 256) ? 0.0f : vb[L * 128 + f - 256]);
        bias384[t] = v;
    }
}

// ------------------- activation fp32 -> bf16 rows --------------------------
__global__ __launch_bounds__(256) void k_cvtx(
    const float* __restrict__ x, short* __restrict__ xb) {
    size_t e = ((size_t)blockIdx.x * 256 + threadIdx.x) * 8;
    const float* src = x + e;
    float4 f0 = *(const float4*)src;
    float4 f1 = *(const float4*)(src + 4);
    union { int4 i4; short s8[8]; } u;
    u.s8[0] = f2bf(f0.x); u.s8[1] = f2bf(f0.y);
    u.s8[2] = f2bf(f0.z); u.s8[3] = f2bf(f0.w);
    u.s8[4] = f2bf(f1.x); u.s8[5] = f2bf(f1.y);
    u.s8[6] = f2bf(f1.z); u.s8[7] = f2bf(f1.w);
    *(int4*)(xb + e) = u.i4;
}

// --------------------------- MFMA GEMM (bf16 A) ----------------------------
// PatchMerging tail (fp32 out).
template <int K, int NT>
__global__ __launch_bounds__(256) void k_gemm(
    const short* __restrict__ Ain, const short* __restrict__ Wb,
    float* __restrict__ Out, int ostride) {
    constexpr int Kb = K / 8;
    constexpr int NC = K / 128;
    __shared__ int4 As4[2048];
    __shared__ int4 Ws4[1024];
    int tid = threadIdx.x;
    int nwg = gridDim.x;
    int chunk = nwg >> 3;
    int lid = (blockIdx.x & 7) * chunk + (blockIdx.x >> 3);
    int mt = lid / NT, nt = lid - mt * NT;
    int mb = mt * 128;
    int w = tid >> 6, l = tid & 63, lr = l & 15, lg = l >> 4;
    const f32x4 fz = {0.f, 0.f, 0.f, 0.f};
    f32x4 acc[2][4];
#pragma unroll
    for (int mi = 0; mi < 2; ++mi)
#pragma unroll
        for (int ni = 0; ni < 4; ++ni) acc[mi][ni] = fz;

    for (int c = 0; c < NC; ++c) {
        if (c) __syncthreads();
#pragma unroll
        for (int it = 0; it < 8; ++it) {
            int s = it * 256 + tid;
            int m = s >> 4, kb = s & 15;
            int slot = kb * 128 + ((m & ~7) | ((m ^ kb) & 7));
            As4[slot] = *(const int4*)(Ain + (size_t)(mb + m) * K + c * 128 + kb * 8);
        }
        {
            const int4* wsrc = (const int4*)(Wb + ((size_t)nt * Kb + c * 16) * 64 * 8);
#pragma unroll
            for (int it = 0; it < 4; ++it) Ws4[it * 256 + tid] = wsrc[it * 256 + tid];
        }
        __syncthreads();
#pragma unroll
        for (int kk = 0; kk < 4; ++kk) {
            int kbl = kk * 4 + lg;
            int m0 = w * 32 + lr;
            bf16x8 a0 = *(const bf16x8*)&As4[kbl * 128 + ((m0 & ~7) | ((m0 ^ kbl) & 7))];
            int m1 = m0 + 16;
            bf16x8 a1 = *(const bf16x8*)&As4[kbl * 128 + ((m1 & ~7) | ((m1 ^ kbl) & 7))];
#pragma unroll
            for (int ni = 0; ni < 4; ++ni) {
                int nn = lr + 16 * ni;
                bf16x8 bfr = *(const bf16x8*)&Ws4[kbl * 64 + ((nn & ~3) | ((nn ^ kbl) & 3))];
                acc[0][ni] = __builtin_amdgcn_mfma_f32_16x16x32_bf16(a0, bfr, acc[0][ni], 0, 0, 0);
                acc[1][ni] = __builtin_amdgcn_mfma_f32_16x16x32_bf16(a1, bfr, acc[1][ni], 0, 0, 0);
            }
        }
    }
#pragma unroll
    for (int ni = 0; ni < 4; ++ni) {
        int col = nt * 64 + ni * 16 + lr;
#pragma unroll
        for (int mi = 0; mi < 2; ++mi) {
#pragma unroll
            for (int r = 0; r < 4; ++r) {
                int row = mb + w * 32 + mi * 16 + lg * 4 + r;
                Out[(size_t)row * ostride + col] = acc[mi][ni][r];
            }
        }
    }
}

// ------------- MFMA GEMM + bias + LN + residual (+roll-back) ---------------
template <int K, bool RF32>
__global__ __launch_bounds__(256) void k_gemm_ln(
    const short* __restrict__ Ain, const short* __restrict__ Wb,
    const float* __restrict__ bias, const float* __restrict__ g,
    const float* __restrict__ bt, const void* __restrict__ resid,
    short* __restrict__ xoutb, int shift) {
    constexpr int Kb = K / 8;
    constexpr int NC = K / 128;
    __shared__ int4 As4[1024];
    __shared__ int4 Ws4[2048];
    int tid = threadIdx.x;
    int mb = blockIdx.x * 64;
    int w = tid >> 6, l = tid & 63, lr = l & 15, lg = l >> 4;
    const f32x4 fz = {0.f, 0.f, 0.f, 0.f};
    f32x4 acc[8];
#pragma unroll
    for (int ni = 0; ni < 8; ++ni) acc[ni] = fz;

    for (int c = 0; c < NC; ++c) {
        if (c) __syncthreads();
#pragma unroll
        for (int it = 0; it < 4; ++it) {
            int s = it * 256 + tid;
            int m = s >> 4, kb = s & 15;
            int slot = kb * 64 + ((m & ~7) | ((m ^ kb) & 7));
            As4[slot] = *(const int4*)(Ain + (size_t)(mb + m) * K + c * 128 + kb * 8);
        }
        {
            const int4* w0 = (const int4*)(Wb + ((size_t)(c * 16)) * 64 * 8);
            const int4* w1 = (const int4*)(Wb + ((size_t)(Kb + c * 16)) * 64 * 8);
#pragma unroll
            for (int it = 0; it < 4; ++it) {
                Ws4[it * 256 + tid] = w0[it * 256 + tid];
                Ws4[1024 + it * 256 + tid] = w1[it * 256 + tid];
            }
        }
        __syncthreads();
#pragma unroll
        for (int kk = 0; kk < 4; ++kk) {
            int kbl = kk * 4 + lg;
            int m0 = w * 16 + lr;
            bf16x8 a0 = *(const bf16x8*)&As4[kbl * 64 + ((m0 & ~7) | ((m0 ^ kbl) & 7))];
#pragma unroll
            for (int ni = 0; ni < 8; ++ni) {
                int nn = lr + 16 * (ni & 3);
                bf16x8 bfr = *(const bf16x8*)&Ws4[(ni >> 2) * 1024 + kbl * 64 +
                                                  ((nn & ~3) | ((nn ^ kbl) & 3))];
                acc[ni] = __builtin_amdgcn_mfma_f32_16x16x32_bf16(a0, bfr, acc[ni], 0, 0, 0);
            }
        }
    }
    float bv[8], gv[8], btv[8];
#pragma unroll
    for (int ni = 0; ni < 8; ++ni) {
        int col = ni * 16 + lr;
        bv[ni] = bias[col]; gv[ni] = g[col]; btv[ni] = bt[col];
    }
#pragma unroll
    for (int r = 0; r < 4; ++r) {
        int row = mb + w * 16 + lg * 4 + r;
        float v[8];
        float s1 = 0.f, s2 = 0.f;
#pragma unroll
        for (int ni = 0; ni < 8; ++ni) {
            v[ni] = acc[ni][r] + bv[ni];
            s1 += v[ni];
            s2 = fmaf(v[ni], v[ni], s2);
        }
#pragma unroll
        for (int off = 8; off >= 1; off >>= 1) {
            s1 += __shfl_xor(s1, off);
            s2 += __shfl_xor(s2, off);
        }
        float mean = s1 * (1.0f / 128.0f);
        float var = s2 * (1.0f / 128.0f) - mean * mean;
        float rstd = rsqrtf(var + 1e-5f);
        int mo = row;
        if (shift) {
            int b = row / 3136, rr = row % 3136;
            int hh = rr / 56 + shift; if (hh >= 56) hh -= 56;
            int ww = rr % 56 + shift; if (ww >= 56) ww -= 56;
            mo = b * 3136 + hh * 56 + ww;
        }
        size_t base = (size_t)mo * 128;
#pragma unroll
        for (int ni = 0; ni < 8; ++ni) {
            int col = ni * 16 + lr;
            float rv = RF32 ? ((const float*)resid)[base + col]
                            : bf2f(((const unsigned short*)resid)[base + col]);
            float o = rv + (v[ni] - mean) * rstd * gv[ni] + btv[ni];
            xoutb[base + col] = f2bf(o);
        }
    }
}

// ---------- Fused MLP: fc1+GELU+fc2+LN+residual, 8 waves x 16 rows ---------
// In-place on xb. BM=128, 512 threads; W1s/W2s shared by 8 waves; Hs
// wave-private [16 tok][72]. Serial chain per wave halved vs 4-wave version.
__global__ __launch_bounds__(512) void k_mlp(
    short* __restrict__ xb, const short* __restrict__ W1b,
    const short* __restrict__ W2b, const float* __restrict__ b1,
    const float* __restrict__ b2, const float* __restrict__ g,
    const float* __restrict__ bt) {
    __shared__ int4 W1s[1024];
    __shared__ int4 W2s[1024];
    __shared__ short Hs[8 * 1152];
    int tid = threadIdx.x;
    int mb = blockIdx.x * 128;
    int w = tid >> 6, l = tid & 63, lr = l & 15, lg = l >> 4;
    const f32x4 fz = {0.f, 0.f, 0.f, 0.f};
    short* Hw = Hs + w * 1152;

    int4 xfrag[4];
#pragma unroll
    for (int kk = 0; kk < 4; ++kk)
        xfrag[kk] = *(const int4*)(
            xb + (size_t)(mb + w * 16 + lr) * 128 + kk * 32 + lg * 8);

    f32x4 acc2[8];
#pragma unroll
    for (int ni = 0; ni < 8; ++ni) acc2[ni] = fz;

    for (int c = 0; c < 8; ++c) {
        __syncthreads();
        {
            const int4* w1src = (const int4*)(W1b + (size_t)c * 8192);
#pragma unroll
            for (int it = 0; it < 2; ++it) W1s[it * 512 + tid] = w1src[it * 512 + tid];
            const int4* w2a = (const int4*)(W2b + (size_t)(c * 8) * 512);
            const int4* w2c = (const int4*)(W2b + (size_t)(64 + c * 8) * 512);
            W2s[tid] = w2a[tid];
            W2s[512 + tid] = w2c[tid];
        }
        __syncthreads();
        // fc1 (swapped operands): Ht rows = hid cols, cols = token (lr)
        f32x4 a1[4];
#pragma unroll
        for (int ct = 0; ct < 4; ++ct) a1[ct] = fz;
        __builtin_amdgcn_s_setprio(1);
#pragma unroll
        for (int kk = 0; kk < 4; ++kk) {
            int kbl = kk * 4 + lg;
            FragU xa; xa.i4 = xfrag[kk];
#pragma unroll
            for (int ct = 0; ct < 4; ++ct) {
                int nn = lr + 16 * ct;
                bf16x8 w1f = *(const bf16x8*)&W1s[kbl * 64 + ((nn & ~3) | ((nn ^ kbl) & 3))];
                a1[ct] = __builtin_amdgcn_mfma_f32_16x16x32_bf16(w1f, xa.b8, a1[ct], 0, 0, 0);
            }
        }
        __builtin_amdgcn_s_setprio(0);
        // bias + gelu + pack: lane writes 4 consecutive hid cols per ct
#pragma unroll
        for (int ct = 0; ct < 4; ++ct) {
            float4 bb = *(const float4*)(b1 + c * 64 + ct * 16 + lg * 4);
            float h0 = gelu_t(a1[ct][0] + bb.x);
            float h1 = gelu_t(a1[ct][1] + bb.y);
            float h2 = gelu_t(a1[ct][2] + bb.z);
            float h3 = gelu_t(a1[ct][3] + bb.w);
            unsigned p0 = cvt_pk_bf16(h0, h1);
            unsigned p1 = cvt_pk_bf16(h2, h3);
            *(int2*)&Hw[lr * 72 + ct * 16 + lg * 4] = make_int2((int)p0, (int)p1);
        }
        // fc2 accumulate (K=64 chunk), A from wave-private Hw
        __builtin_amdgcn_s_setprio(1);
#pragma unroll
        for (int kc = 0; kc < 2; ++kc) {
            int kbl = kc * 4 + lg;
            FragU ha; ha.i4 = *(const int4*)&Hw[lr * 72 + kc * 32 + lg * 8];
#pragma unroll
            for (int ni = 0; ni < 8; ++ni) {
                int nn = lr + 16 * (ni & 3);
                bf16x8 w2f = *(const bf16x8*)&W2s[(ni >> 2) * 512 + kbl * 64 +
                                                  ((nn & ~3) | ((nn ^ kbl) & 3))];
                acc2[ni] = __builtin_amdgcn_mfma_f32_16x16x32_bf16(ha.b8, w2f, acc2[ni], 0, 0, 0);
            }
        }
        __builtin_amdgcn_s_setprio(0);
    }

    // LN + residual epilogue (fp32 math, bf16 storage, in-place)
    float bv[8], gv[8], btv[8];
#pragma unroll
    for (int ni = 0; ni < 8; ++ni) {
        int col = ni * 16 + lr;
        bv[ni] = b2[col]; gv[ni] = g[col]; btv[ni] = bt[col];
    }
#pragma unroll
    for (int r = 0; r < 4; ++r) {
        int row = mb + w * 16 + lg * 4 + r;
        float v[8];
        float s1 = 0.f, s2 = 0.f;
#pragma unroll
        for (int ni = 0; ni < 8; ++ni) {
            v[ni] = acc2[ni][r] + bv[ni];
            s1 += v[ni];
            s2 = fmaf(v[ni], v[ni], s2);
        }
#pragma unroll
        for (int off = 8; off >= 1; off >>= 1) {
            s1 += __shfl_xor(s1, off);
            s2 += __shfl_xor(s2, off);
        }
        float mean = s1 * (1.0f / 128.0f);
        float var = s2 * (1.0f / 128.0f) - mean * mean;
        float rstd = rsqrtf(var + 1e-5f);
        size_t base = (size_t)row * 128;
#pragma unroll
        for (int ni = 0; ni < 8; ++ni) {
            int col = ni * 16 + lr;
            float rv = bf2f(((const unsigned short*)xb)[base + col]);
            float o = rv + (v[ni] - mean) * rstd * gv[ni] + btv[ni];
            xb[base + col] = f2bf(o);
        }
    }
}

// ---------------- Fused qkv + windowed attention (lean LDS) ----------------
__global__ __launch_bounds__(256) void k_attn(
    const short* __restrict__ xb, const short* __restrict__ Wq,
    const float* __restrict__ bias384, const float* __restrict__ rpb64,
    const float* __restrict__ ls, short* __restrict__ aout, int shift) {
    __shared__ short qkvs[64 * 264];          // [tok][256+8] q,k; later Pt
    __shared__ short Vth[4 * 2304];           // [head][32 d][72]
    int wid = blockIdx.x;
    int b = wid >> 6, wrem = wid & 63;
    int wh = wrem >> 3, ww_ = wrem & 7;
    int tid = threadIdx.x;
    int w = tid >> 6;
    int l = tid & 63, lr = l & 15, lg = l >> 4;
    int tokbase = b * 3136 + wh * 7 * 56 + ww_ * 7;
    const f32x4 fz = {0.f, 0.f, 0.f, 0.f};

    // ---------------- phase 1: qkv for tokens w*16+lr ----------------
    {
        int ti = w * 16 + lr;
        bool valid = (ti < 49);
        int4 xfrag[4];
        const int4 zero4 = make_int4(0, 0, 0, 0);
        if (valid) {
            int m = tokbase + (ti / 7) * 56 + (ti % 7);
            if (shift) {
                int bb2 = m / 3136, rr = m % 3136;
                int hh = rr / 56 + shift; if (hh >= 56) hh -= 56;
                int ww2 = rr % 56 + shift; if (ww2 >= 56) ww2 -= 56;
                m = bb2 * 3136 + hh * 56 + ww2;
            }
#pragma unroll
            for (int kk = 0; kk < 4; ++kk)
                xfrag[kk] = *(const int4*)(xb + (size_t)m * 128 + kk * 32 + lg * 8);
        } else {
#pragma unroll
            for (int kk = 0; kk < 4; ++kk) xfrag[kk] = zero4;
        }
        short* orow = qkvs + (w * 16 + lr) * 264;
#pragma unroll
        for (int ft = 0; ft < 24; ++ft) {
            f32x4 a = fz;
            int n = ft * 16 + lr;
            int nt = n >> 6, nn = n & 63;
#pragma unroll
            for (int kk = 0; kk < 4; ++kk) {
                int kbl = kk * 4 + lg;
                int nns = (nn & ~3) | ((nn ^ kbl) & 3);
                bf16x8 wf = *(const bf16x8*)(Wq + (((size_t)nt * 16 + kbl) * 64 + nns) * 8);
                FragU xa; xa.i4 = xfrag[kk];
                a = __builtin_amdgcn_mfma_f32_16x16x32_bf16(wf, xa.b8, a, 0, 0, 0);
            }
            float4 bb = *(const float4*)(bias384 + ft * 16 + lg * 4);
            if (ft < 16) {
                unsigned p0 = cvt_pk_bf16(a[0] + bb.x, a[1] + bb.y);
                unsigned p1 = cvt_pk_bf16(a[2] + bb.z, a[3] + bb.w);
                *(int2*)&orow[ft * 16 + lg * 4] = make_int2((int)p0, (int)p1);
            } else {
                int f = ft - 16;
                int h2 = f >> 1;
                int dbase = (f & 1) * 16 + lg * 4;
                int tok = w * 16 + lr;
                short* vdst = Vth + h2 * 2304 + dbase * 72 + tok;
                float av[4] = {a[0] + bb.x, a[1] + bb.y, a[2] + bb.z, a[3] + bb.w};
#pragma unroll
                for (int r = 0; r < 4; ++r) vdst[r * 72] = f2bf(av[r]);
            }
        }
    }
    __syncthreads();

    // ---------------- phase 2: attention, wave = head ----------------
    int h = w;
    short* Vt = Vth + h * 2304;              // [32 d][72]

    float scale = __expf(fminf(ls[h], 4.6051702f));  // ln(100)
    int4 qf[4], kf[4];
#pragma unroll
    for (int t = 0; t < 4; ++t) {
        const short* base = qkvs + (t * 16 + lr) * 264 + h * 32 + lg * 8;
        qf[t] = *(const int4*)base;
        kf[t] = *(const int4*)(base + 128);
    }
    __syncthreads();   // all waves done reading q/k; qkvs now reusable as Pt
    short* Pt = qkvs + h * 1152;             // [16 qrow][72]

    float invq[4], ikreg[4];
#pragma unroll
    for (int t = 0; t < 4; ++t) {
        {
            FragU u; u.i4 = qf[t];
            float ss = 0.f;
#pragma unroll
            for (int e = 0; e < 8; ++e) { float x = bf2f(u.u[e]); ss = fmaf(x, x, ss); }
            ss += __shfl_xor(ss, 16);
            ss += __shfl_xor(ss, 32);
            invq[t] = scale / fmaxf(sqrtf(ss), 1e-12f);
        }
        {
            FragU u; u.i4 = kf[t];
            float ss = 0.f;
#pragma unroll
            for (int e = 0; e < 8; ++e) { float x = bf2f(u.u[e]); ss = fmaf(x, x, ss); }
            ss += __shfl_xor(ss, 16);
            ss += __shfl_xor(ss, 32);
            ikreg[t] = 1.0f / fmaxf(sqrtf(ss), 1e-12f);
        }
    }
    float ika[4][4];
#pragma unroll
    for (int jt = 0; jt < 4; ++jt)
#pragma unroll
        for (int r = 0; r < 4; ++r)
            ika[jt][r] = __shfl(ikreg[jt], lg * 4 + r);

    bool edge = (shift != 0) && ((wh == 7) || (ww_ == 7));
    const float* rbase = rpb64 + h * 4096;
    f32x4 oacc[2][4];
#pragma unroll
    for (int mi = 0; mi < 2; ++mi)
#pragma unroll
        for (int ni = 0; ni < 4; ++ni) oacc[mi][ni] = fz;

#pragma unroll
    for (int qt = 0; qt < 4; ++qt) {
        f32x4 at[4];
        __builtin_amdgcn_s_setprio(1);
#pragma unroll
        for (int jt = 0; jt < 4; ++jt) {
            FragU a; a.i4 = kf[jt];
            FragU bq; bq.i4 = qf[qt];
            at[jt] = __builtin_amdgcn_mfma_f32_16x16x32_bf16(a.b8, bq.b8, fz, 0, 0, 0);
        }
        __builtin_amdgcn_s_setprio(0);

        float iq = invq[qt];
        int qi = qt * 16 + lr;
        int qc = (qi < 49) ? qi : 48;
        int rlq = 0, clq = 0;
        if (edge) {
            rlq = (wh == 7) ? ((qc / 7) < 4 ? 1 : 2) : 0;
            clq = (ww_ == 7) ? ((qc % 7) < 4 ? 1 : 2) : 0;
        }
#pragma unroll
        for (int jt = 0; jt < 4; ++jt) {
            float4 rv = *(const float4*)(rbase + qc * 64 + jt * 16 + lg * 4);
            float rr[4] = {rv.x, rv.y, rv.z, rv.w};
#pragma unroll
            for (int r = 0; r < 4; ++r) {
                float v = fmaf(at[jt][r] * ika[jt][r], iq, rr[r]);
                if (edge) {
                    int j = jt * 16 + lg * 4 + r;
                    int jc = (j < 49) ? j : 48;
                    int rlk = (wh == 7) ? ((jc / 7) < 4 ? 1 : 2) : 0;
                    int clk = (ww_ == 7) ? ((jc % 7) < 4 ? 1 : 2) : 0;
                    if (rlk != rlq || clk != clq) v -= 100.0f;
                }
                at[jt][r] = v;
            }
        }
        float m = -1e30f;
#pragma unroll
        for (int jt = 0; jt < 4; ++jt)
#pragma unroll
            for (int r = 0; r < 4; ++r) m = fmaxf(m, at[jt][r]);
        m = fmaxf(m, __shfl_xor(m, 16));
        m = fmaxf(m, __shfl_xor(m, 32));
        float s = 0.f;
#pragma unroll
        for (int jt = 0; jt < 4; ++jt)
#pragma unroll
            for (int r = 0; r < 4; ++r) {
                float p = __expf(at[jt][r] - m);
                at[jt][r] = p;
                s += p;
            }
        s += __shfl_xor(s, 16);
        s += __shfl_xor(s, 32);
        float inv = 1.0f / s;
#pragma unroll
        for (int jt = 0; jt < 4; ++jt) {
            unsigned lo = cvt_pk_bf16(at[jt][0] * inv, at[jt][1] * inv);
            unsigned hi = cvt_pk_bf16(at[jt][2] * inv, at[jt][3] * inv);
            *(int2*)&Pt[lr * 72 + jt * 16 + lg * 4] = make_int2((int)lo, (int)hi);
        }
        __builtin_amdgcn_s_setprio(1);
#pragma unroll
        for (int kc = 0; kc < 2; ++kc) {
            FragU pb;
            pb.i4 = *(const int4*)&Pt[lr * 72 + kc * 32 + lg * 8];
#pragma unroll
            for (int mi = 0; mi < 2; ++mi) {
                FragU va;
                va.i4 = *(const int4*)&Vt[(mi * 16 + lr) * 72 + kc * 32 + lg * 8];
                oacc[mi][qt] = __builtin_amdgcn_mfma_f32_16x16x32_bf16(
                    va.b8, pb.b8, oacc[mi][qt], 0, 0, 0);
            }
        }
        __builtin_amdgcn_s_setprio(0);
    }

#pragma unroll
    for (int ni = 0; ni < 4; ++ni) {
        int qrow = ni * 16 + lr;
        if (qrow < 49) {
            int tok = tokbase + (qrow / 7) * 56 + (qrow % 7);
#pragma unroll
            for (int mi = 0; mi < 2; ++mi) {
                unsigned lo = cvt_pk_bf16(oacc[mi][ni][0], oacc[mi][ni][1]);
                unsigned hi = cvt_pk_bf16(oacc[mi][ni][2], oacc[mi][ni][3]);
                *(int2*)&aout[(size_t)tok * 128 + h * 32 + mi * 16 + lg * 4] =
                    make_int2((int)lo, (int)hi);
            }
        }
    }
}

// ------------- PatchMerging gather + LN -> bf16 rows [25088][512] ----------
__global__ __launch_bounds__(256) void k_pmln(
    const short* __restrict__ x, const float* __restrict__ g,
    const float* __restrict__ bt, short* __restrict__ outb) {
    int m2 = blockIdx.x * 4 + (threadIdx.x >> 6);
    int l = threadIdx.x & 63;
    int b = m2 / 784, r = m2 % 784;
    int h2 = r / 28, w2 = r % 28;
    int q0 = l * 8;
    int i2 = q0 >> 8, j2 = (q0 >> 7) & 1, c = q0 & 127;
    const short* src = x + (size_t)((b * 56 + 2 * h2 + i2) * 56 + 2 * w2 + j2) * 128 + c;
    FragU u; u.i4 = *(const int4*)src;
    float v[8];
#pragma unroll
    for (int e = 0; e < 8; ++e) v[e] = bf2f(u.u[e]);
    float s1 = 0.f, s2 = 0.f;
#pragma unroll
    for (int e = 0; e < 8; ++e) { s1 += v[e]; s2 = fmaf(v[e], v[e], s2); }
#pragma unroll
    for (int off = 32; off >= 1; off >>= 1) {
        s1 += __shfl_xor(s1, off);
        s2 += __shfl_xor(s2, off);
    }
    float mean = s1 * (1.0f / 512.0f);
    float var = s2 * (1.0f / 512.0f) - mean * mean;
    float rstd = rsqrtf(var + 1e-5f);
    union { int4 i4; short s8[8]; } o;
#pragma unroll
    for (int e = 0; e < 8; ++e)
        o.s8[e] = f2bf((v[e] - mean) * rstd * g[q0 + e] + bt[q0 + e]);
    *(int4*)(outb + (size_t)m2 * 512 + q0) = o.i4;
}

// ---------------------------------------------------------------------------
extern "C" void kernel_launch(void* const* d_in, const int* in_sizes, int n_in,
                              void* d_out, int out_size, void* d_ws, size_t ws_size,
                              hipStream_t stream) {
    const float* x_in   = (const float*)d_in[0];
    const float* qkv_w  = (const float*)d_in[1];
    const float* q_bias = (const float*)d_in[2];
    const float* v_bias = (const float*)d_in[3];
    const float* lscale = (const float*)d_in[4];
    const float* cpb_w1 = (const float*)d_in[5];
    const float* cpb_b1 = (const float*)d_in[6];
    const float* cpb_w2 = (const float*)d_in[7];
    const float* proj_w = (const float*)d_in[8];
    const float* proj_b = (const float*)d_in[9];
    const float* n1g    = (const float*)d_in[10];
    const float* n1b    = (const float*)d_in[11];
    const float* mw1    = (const float*)d_in[12];
    const float* mb1    = (const float*)d_in[13];
    const float* mw2    = (const float*)d_in[14];
    const float* mb2    = (const float*)d_in[15];
    const float* n2g    = (const float*)d_in[16];
    const float* n2b    = (const float*)d_in[17];
    const float* pmg    = (const float*)d_in[18];
    const float* pmb    = (const float*)d_in[19];
    const float* pmw    = (const float*)d_in[20];
    float* out = (float*)d_out;

    float* wsf    = (float*)d_ws;
    short* wall   = (short*)wsf;                 // 524,288 shorts
    short* wqkvb  = wall;                        // 2 x 49,152
    short* wprojb = wall + 98304;                // 2 x 16,384
    short* wm1b   = wall + 131072;               // 2 x 65,536
    short* wm2b   = wall + 262144;               // 2 x 65,536
    short* wpmb   = wall + 393216;               // 131,072
    float* out169 = wsf + 262144;                // 2 x 704
    float* rpb64  = out169 + 1408;               // 2 x 16,384
    float* bias384 = rpb64 + 32768;              // 2 x 384

    float* R1      = wsf + (size_t)12845056;
    short* attnout = (short*)(R1 + (size_t)19267584);   // kTok*128 bf16
    short* pmin    = (short*)R1;                        // 25088*512 bf16
    short* xb      = (short*)(R1 + (size_t)25690112);   // kTok*128 bf16

    k_cvtall<<<260, 256, 0, stream>>>(qkv_w, proj_w, mw1, mw2, pmw,
                                      q_bias, v_bias, wall, bias384);
    k_cpb<<<338, 256, 0, stream>>>(cpb_w1, cpb_b1, cpb_w2, out169);
    k_rpb<<<128, 256, 0, stream>>>(out169, rpb64);
    k_cvtx<<<6272, 256, 0, stream>>>(x_in, xb);

    for (int i = 0; i < 2; ++i) {
        int shift = i ? 3 : 0;
        k_attn<<<2048, 256, 0, stream>>>(
            xb, wqkvb + i * 49152, bias384 + i * 384, rpb64 + i * 16384,
            lscale + i * 4, attnout, shift);
        if (i == 0) {
            k_gemm_ln<128, true><<<1568, 256, 0, stream>>>(
                attnout, wprojb, proj_b, n1g, n1b, x_in, xb, shift);
        } else {
            k_gemm_ln<128, false><<<1568, 256, 0, stream>>>(
                attnout, wprojb + 16384, proj_b + 128, n1g + 128, n1b + 128,
                xb, xb, shift);
        }
        k_mlp<<<784, 512, 0, stream>>>(
            xb, wm1b + i * 65536, wm2b + i * 65536, mb1 + i * 512,
            mb2 + i * 128, n2g + i * 128, n2b + i * 128);
    }
    k_pmln<<<6272, 256, 0, stream>>>(xb, pmg, pmb, pmin);
    k_gemm<512, 4><<<784, 256, 0, stream>>>(pmin, wpmb, out, 256);
}